// Round 2
// baseline (6178.361 us; speedup 1.0000x reference)
//
#include <hip/hip_runtime.h>
#include <stdint.h>

#define B_   2
#define L_   4096
#define D_   2048
#define H_   16
#define DK_  128
#define ND3  6144      // 3*D
#define BL_  8192      // B*L

typedef __bf16 bf16x8 __attribute__((ext_vector_type(8)));
typedef float  f32x4  __attribute__((ext_vector_type(4)));

__device__ __forceinline__ float bf2f(ushort u){ return __uint_as_float(((unsigned)u)<<16); }
__device__ __forceinline__ ushort f2bf(float f){
  unsigned u = __float_as_uint(f);
  unsigned r = u + 0x7FFFu + ((u>>16)&1u);   // RNE
  return (ushort)(r>>16);
}

// ---------------- cast hidden f32 -> bf16 ----------------
__global__ __launch_bounds__(256) void k_cast(const float* __restrict__ x, ushort* __restrict__ y, int n4){
  int i = blockIdx.x*blockDim.x + threadIdx.x;
  int stride = gridDim.x*blockDim.x;
  for (; i < n4; i += stride){
    float4 v = ((const float4*)x)[i];
    ushort4 o; o.x=f2bf(v.x); o.y=f2bf(v.y); o.z=f2bf(v.z); o.w=f2bf(v.w);
    ((ushort4*)y)[i] = o;
  }
}

// ---------------- transpose + cast: in [R][C] f32 -> out [C][R] bf16 ----------------
__global__ __launch_bounds__(256) void k_transpose_cast(const float* __restrict__ in, ushort* __restrict__ out,
                                                        int R, int C){
  __shared__ float tile[32][33];
  int c0 = blockIdx.x*32, r0 = blockIdx.y*32;
  int tx = threadIdx.x, ty = threadIdx.y;  // block (32,8)
  #pragma unroll
  for (int i=0;i<32;i+=8) tile[ty+i][tx] = in[(size_t)(r0+ty+i)*C + (c0+tx)];
  __syncthreads();
  #pragma unroll
  for (int i=0;i<32;i+=8) out[(size_t)(c0+ty+i)*R + (r0+tx)] = f2bf(tile[tx][ty+i]);
}

// ---------------- bf16 MFMA GEMM: C[M][N] = A[M][K] * Bt[N][K]^T  (m97 structure) ----------------
template<int OUT_BF16>
__global__ __launch_bounds__(256) void k_gemm_bt(const ushort* __restrict__ A, const ushort* __restrict__ Bt,
                                                 void* __restrict__ Cv, int M, int N, int K){
  __shared__ ushort As[128*32];
  __shared__ ushort Bs[128*32];
  const int tid = threadIdx.x, lane = tid & 63, w = tid >> 6;
  const int m0 = blockIdx.y*128, n0 = blockIdx.x*128;
  const int wr = w >> 1, wc = w & 1;

  f32x4 acc[4][4];
  #pragma unroll
  for (int i=0;i<4;i++)
    #pragma unroll
    for (int j=0;j<4;j++) acc[i][j] = (f32x4){0.f,0.f,0.f,0.f};

  const int lr  = lane & 15;
  const int lk8 = (lane >> 4) * 8;

  for (int k0 = 0; k0 < K; k0 += 32){
    #pragma unroll
    for (int c=0;c<2;c++){
      int chunk = w*2 + c;              // 0..7, 512 elems (1KB) each
      int elem  = chunk*512 + lane*8;
      int row   = elem >> 5, kk = elem & 31;
      __builtin_amdgcn_global_load_lds(
        (const __attribute__((address_space(1))) void*)(A + (size_t)(m0+row)*K + k0 + kk),
        (__attribute__((address_space(3))) void*)(As + chunk*512), 16, 0, 0);
      __builtin_amdgcn_global_load_lds(
        (const __attribute__((address_space(1))) void*)(Bt + (size_t)(n0+row)*K + k0 + kk),
        (__attribute__((address_space(3))) void*)(Bs + chunk*512), 16, 0, 0);
    }
    __syncthreads();
    bf16x8 af[4], bfr[4];
    #pragma unroll
    for (int m=0;m<4;m++) af[m]  = *(const bf16x8*)&As[(wr*64 + m*16 + lr)*32 + lk8];
    #pragma unroll
    for (int n=0;n<4;n++) bfr[n] = *(const bf16x8*)&Bs[(wc*64 + n*16 + lr)*32 + lk8];
    #pragma unroll
    for (int m=0;m<4;m++)
      #pragma unroll
      for (int n=0;n<4;n++)
        acc[m][n] = __builtin_amdgcn_mfma_f32_16x16x32_bf16(af[m], bfr[n], acc[m][n], 0,0,0);
    __syncthreads();
  }

  const int rbase = m0 + wr*64 + (lane>>4)*4;
  const int cbase = n0 + wc*64 + (lane&15);
  #pragma unroll
  for (int m=0;m<4;m++)
    #pragma unroll
    for (int n=0;n<4;n++)
      #pragma unroll
      for (int r=0;r<4;r++){
        int row = rbase + m*16 + r;
        int col = cbase + n*16;
        float v = acc[m][n][r];
        if (OUT_BF16) ((ushort*)Cv)[(size_t)row*N + col] = f2bf(v);
        else          ((float*) Cv)[(size_t)row*N + col] = v;
      }
}

// ---------------- beta = sigmoid(hidden @ w_beta), layout [b][h][l] ----------------
__global__ __launch_bounds__(256) void k_beta(const float* __restrict__ hidden, const float* __restrict__ wb,
                                              float* __restrict__ beta){
  __shared__ float hrow[D_];
  __shared__ float red[256];
  const int blk = blockIdx.x;       // b*L + l
  const int t = threadIdx.x;
  const float* hp = hidden + (size_t)blk * D_;
  for (int i = t; i < D_; i += 256) hrow[i] = hp[i];
  __syncthreads();
  const int h = t >> 4, s = t & 15;
  float acc = 0.f;
  #pragma unroll 8
  for (int i=0;i<128;i++){ int d = s + 16*i; acc += hrow[d] * wb[d*H_ + h]; }
  red[t] = acc;
  __syncthreads();
  if (t < H_){
    float sum = 0.f;
    #pragma unroll
    for (int j=0;j<16;j++) sum += red[t*16 + j];
    float sg = 1.f/(1.f + __expf(-sum));
    int b = blk >> 12, l = blk & 4095;
    beta[((size_t)(b*H_ + t))*L_ + l] = sg;
  }
}

// ---------------- conv(K=4, causal) + SiLU + head reshape + l2norm(q,k) ----------------
__global__ __launch_bounds__(256) void k_convhead(const ushort* __restrict__ qkv,
      const float* __restrict__ wq, const float* __restrict__ wk, const float* __restrict__ wv,
      ushort* __restrict__ QH, ushort* __restrict__ KH, ushort* __restrict__ VH){
  const int blk = blockIdx.x;       // b*L + l
  const int b = blk >> 12, l = blk & 4095;
  const int t = threadIdx.x;
  const int h = t >> 4, d0 = (t & 15) * 8;
  const int ch = h*DK_ + d0;        // channel in [0, D)
  const float* wcs[3] = {wq, wk, wv};
  ushort* outs[3] = {QH, KH, VH};
  #pragma unroll
  for (int part=0; part<3; part++){
    float x[4][8];
    #pragma unroll
    for (int i=0;i<4;i++){
      int lr = l - 3 + i;
      if (lr >= 0){
        const ushort* p = qkv + ((size_t)(b*L_ + lr))*ND3 + part*D_ + ch;
        ushort4 a = *(const ushort4*)p, c = *(const ushort4*)(p+4);
        x[i][0]=bf2f(a.x); x[i][1]=bf2f(a.y); x[i][2]=bf2f(a.z); x[i][3]=bf2f(a.w);
        x[i][4]=bf2f(c.x); x[i][5]=bf2f(c.y); x[i][6]=bf2f(c.z); x[i][7]=bf2f(c.w);
      } else {
        #pragma unroll
        for (int j=0;j<8;j++) x[i][j] = 0.f;
      }
    }
    const float* wc = wcs[part];
    float y[8]; float ss = 0.f;
    #pragma unroll
    for (int j=0;j<8;j++){
      float4 w4 = *(const float4*)&wc[(ch + j)*4];
      float yy = x[0][j]*w4.x + x[1][j]*w4.y + x[2][j]*w4.z + x[3][j]*w4.w;
      yy = yy / (1.f + __expf(-yy));   // SiLU
      y[j] = yy; ss += yy*yy;
    }
    if (part < 2){
      #pragma unroll
      for (int m=1;m<16;m<<=1) ss += __shfl_xor(ss, m, 64);
      float sc = rsqrtf(ss + 1e-12f);
      #pragma unroll
      for (int j=0;j<8;j++) y[j] *= sc;
    }
    ushort* op = outs[part] + ((size_t)(b*H_ + h)*L_ + l)*DK_ + d0;
    ushort4 o0, o1;
    o0.x=f2bf(y[0]); o0.y=f2bf(y[1]); o0.z=f2bf(y[2]); o0.w=f2bf(y[3]);
    o1.x=f2bf(y[4]); o1.y=f2bf(y[5]); o1.z=f2bf(y[6]); o1.w=f2bf(y[7]);
    *(ushort4*)op = o0; *(ushort4*)(op+4) = o1;
  }
}

// ---------------- delta-rule scan: 1 wave per (b,h,half); lane owns one S column ----------------
__global__ __launch_bounds__(64) void k_scan(const ushort* __restrict__ QH, const ushort* __restrict__ KH,
        const ushort* __restrict__ VH, const float* __restrict__ BETA, ushort* __restrict__ OH){
  const int blk = blockIdx.x;          // bh*2 + half
  const int bh = blk >> 1, half = blk & 1;
  const int lane = threadIdx.x;        // 0..63
  const int col = half*64 + lane;
  const ushort* kp = KH + (size_t)bh*L_*DK_;
  const ushort* qp = QH + (size_t)bh*L_*DK_;
  const ushort* vp = VH + (size_t)bh*L_*DK_;
  const float*  bp = BETA + (size_t)bh*L_;
  ushort* op = OH + (size_t)bh*L_*DK_;

  float S[128];
  #pragma unroll
  for (int i=0;i<128;i++) S[i] = 0.f;

  unsigned kk = *(const unsigned*)(kp + 2*lane);
  unsigned qq = *(const unsigned*)(qp + 2*lane);
  ushort vv = vp[col];
  float bt = bp[0];

  for (int t=0;t<L_;t++){
    float k0 = bf2f((ushort)(kk & 0xffff)), k1 = bf2f((ushort)(kk >> 16));
    float q0 = bf2f((ushort)(qq & 0xffff)), q1 = bf2f((ushort)(qq >> 16));
    float vf = bf2f(vv);
    float bc = bt;
    if (t+1 < L_){
      kk = *(const unsigned*)(kp + (size_t)(t+1)*DK_ + 2*lane);
      qq = *(const unsigned*)(qp + (size_t)(t+1)*DK_ + 2*lane);
      vv = vp[(size_t)(t+1)*DK_ + col];
      bt = bp[t+1];
    }
    // pass 1: kS = k . S[:,col]  -- 4 independent accumulation chains
    float kSa = 0.f, kSb = 0.f, kSc = 0.f, kSd = 0.f;
    #pragma unroll
    for (int j=0;j<64;j+=2){
      float ka0 = __int_as_float(__builtin_amdgcn_readlane(__float_as_int(k0), j));
      float kb0 = __int_as_float(__builtin_amdgcn_readlane(__float_as_int(k1), j));
      float ka1 = __int_as_float(__builtin_amdgcn_readlane(__float_as_int(k0), j+1));
      float kb1 = __int_as_float(__builtin_amdgcn_readlane(__float_as_int(k1), j+1));
      kSa += ka0 * S[2*j];   kSb += kb0 * S[2*j+1];
      kSc += ka1 * S[2*j+2]; kSd += kb1 * S[2*j+3];
    }
    float u = bc * (vf - ((kSa + kSb) + (kSc + kSd)));
    // pass 2: S += k*u ; o = q . S (post-update), 4 chains
    float oa = 0.f, ob = 0.f, oc = 0.f, od = 0.f;
    #pragma unroll
    for (int j=0;j<64;j+=2){
      float ka0 = __int_as_float(__builtin_amdgcn_readlane(__float_as_int(k0), j));
      float kb0 = __int_as_float(__builtin_amdgcn_readlane(__float_as_int(k1), j));
      float qa0 = __int_as_float(__builtin_amdgcn_readlane(__float_as_int(q0), j));
      float qb0 = __int_as_float(__builtin_amdgcn_readlane(__float_as_int(q1), j));
      float ka1 = __int_as_float(__builtin_amdgcn_readlane(__float_as_int(k0), j+1));
      float kb1 = __int_as_float(__builtin_amdgcn_readlane(__float_as_int(k1), j+1));
      float qa1 = __int_as_float(__builtin_amdgcn_readlane(__float_as_int(q0), j+1));
      float qb1 = __int_as_float(__builtin_amdgcn_readlane(__float_as_int(q1), j+1));
      S[2*j]   += ka0*u;  oa += qa0 * S[2*j];
      S[2*j+1] += kb0*u;  ob += qb0 * S[2*j+1];
      S[2*j+2] += ka1*u;  oc += qa1 * S[2*j+2];
      S[2*j+3] += kb1*u;  od += qb1 * S[2*j+3];
    }
    op[(size_t)t*DK_ + col] = f2bf((oa + ob) + (oc + od));
  }
}

// ---------------- RMSNorm over head dim + merge to [b*l][D] bf16 ----------------
__global__ __launch_bounds__(256) void k_norm(const ushort* __restrict__ OH, const float* __restrict__ gw,
                                              ushort* __restrict__ O2){
  const int blk = blockIdx.x;      // b*L + l
  const int b = blk >> 12, l = blk & 4095;
  const int t = threadIdx.x;
  const int h = t >> 4, d0 = (t & 15) * 8;
  const ushort* ip = OH + ((size_t)(b*H_ + h)*L_ + l)*DK_ + d0;
  ushort4 a = *(const ushort4*)ip, c = *(const ushort4*)(ip+4);
  float x[8];
  x[0]=bf2f(a.x); x[1]=bf2f(a.y); x[2]=bf2f(a.z); x[3]=bf2f(a.w);
  x[4]=bf2f(c.x); x[5]=bf2f(c.y); x[6]=bf2f(c.z); x[7]=bf2f(c.w);
  float ss = 0.f;
  #pragma unroll
  for (int j=0;j<8;j++) ss += x[j]*x[j];
  #pragma unroll
  for (int m=1;m<16;m<<=1) ss += __shfl_xor(ss, m, 64);
  float sc = rsqrtf(ss * (1.f/128.f) + 1e-5f);
  ushort* opp = O2 + (size_t)blk*D_ + h*DK_ + d0;
  ushort4 o0, o1;
  o0.x=f2bf(x[0]*sc*gw[d0+0]); o0.y=f2bf(x[1]*sc*gw[d0+1]);
  o0.z=f2bf(x[2]*sc*gw[d0+2]); o0.w=f2bf(x[3]*sc*gw[d0+3]);
  o1.x=f2bf(x[4]*sc*gw[d0+4]); o1.y=f2bf(x[5]*sc*gw[d0+5]);
  o1.z=f2bf(x[6]*sc*gw[d0+6]); o1.w=f2bf(x[7]*sc*gw[d0+7]);
  *(ushort4*)opp = o0; *(ushort4*)(opp+4) = o1;
}

extern "C" void kernel_launch(void* const* d_in, const int* in_sizes, int n_in,
                              void* d_out, int out_size, void* d_ws, size_t ws_size,
                              hipStream_t stream) {
  (void)in_sizes; (void)n_in; (void)out_size; (void)ws_size;
  const float* hidden  = (const float*)d_in[0];
  const float* w_cattn = (const float*)d_in[1];
  const float* wq_conv = (const float*)d_in[2];
  const float* wk_conv = (const float*)d_in[3];
  const float* wv_conv = (const float*)d_in[4];
  const float* w_beta  = (const float*)d_in[5];
  const float* o_nw    = (const float*)d_in[6];
  const float* w_o     = (const float*)d_in[7];
  float* out = (float*)d_out;

  // workspace layout -- total 260,046,848 B (~248 MiB), fits 256 MiB budget
  char* W = (char*)d_ws;
  ushort* A16   = (ushort*)(W);                       // 33,554,432 B [8192][2048] bf16; reused as OH after gemm1
  ushort* WcatT = (ushort*)(W + 33554432u);           // 25,165,824 B [6144][2048]; dead after gemm1
  ushort* WoT   = (ushort*)(W + 33554432u);           //  8,388,608 B (aliases WcatT region, written AFTER gemm1)
  float*  BETA  = (float*) (W + 41943040u);           //    524,288 B (aliases WcatT region, written AFTER gemm1)
  ushort* QKV   = (ushort*)(W + 58720256u);           // 100,663,296 B [8192][6144]; reused as O2 after conv
  ushort* QH    = (ushort*)(W + 159383552u);          // 33,554,432 B
  ushort* KH    = (ushort*)(W + 192937984u);          // 33,554,432 B
  ushort* VH    = (ushort*)(W + 226492416u);          // 33,554,432 B  -> end 260,046,848
  ushort* OH = A16;      // alias (hidden_bf16 dead after gemm1)
  ushort* O2 = QKV;      // alias (qkv dead after conv)

  // 1. cast hidden -> bf16
  k_cast<<<4096, 256, 0, stream>>>(hidden, A16, (BL_*D_)/4);
  // 2. transpose+cast w_cattn
  k_transpose_cast<<<dim3(ND3/32, D_/32), dim3(32,8), 0, stream>>>(w_cattn, WcatT, D_, ND3);
  // 3. qkv = hidden @ w_cattn   (bf16 out)
  k_gemm_bt<1><<<dim3(ND3/128, BL_/128), 256, 0, stream>>>(A16, WcatT, QKV, BL_, ND3, D_);
  // 4. transpose+cast w_o into the now-dead WcatT region (stream-ordered after gemm1)
  k_transpose_cast<<<dim3(D_/32, D_/32), dim3(32,8), 0, stream>>>(w_o, WoT, D_, D_);
  // 5. beta (reads f32 hidden input; BETA also lives in dead WcatT region)
  k_beta<<<BL_, 256, 0, stream>>>(hidden, w_beta, BETA);
  // 6. conv + silu + heads + l2norm
  k_convhead<<<BL_, 256, 0, stream>>>(QKV, wq_conv, wk_conv, wv_conv, QH, KH, VH);
  // 7. delta-rule scan
  k_scan<<<64, 64, 0, stream>>>(QH, KH, VH, BETA, OH);
  // 8. RMSNorm + merge heads
  k_norm<<<BL_, 256, 0, stream>>>(OH, o_nw, O2);
  // 9. out = o2 @ w_o  (f32 out)
  k_gemm_bt<0><<<dim3(D_/128, BL_/128), 256, 0, stream>>>(O2, WoT, out, BL_, D_, D_);
}

// Round 3
// 1364.073 us; speedup vs baseline: 4.5293x; 4.5293x over previous
//
#include <hip/hip_runtime.h>
#include <stdint.h>

#define B_   2
#define L_   4096
#define D_   2048
#define H_   16
#define DK_  128
#define ND3  6144
#define BL_  8192

typedef __bf16 bf16x8 __attribute__((ext_vector_type(8)));
typedef float  f32x4  __attribute__((ext_vector_type(4)));

__device__ __forceinline__ float bf2f(ushort u){ return __uint_as_float(((unsigned)u)<<16); }
__device__ __forceinline__ ushort f2bf(float f){
  unsigned u = __float_as_uint(f);
  unsigned r = u + 0x7FFFu + ((u>>16)&1u);
  return (ushort)(r>>16);
}
__device__ __forceinline__ f32x4 mfma16(bf16x8 a, bf16x8 b, f32x4 c){
  return __builtin_amdgcn_mfma_f32_16x16x32_bf16(a, b, c, 0, 0, 0);
}

__global__ __launch_bounds__(256) void k_cast(const float* __restrict__ x, ushort* __restrict__ y, int n4){
  int i = blockIdx.x*blockDim.x + threadIdx.x;
  int stride = gridDim.x*blockDim.x;
  for (; i < n4; i += stride){
    float4 v = ((const float4*)x)[i];
    ushort4 o; o.x=f2bf(v.x); o.y=f2bf(v.y); o.z=f2bf(v.z); o.w=f2bf(v.w);
    ((ushort4*)y)[i] = o;
  }
}

__global__ __launch_bounds__(256) void k_transpose_cast(const float* __restrict__ in, ushort* __restrict__ out,
                                                        int R, int C){
  __shared__ float tile[32][33];
  int c0 = blockIdx.x*32, r0 = blockIdx.y*32;
  int tx = threadIdx.x, ty = threadIdx.y;
  #pragma unroll
  for (int i=0;i<32;i+=8) tile[ty+i][tx] = in[(size_t)(r0+ty+i)*C + (c0+tx)];
  __syncthreads();
  #pragma unroll
  for (int i=0;i<32;i+=8) out[(size_t)(c0+ty+i)*R + (r0+tx)] = f2bf(tile[tx][ty+i]);
}

template<int OUT_BF16>
__global__ __launch_bounds__(256) void k_gemm_bt(const ushort* __restrict__ A, const ushort* __restrict__ Bt,
                                                 void* __restrict__ Cv, int M, int N, int K){
  __shared__ ushort As[128*32];
  __shared__ ushort Bs[128*32];
  const int tid = threadIdx.x, lane = tid & 63, w = tid >> 6;
  const int m0 = blockIdx.y*128, n0 = blockIdx.x*128;
  const int wr = w >> 1, wc = w & 1;
  f32x4 acc[4][4];
  #pragma unroll
  for (int i=0;i<4;i++)
    #pragma unroll
    for (int j=0;j<4;j++) acc[i][j] = (f32x4){0.f,0.f,0.f,0.f};
  const int lr  = lane & 15;
  const int lk8 = (lane >> 4) * 8;
  for (int k0 = 0; k0 < K; k0 += 32){
    #pragma unroll
    for (int c=0;c<2;c++){
      int chunk = w*2 + c;
      int elem  = chunk*512 + lane*8;
      int row   = elem >> 5, kk = elem & 31;
      __builtin_amdgcn_global_load_lds(
        (const __attribute__((address_space(1))) void*)(A + (size_t)(m0+row)*K + k0 + kk),
        (__attribute__((address_space(3))) void*)(As + chunk*512), 16, 0, 0);
      __builtin_amdgcn_global_load_lds(
        (const __attribute__((address_space(1))) void*)(Bt + (size_t)(n0+row)*K + k0 + kk),
        (__attribute__((address_space(3))) void*)(Bs + chunk*512), 16, 0, 0);
    }
    __syncthreads();
    bf16x8 af[4], bfr[4];
    #pragma unroll
    for (int m=0;m<4;m++) af[m]  = *(const bf16x8*)&As[(wr*64 + m*16 + lr)*32 + lk8];
    #pragma unroll
    for (int n=0;n<4;n++) bfr[n] = *(const bf16x8*)&Bs[(wc*64 + n*16 + lr)*32 + lk8];
    #pragma unroll
    for (int m=0;m<4;m++)
      #pragma unroll
      for (int n=0;n<4;n++)
        acc[m][n] = __builtin_amdgcn_mfma_f32_16x16x32_bf16(af[m], bfr[n], acc[m][n], 0,0,0);
    __syncthreads();
  }
  const int rbase = m0 + wr*64 + (lane>>4)*4;
  const int cbase = n0 + wc*64 + (lane&15);
  #pragma unroll
  for (int m=0;m<4;m++)
    #pragma unroll
    for (int n=0;n<4;n++)
      #pragma unroll
      for (int r=0;r<4;r++){
        int row = rbase + m*16 + r;
        int col = cbase + n*16;
        float v = acc[m][n][r];
        if (OUT_BF16) ((ushort*)Cv)[(size_t)row*N + col] = f2bf(v);
        else          ((float*) Cv)[(size_t)row*N + col] = v;
      }
}

__global__ __launch_bounds__(256) void k_beta(const float* __restrict__ hidden, const float* __restrict__ wb,
                                              float* __restrict__ beta){
  __shared__ float hrow[D_];
  __shared__ float red[256];
  const int blk = blockIdx.x;
  const int t = threadIdx.x;
  const float* hp = hidden + (size_t)blk * D_;
  for (int i = t; i < D_; i += 256) hrow[i] = hp[i];
  __syncthreads();
  const int h = t >> 4, s = t & 15;
  float acc = 0.f;
  #pragma unroll 8
  for (int i=0;i<128;i++){ int d = s + 16*i; acc += hrow[d] * wb[d*H_ + h]; }
  red[t] = acc;
  __syncthreads();
  if (t < H_){
    float sum = 0.f;
    #pragma unroll
    for (int j=0;j<16;j++) sum += red[t*16 + j];
    float sg = 1.f/(1.f + __expf(-sum));
    int b = blk >> 12, l = blk & 4095;
    beta[((size_t)(b*H_ + t))*L_ + l] = sg;
  }
}

__global__ __launch_bounds__(256) void k_convhead(const ushort* __restrict__ qkv,
      const float* __restrict__ wq, const float* __restrict__ wk, const float* __restrict__ wv,
      ushort* __restrict__ QH, ushort* __restrict__ KH, ushort* __restrict__ VH){
  const int blk = blockIdx.x;
  const int b = blk >> 12, l = blk & 4095;
  const int t = threadIdx.x;
  const int h = t >> 4, d0 = (t & 15) * 8;
  const int ch = h*DK_ + d0;
  const float* wcs[3] = {wq, wk, wv};
  ushort* outs[3] = {QH, KH, VH};
  #pragma unroll
  for (int part=0; part<3; part++){
    float x[4][8];
    #pragma unroll
    for (int i=0;i<4;i++){
      int lrr = l - 3 + i;
      if (lrr >= 0){
        const ushort* p = qkv + ((size_t)(b*L_ + lrr))*ND3 + part*D_ + ch;
        ushort4 a = *(const ushort4*)p, c = *(const ushort4*)(p+4);
        x[i][0]=bf2f(a.x); x[i][1]=bf2f(a.y); x[i][2]=bf2f(a.z); x[i][3]=bf2f(a.w);
        x[i][4]=bf2f(c.x); x[i][5]=bf2f(c.y); x[i][6]=bf2f(c.z); x[i][7]=bf2f(c.w);
      } else {
        #pragma unroll
        for (int j=0;j<8;j++) x[i][j] = 0.f;
      }
    }
    const float* wc = wcs[part];
    float y[8]; float ss = 0.f;
    #pragma unroll
    for (int j=0;j<8;j++){
      float4 w4 = *(const float4*)&wc[(ch + j)*4];
      float yy = x[0][j]*w4.x + x[1][j]*w4.y + x[2][j]*w4.z + x[3][j]*w4.w;
      yy = yy / (1.f + __expf(-yy));
      y[j] = yy; ss += yy*yy;
    }
    if (part < 2){
      #pragma unroll
      for (int m=1;m<16;m<<=1) ss += __shfl_xor(ss, m, 64);
      float sc = rsqrtf(ss + 1e-12f);
      #pragma unroll
      for (int j=0;j<8;j++) y[j] *= sc;
    }
    ushort* op = outs[part] + ((size_t)(b*H_ + h)*L_ + l)*DK_ + d0;
    ushort4 o0, o1;
    o0.x=f2bf(y[0]); o0.y=f2bf(y[1]); o0.z=f2bf(y[2]); o0.w=f2bf(y[3]);
    o1.x=f2bf(y[4]); o1.y=f2bf(y[5]); o1.z=f2bf(y[6]); o1.w=f2bf(y[7]);
    *(ushort4*)op = o0; *(ushort4*)(op+4) = o1;
  }
}

// ---------------- phase 1: per-chunk Tb, M, Kt ----------------
__global__ __launch_bounds__(64) void k_prep(const ushort* __restrict__ QH, const ushort* __restrict__ KH,
      const float* __restrict__ BETA, ushort* __restrict__ TB, ushort* __restrict__ MM,
      ushort* __restrict__ KT){
  const int bid = blockIdx.x, bh = bid>>6, c = bid&63;
  const int lane = threadIdx.x;
  __shared__ ushort Ks[64][136];
  __shared__ ushort Qs[64][136];
  __shared__ float As[64][64];
  __shared__ float Ts[64][64];
  __shared__ float bs[64];
  const ushort* kg = KH + ((size_t)bh*L_ + c*64)*DK_;
  const ushort* qg = QH + ((size_t)bh*L_ + c*64)*DK_;
  {
    const uint4* ks4 = (const uint4*)(kg + (size_t)lane*DK_);
    const uint4* qs4 = (const uint4*)(qg + (size_t)lane*DK_);
    uint4* kd = (uint4*)&Ks[lane][0];
    uint4* qd = (uint4*)&Qs[lane][0];
    #pragma unroll
    for (int i=0;i<16;i++){ kd[i] = ks4[i]; qd[i] = qs4[i]; }
    bs[lane] = BETA[(size_t)bh*L_ + c*64 + lane];
  }
  __syncthreads();
  const int lr = lane&15, lk = lane>>4;
  {
    f32x4 gac[4][4];
    #pragma unroll
    for (int i=0;i<4;i++)
      #pragma unroll
      for (int j=0;j<4;j++) gac[i][j] = (f32x4){0.f,0.f,0.f,0.f};
    #pragma unroll
    for (int kk=0;kk<4;kk++){
      bf16x8 fr[4];
      #pragma unroll
      for (int i=0;i<4;i++) fr[i] = *(const bf16x8*)&Ks[i*16+lr][kk*32 + lk*8];
      #pragma unroll
      for (int mi=0;mi<4;mi++)
        #pragma unroll
        for (int ni=0;ni<4;ni++)
          gac[mi][ni] = mfma16(fr[mi], fr[ni], gac[mi][ni]);
    }
    #pragma unroll
    for (int mi=0;mi<4;mi++)
      #pragma unroll
      for (int ni=0;ni<4;ni++)
        #pragma unroll
        for (int r=0;r<4;r++){
          int t = mi*16 + lk*4 + r, s = ni*16 + lr;
          As[t][s] = (s < t) ? (bs[t] * gac[mi][ni][r]) : 0.f;
        }
  }
  {
    f32x4 mac[4][4];
    #pragma unroll
    for (int i=0;i<4;i++)
      #pragma unroll
      for (int j=0;j<4;j++) mac[i][j] = (f32x4){0.f,0.f,0.f,0.f};
    #pragma unroll
    for (int kk=0;kk<4;kk++){
      bf16x8 frq[4], frk[4];
      #pragma unroll
      for (int i=0;i<4;i++){
        frq[i] = *(const bf16x8*)&Qs[i*16+lr][kk*32 + lk*8];
        frk[i] = *(const bf16x8*)&Ks[i*16+lr][kk*32 + lk*8];
      }
      #pragma unroll
      for (int mi=0;mi<4;mi++)
        #pragma unroll
        for (int ni=0;ni<4;ni++)
          mac[mi][ni] = mfma16(frq[mi], frk[ni], mac[mi][ni]);
    }
    #pragma unroll
    for (int mi=0;mi<4;mi++)
      #pragma unroll
      for (int ni=0;ni<4;ni++)
        #pragma unroll
        for (int r=0;r<4;r++){
          int t = mi*16 + lk*4 + r, s = ni*16 + lr;
          float v = (s <= t) ? mac[mi][ni][r] : 0.f;
          MM[(size_t)bid*4096 + t*64 + s] = f2bf(v);
        }
  }
  __syncthreads();
  for (int t=0;t<64;t++){
    float a = (t==lane) ? 1.f : 0.f;
    for (int s=0;s<t;s++) a -= As[t][s] * Ts[s][lane];
    Ts[t][lane] = a;
  }
  {
    float bc = bs[lane];
    for (int t=0;t<64;t++)
      TB[(size_t)bid*4096 + t*64 + lane] = f2bf(Ts[t][lane] * bc);
  }
  for (int d2=0; d2<64; d2++){
    unsigned uu = *(const unsigned*)&Ks[lane][2*d2];
    KT[(size_t)bid*8192 + (size_t)(2*d2)*64 + lane]   = (ushort)(uu & 0xffffu);
    KT[(size_t)bid*8192 + (size_t)(2*d2+1)*64 + lane] = (ushort)(uu >> 16);
  }
}

template<int LRB, int GRB, int NB>
__device__ __forceinline__ void stage_swz(const ushort* __restrict__ g, ushort* l,
                                          int colOff, int w, int lane){
  for (int idx = w; idx < NB/1024; idx += 4){
    int off = idx*1024 + lane*16;
    int row = off / LRB;
    int inner = off & (LRB-1);
    int src = row*GRB + colOff + (inner ^ ((row&7)<<4));
    __builtin_amdgcn_global_load_lds(
      (const __attribute__((address_space(1))) void*)((const char*)g + src),
      (__attribute__((address_space(3))) void*)((char*)l + idx*1024), 16, 0, 0);
  }
}

__global__ __launch_bounds__(256) void k_chunkrec(const ushort* __restrict__ QH, const ushort* __restrict__ KH,
      const ushort* __restrict__ VH, const ushort* __restrict__ TB, const ushort* __restrict__ MM,
      const ushort* __restrict__ KT, ushort* __restrict__ OH){
  const int bid = blockIdx.x, bh = bid>>1, vh = bid&1;
  const int tid = threadIdx.x, lane = tid&63, w = tid>>6;
  __shared__ ushort Kc[64*128], Qc[64*128], Ktc[128*64], Tbc[64*64], Mc[64*64], Vc[64*64];
  __shared__ ushort Stl[64*128], Ztl[64*64], Utl[64*64];
  const int lr = lane&15, lk = lane>>4;
  const int tq = (w>>1)*32, jq = (w&1)*32;
  const int dq = (w>>1)*64;

  f32x4 Stf[2][4];
  #pragma unroll
  for (int a=0;a<2;a++)
    #pragma unroll
    for (int b=0;b<4;b++) Stf[a][b] = (f32x4){0.f,0.f,0.f,0.f};

  const ushort* kbase  = KH + ((size_t)bh*L_)*DK_;
  const ushort* qbase  = QH + ((size_t)bh*L_)*DK_;
  const ushort* vbase  = VH + ((size_t)bh*L_)*DK_;
  const ushort* tbase  = TB + ((size_t)bh*64)*4096;
  const ushort* mbase  = MM + ((size_t)bh*64)*4096;
  const ushort* ktbase = KT + ((size_t)bh*64)*8192;
  ushort* obase = OH + ((size_t)bh*L_)*DK_ + vh*64;

  for (int c=0; c<64; c++){
    stage_swz<256,256,16384>(kbase  + (size_t)c*8192, Kc,  0, w, lane);
    stage_swz<256,256,16384>(qbase  + (size_t)c*8192, Qc,  0, w, lane);
    stage_swz<128,128,16384>(ktbase + (size_t)c*8192, Ktc, 0, w, lane);
    stage_swz<128,128, 8192>(tbase  + (size_t)c*4096, Tbc, 0, w, lane);
    stage_swz<128,128, 8192>(mbase  + (size_t)c*4096, Mc,  0, w, lane);
    stage_swz<128,256, 8192>(vbase  + (size_t)c*8192, Vc,  vh*128, w, lane);
    #pragma unroll
    for (int mj=0;mj<2;mj++)
      #pragma unroll
      for (int nd=0;nd<4;nd++)
        #pragma unroll
        for (int r=0;r<4;r++){
          int j = jq + mj*16 + lk*4 + r;
          int d = dq + nd*16 + lr;
          Stl[j*128 + (d ^ ((j&7)<<3))] = f2bf(Stf[mj][nd][r]);
        }
    __syncthreads();

    f32x4 xac[2][2];
    #pragma unroll
    for (int i=0;i<2;i++)
      #pragma unroll
      for (int j2=0;j2<2;j2++) xac[i][j2] = (f32x4){0.f,0.f,0.f,0.f};
    #pragma unroll
    for (int kk=0;kk<4;kk++){
      int e = kk*32 + lk*8;
      bf16x8 bst[2], ak[2];
      #pragma unroll
      for (int ni=0;ni<2;ni++){ int j = jq + ni*16 + lr; bst[ni] = *(const bf16x8*)&Stl[j*128 + (e ^ ((j&7)<<3))]; }
      #pragma unroll
      for (int mi=0;mi<2;mi++){ int t = tq + mi*16 + lr; ak[mi]  = *(const bf16x8*)&Kc [t*128 + (e ^ ((t&7)<<3))]; }
      #pragma unroll
      for (int mi=0;mi<2;mi++)
        #pragma unroll
        for (int ni=0;ni<2;ni++)
          xac[mi][ni] = mfma16(ak[mi], bst[ni], xac[mi][ni]);
    }
    #pragma unroll
    for (int mi=0;mi<2;mi++)
      #pragma unroll
      for (int ni=0;ni<2;ni++)
        #pragma unroll
        for (int r=0;r<4;r++){
          int t = tq + mi*16 + lk*4 + r;
          int j = jq + ni*16 + lr;
          float v = bf2f(Vc[t*64 + (j ^ ((t&7)<<3))]);
          Ztl[j*64 + (t ^ ((j&7)<<3))] = f2bf(v - xac[mi][ni][r]);
        }
    __syncthreads();

    f32x4 uac[2][2];
    #pragma unroll
    for (int i=0;i<2;i++)
      #pragma unroll
      for (int j2=0;j2<2;j2++) uac[i][j2] = (f32x4){0.f,0.f,0.f,0.f};
    #pragma unroll
    for (int kk=0;kk<2;kk++){
      int e = kk*32 + lk*8;
      bf16x8 bz[2], at[2];
      #pragma unroll
      for (int ni=0;ni<2;ni++){ int j = jq + ni*16 + lr; bz[ni] = *(const bf16x8*)&Ztl[j*64 + (e ^ ((j&7)<<3))]; }
      #pragma unroll
      for (int mi=0;mi<2;mi++){ int t = tq + mi*16 + lr; at[mi] = *(const bf16x8*)&Tbc[t*64 + (e ^ ((t&7)<<3))]; }
      #pragma unroll
      for (int mi=0;mi<2;mi++)
        #pragma unroll
        for (int ni=0;ni<2;ni++)
          uac[mi][ni] = mfma16(at[mi], bz[ni], uac[mi][ni]);
    }
    #pragma unroll
    for (int mi=0;mi<2;mi++)
      #pragma unroll
      for (int ni=0;ni<2;ni++)
        #pragma unroll
        for (int r=0;r<4;r++){
          int t = tq + mi*16 + lk*4 + r;
          int j = jq + ni*16 + lr;
          Utl[j*64 + (t ^ ((j&7)<<3))] = f2bf(uac[mi][ni][r]);
        }
    __syncthreads();

    f32x4 oac[2][2];
    #pragma unroll
    for (int i=0;i<2;i++)
      #pragma unroll
      for (int j2=0;j2<2;j2++) oac[i][j2] = (f32x4){0.f,0.f,0.f,0.f};
    #pragma unroll
    for (int kk=0;kk<4;kk++){
      int e = kk*32 + lk*8;
      bf16x8 bst[2], aq[2];
      #pragma unroll
      for (int ni=0;ni<2;ni++){ int j = jq + ni*16 + lr; bst[ni] = *(const bf16x8*)&Stl[j*128 + (e ^ ((j&7)<<3))]; }
      #pragma unroll
      for (int mi=0;mi<2;mi++){ int t = tq + mi*16 + lr; aq[mi]  = *(const bf16x8*)&Qc [t*128 + (e ^ ((t&7)<<3))]; }
      #pragma unroll
      for (int mi=0;mi<2;mi++)
        #pragma unroll
        for (int ni=0;ni<2;ni++)
          oac[mi][ni] = mfma16(aq[mi], bst[ni], oac[mi][ni]);
    }
    #pragma unroll
    for (int kk=0;kk<2;kk++){
      int e = kk*32 + lk*8;
      bf16x8 bu[2], am[2];
      #pragma unroll
      for (int ni=0;ni<2;ni++){ int j = jq + ni*16 + lr; bu[ni] = *(const bf16x8*)&Utl[j*64 + (e ^ ((j&7)<<3))]; }
      #pragma unroll
      for (int mi=0;mi<2;mi++){ int t = tq + mi*16 + lr; am[mi] = *(const bf16x8*)&Mc [t*64 + (e ^ ((t&7)<<3))]; }
      #pragma unroll
      for (int mi=0;mi<2;mi++)
        #pragma unroll
        for (int ni=0;ni<2;ni++)
          oac[mi][ni] = mfma16(am[mi], bu[ni], oac[mi][ni]);
    }
    #pragma unroll
    for (int mi=0;mi<2;mi++)
      #pragma unroll
      for (int ni=0;ni<2;ni++)
        #pragma unroll
        for (int r=0;r<4;r++){
          int t = tq + mi*16 + lk*4 + r;
          int j = jq + ni*16 + lr;
          obase[(size_t)(c*64 + t)*DK_ + j] = f2bf(oac[mi][ni][r]);
        }

    #pragma unroll
    for (int kk=0;kk<2;kk++){
      int e = kk*32 + lk*8;
      bf16x8 au[2], bk[4];
      #pragma unroll
      for (int mj=0;mj<2;mj++){ int j = jq + mj*16 + lr; au[mj] = *(const bf16x8*)&Utl[j*64 + (e ^ ((j&7)<<3))]; }
      #pragma unroll
      for (int nd=0;nd<4;nd++){ int d = dq + nd*16 + lr; bk[nd] = *(const bf16x8*)&Ktc[d*64 + (e ^ ((d&7)<<3))]; }
      #pragma unroll
      for (int mj=0;mj<2;mj++)
        #pragma unroll
        for (int nd=0;nd<4;nd++)
          Stf[mj][nd] = mfma16(au[mj], bk[nd], Stf[mj][nd]);
    }
    __syncthreads();
  }
}

__global__ __launch_bounds__(256) void k_norm(const ushort* __restrict__ OH, const float* __restrict__ gw,
                                              ushort* __restrict__ O2){
  const int blk = blockIdx.x;
  const int b = blk >> 12, l = blk & 4095;
  const int t = threadIdx.x;
  const int h = t >> 4, d0 = (t & 15) * 8;
  const ushort* ip = OH + ((size_t)(b*H_ + h)*L_ + l)*DK_ + d0;
  ushort4 a = *(const ushort4*)ip, c = *(const ushort4*)(ip+4);
  float x[8];
  x[0]=bf2f(a.x); x[1]=bf2f(a.y); x[2]=bf2f(a.z); x[3]=bf2f(a.w);
  x[4]=bf2f(c.x); x[5]=bf2f(c.y); x[6]=bf2f(c.z); x[7]=bf2f(c.w);
  float ss = 0.f;
  #pragma unroll
  for (int j=0;j<8;j++) ss += x[j]*x[j];
  #pragma unroll
  for (int m=1;m<16;m<<=1) ss += __shfl_xor(ss, m, 64);
  float sc = rsqrtf(ss * (1.f/128.f) + 1e-5f);
  ushort* opp = O2 + (size_t)blk*D_ + h*DK_ + d0;
  ushort4 o0, o1;
  o0.x=f2bf(x[0]*sc*gw[d0+0]); o0.y=f2bf(x[1]*sc*gw[d0+1]);
  o0.z=f2bf(x[2]*sc*gw[d0+2]); o0.w=f2bf(x[3]*sc*gw[d0+3]);
  o1.x=f2bf(x[4]*sc*gw[d0+4]); o1.y=f2bf(x[5]*sc*gw[d0+5]);
  o1.z=f2bf(x[6]*sc*gw[d0+6]); o1.w=f2bf(x[7]*sc*gw[d0+7]);
  *(ushort4*)opp = o0; *(ushort4*)(opp+4) = o1;
}

extern "C" void kernel_launch(void* const* d_in, const int* in_sizes, int n_in,
                              void* d_out, int out_size, void* d_ws, size_t ws_size,
                              hipStream_t stream) {
  (void)in_sizes; (void)n_in; (void)out_size; (void)ws_size;
  const float* hidden  = (const float*)d_in[0];
  const float* w_cattn = (const float*)d_in[1];
  const float* wq_conv = (const float*)d_in[2];
  const float* wk_conv = (const float*)d_in[3];
  const float* wv_conv = (const float*)d_in[4];
  const float* w_beta  = (const float*)d_in[5];
  const float* o_nw    = (const float*)d_in[6];
  const float* w_o     = (const float*)d_in[7];
  float* out = (float*)d_out;

  char* W = (char*)d_ws;                              // total 260,046,848 B (known-good size)
  ushort* A16   = (ushort*)(W);                       // 32MB ; -> OH after gemm1
  ushort* WcatT = (ushort*)(W + 33554432u);           // 24MB [6144][2048]; dead after gemm1
  ushort* WoT   = (ushort*)(W + 33554432u);           //  8MB (alias, written after gemm1)
  float*  BETA  = (float*) (W + 41943040u);           // 512KB (alias in dead WcatT region)
  ushort* QKV   = (ushort*)(W + 58720256u);           // 96MB; dead after convhead
  ushort* TB    = (ushort*)(W + 58720256u);           // 16MB (alias in dead QKV)
  ushort* MM    = (ushort*)(W + 75497472u);           // 16MB
  ushort* KT    = (ushort*)(W + 92274688u);           // 32MB
  ushort* O2    = (ushort*)(W + 125829120u);          // 32MB
  ushort* QH    = (ushort*)(W + 159383552u);          // 32MB
  ushort* KH    = (ushort*)(W + 192937984u);          // 32MB
  ushort* VH    = (ushort*)(W + 226492416u);          // 32MB -> end 260,046,848
  ushort* OH = A16;

  k_cast<<<4096, 256, 0, stream>>>(hidden, A16, (BL_*D_)/4);
  k_transpose_cast<<<dim3(ND3/32, D_/32), dim3(32,8), 0, stream>>>(w_cattn, WcatT, D_, ND3);
  k_gemm_bt<1><<<dim3(ND3/128, BL_/128), 256, 0, stream>>>(A16, WcatT, QKV, BL_, ND3, D_);
  k_transpose_cast<<<dim3(D_/32, D_/32), dim3(32,8), 0, stream>>>(w_o, WoT, D_, D_);
  k_beta<<<BL_, 256, 0, stream>>>(hidden, w_beta, BETA);
  k_convhead<<<BL_, 256, 0, stream>>>(QKV, wq_conv, wk_conv, wv_conv, QH, KH, VH);
  k_prep<<<2048, 64, 0, stream>>>(QH, KH, BETA, TB, MM, KT);
  k_chunkrec<<<64, 256, 0, stream>>>(QH, KH, VH, TB, MM, KT, OH);
  k_norm<<<BL_, 256, 0, stream>>>(OH, o_nw, O2);
  k_gemm_bt<0><<<dim3(D_/128, BL_/128), 256, 0, stream>>>(O2, WoT, out, BL_, D_, D_);
}

// Round 4
// 915.743 us; speedup vs baseline: 6.7468x; 1.4896x over previous
//
#include <hip/hip_runtime.h>
#include <stdint.h>

#define B_   2
#define L_   4096
#define D_   2048
#define H_   16
#define DK_  128
#define ND3  6144
#define BL_  8192

typedef __bf16 bf16x8 __attribute__((ext_vector_type(8)));
typedef float  f32x4  __attribute__((ext_vector_type(4)));

__device__ __forceinline__ float bf2f(ushort u){ return __uint_as_float(((unsigned)u)<<16); }
__device__ __forceinline__ ushort f2bf(float f){
  unsigned u = __float_as_uint(f);
  unsigned r = u + 0x7FFFu + ((u>>16)&1u);
  return (ushort)(r>>16);
}
__device__ __forceinline__ f32x4 mfma16(bf16x8 a, bf16x8 b, f32x4 c){
  return __builtin_amdgcn_mfma_f32_16x16x32_bf16(a, b, c, 0, 0, 0);
}

__global__ __launch_bounds__(256) void k_cast(const float* __restrict__ x, ushort* __restrict__ y, int n4){
  int i = blockIdx.x*blockDim.x + threadIdx.x;
  int stride = gridDim.x*blockDim.x;
  for (; i < n4; i += stride){
    float4 v = ((const float4*)x)[i];
    ushort4 o; o.x=f2bf(v.x); o.y=f2bf(v.y); o.z=f2bf(v.z); o.w=f2bf(v.w);
    ((ushort4*)y)[i] = o;
  }
}

__global__ __launch_bounds__(256) void k_transpose_cast(const float* __restrict__ in, ushort* __restrict__ out,
                                                        int R, int C){
  __shared__ float tile[32][33];
  int c0 = blockIdx.x*32, r0 = blockIdx.y*32;
  int tx = threadIdx.x, ty = threadIdx.y;
  #pragma unroll
  for (int i=0;i<32;i+=8) tile[ty+i][tx] = in[(size_t)(r0+ty+i)*C + (c0+tx)];
  __syncthreads();
  #pragma unroll
  for (int i=0;i<32;i+=8) out[(size_t)(c0+ty+i)*R + (r0+tx)] = f2bf(tile[tx][ty+i]);
}

template<int OUT_BF16>
__global__ __launch_bounds__(256) void k_gemm_bt(const ushort* __restrict__ A, const ushort* __restrict__ Bt,
                                                 void* __restrict__ Cv, int M, int N, int K){
  __shared__ ushort As[128*32];
  __shared__ ushort Bs[128*32];
  const int tid = threadIdx.x, lane = tid & 63, w = tid >> 6;
  // XCD-aware bijective swizzle (T1); valid when nwg%8==0, guarded otherwise
  int nwg = gridDim.x*gridDim.y;
  int id  = blockIdx.y*gridDim.x + blockIdx.x;
  int sw  = ((nwg & 7) == 0) ? ((id & 7)*(nwg >> 3) + (id >> 3)) : id;
  const int bx = sw % gridDim.x, by = sw / gridDim.x;
  const int m0 = by*128, n0 = bx*128;
  const int wr = w >> 1, wc = w & 1;
  f32x4 acc[4][4];
  #pragma unroll
  for (int i=0;i<4;i++)
    #pragma unroll
    for (int j=0;j<4;j++) acc[i][j] = (f32x4){0.f,0.f,0.f,0.f};
  const int lr  = lane & 15;
  const int lk8 = (lane >> 4) * 8;
  for (int k0 = 0; k0 < K; k0 += 32){
    #pragma unroll
    for (int c=0;c<2;c++){
      int chunk = w*2 + c;
      int elem  = chunk*512 + lane*8;
      int row   = elem >> 5, kk = elem & 31;
      __builtin_amdgcn_global_load_lds(
        (const __attribute__((address_space(1))) void*)(A + (size_t)(m0+row)*K + k0 + kk),
        (__attribute__((address_space(3))) void*)(As + chunk*512), 16, 0, 0);
      __builtin_amdgcn_global_load_lds(
        (const __attribute__((address_space(1))) void*)(Bt + (size_t)(n0+row)*K + k0 + kk),
        (__attribute__((address_space(3))) void*)(Bs + chunk*512), 16, 0, 0);
    }
    __syncthreads();
    bf16x8 af[4], bfr[4];
    #pragma unroll
    for (int m=0;m<4;m++) af[m]  = *(const bf16x8*)&As[(wr*64 + m*16 + lr)*32 + lk8];
    #pragma unroll
    for (int n=0;n<4;n++) bfr[n] = *(const bf16x8*)&Bs[(wc*64 + n*16 + lr)*32 + lk8];
    #pragma unroll
    for (int m=0;m<4;m++)
      #pragma unroll
      for (int n=0;n<4;n++)
        acc[m][n] = __builtin_amdgcn_mfma_f32_16x16x32_bf16(af[m], bfr[n], acc[m][n], 0,0,0);
    __syncthreads();
  }
  const int rbase = m0 + wr*64 + (lane>>4)*4;
  const int cbase = n0 + wc*64 + (lane&15);
  #pragma unroll
  for (int m=0;m<4;m++)
    #pragma unroll
    for (int n=0;n<4;n++)
      #pragma unroll
      for (int r=0;r<4;r++){
        int row = rbase + m*16 + r;
        int col = cbase + n*16;
        float v = acc[m][n][r];
        if (OUT_BF16) ((ushort*)Cv)[(size_t)row*N + col] = f2bf(v);
        else          ((float*) Cv)[(size_t)row*N + col] = v;
      }
}

// ---------------- wbT[h][d] bf16 <- wb[d][h] f32 ----------------
__global__ __launch_bounds__(256) void k_wbt(const float* __restrict__ wb, ushort* __restrict__ wbT){
  int d = blockIdx.x*256 + threadIdx.x;   // grid 8 -> d in [0,2048)
  #pragma unroll
  for (int h=0;h<16;h++) wbT[(size_t)h*2048 + d] = f2bf(wb[(size_t)d*16 + h]);
}

// ---------------- beta = sigmoid(A16 @ wbT^T) via MFMA; out [b][h][l] f32 ----------------
__global__ __launch_bounds__(64) void k_beta2(const ushort* __restrict__ A16, const ushort* __restrict__ wbT,
                                              float* __restrict__ beta){
  const int rt = blockIdx.x;        // 0..511, 16 rows each
  const int lane = threadIdx.x;
  const int lr = lane & 15, lk8 = (lane>>4)*8;
  const int r0 = rt*16;
  f32x4 acc = (f32x4){0.f,0.f,0.f,0.f};
  for (int k0=0; k0<2048; k0+=32){
    bf16x8 a = *(const bf16x8*)&A16[(size_t)(r0+lr)*2048 + k0 + lk8];
    bf16x8 b = *(const bf16x8*)&wbT[(size_t)lr*2048 + k0 + lk8];
    acc = mfma16(a, b, acc);
  }
  const int h = lane & 15;
  const int rbase = r0 + (lane>>4)*4;
  #pragma unroll
  for (int r=0;r<4;r++){
    int row = rbase + r;
    int b = row >> 12, l = row & 4095;
    float sg = 1.f/(1.f + __expf(-acc[r]));
    beta[((size_t)(b*H_ + h))*L_ + l] = sg;
  }
}

__global__ __launch_bounds__(256) void k_convhead(const ushort* __restrict__ qkv,
      const float* __restrict__ wq, const float* __restrict__ wk, const float* __restrict__ wv,
      ushort* __restrict__ QH, ushort* __restrict__ KH, ushort* __restrict__ VH){
  const int blk = blockIdx.x;
  const int b = blk >> 12, l = blk & 4095;
  const int t = threadIdx.x;
  const int h = t >> 4, d0 = (t & 15) * 8;
  const int ch = h*DK_ + d0;
  const float* wcs[3] = {wq, wk, wv};
  ushort* outs[3] = {QH, KH, VH};
  #pragma unroll
  for (int part=0; part<3; part++){
    float x[4][8];
    #pragma unroll
    for (int i=0;i<4;i++){
      int lrr = l - 3 + i;
      if (lrr >= 0){
        const ushort* p = qkv + ((size_t)(b*L_ + lrr))*ND3 + part*D_ + ch;
        ushort4 a = *(const ushort4*)p, c = *(const ushort4*)(p+4);
        x[i][0]=bf2f(a.x); x[i][1]=bf2f(a.y); x[i][2]=bf2f(a.z); x[i][3]=bf2f(a.w);
        x[i][4]=bf2f(c.x); x[i][5]=bf2f(c.y); x[i][6]=bf2f(c.z); x[i][7]=bf2f(c.w);
      } else {
        #pragma unroll
        for (int j=0;j<8;j++) x[i][j] = 0.f;
      }
    }
    const float* wc = wcs[part];
    float y[8]; float ss = 0.f;
    #pragma unroll
    for (int j=0;j<8;j++){
      float4 w4 = *(const float4*)&wc[(ch + j)*4];
      float yy = x[0][j]*w4.x + x[1][j]*w4.y + x[2][j]*w4.z + x[3][j]*w4.w;
      yy = yy / (1.f + __expf(-yy));
      y[j] = yy; ss += yy*yy;
    }
    if (part < 2){
      #pragma unroll
      for (int m=1;m<16;m<<=1) ss += __shfl_xor(ss, m, 64);
      float sc = rsqrtf(ss + 1e-12f);
      #pragma unroll
      for (int j=0;j<8;j++) y[j] *= sc;
    }
    ushort* op = outs[part] + ((size_t)(b*H_ + h)*L_ + l)*DK_ + d0;
    ushort4 o0, o1;
    o0.x=f2bf(y[0]); o0.y=f2bf(y[1]); o0.z=f2bf(y[2]); o0.w=f2bf(y[3]);
    o1.x=f2bf(y[4]); o1.y=f2bf(y[5]); o1.z=f2bf(y[6]); o1.w=f2bf(y[7]);
    *(ushort4*)op = o0; *(ushort4*)(op+4) = o1;
  }
}

// ---------------- phase 1: per-chunk Tb, M, Kt ----------------
__global__ __launch_bounds__(64) void k_prep(const ushort* __restrict__ QH, const ushort* __restrict__ KH,
      const float* __restrict__ BETA, ushort* __restrict__ TB, ushort* __restrict__ MM,
      ushort* __restrict__ KT){
  const int bid = blockIdx.x, bh = bid>>6, c = bid&63;
  const int lane = threadIdx.x;
  __shared__ ushort Ks[64][136];
  __shared__ ushort Qs[64][136];
  __shared__ float As[64][64];
  __shared__ float Ts[64][64];
  __shared__ float bs[64];
  const ushort* kg = KH + ((size_t)bh*L_ + c*64)*DK_;
  const ushort* qg = QH + ((size_t)bh*L_ + c*64)*DK_;
  {
    const uint4* ks4 = (const uint4*)(kg + (size_t)lane*DK_);
    const uint4* qs4 = (const uint4*)(qg + (size_t)lane*DK_);
    uint4* kd = (uint4*)&Ks[lane][0];
    uint4* qd = (uint4*)&Qs[lane][0];
    #pragma unroll
    for (int i=0;i<16;i++){ kd[i] = ks4[i]; qd[i] = qs4[i]; }
    bs[lane] = BETA[(size_t)bh*L_ + c*64 + lane];
  }
  __syncthreads();
  const int lr = lane&15, lk = lane>>4;
  {
    f32x4 gac[4][4];
    #pragma unroll
    for (int i=0;i<4;i++)
      #pragma unroll
      for (int j=0;j<4;j++) gac[i][j] = (f32x4){0.f,0.f,0.f,0.f};
    #pragma unroll
    for (int kk=0;kk<4;kk++){
      bf16x8 fr[4];
      #pragma unroll
      for (int i=0;i<4;i++) fr[i] = *(const bf16x8*)&Ks[i*16+lr][kk*32 + lk*8];
      #pragma unroll
      for (int mi=0;mi<4;mi++)
        #pragma unroll
        for (int ni=0;ni<4;ni++)
          gac[mi][ni] = mfma16(fr[mi], fr[ni], gac[mi][ni]);
    }
    #pragma unroll
    for (int mi=0;mi<4;mi++)
      #pragma unroll
      for (int ni=0;ni<4;ni++)
        #pragma unroll
        for (int r=0;r<4;r++){
          int t = mi*16 + lk*4 + r, s = ni*16 + lr;
          As[t][s] = (s < t) ? (bs[t] * gac[mi][ni][r]) : 0.f;
        }
  }
  {
    f32x4 mac[4][4];
    #pragma unroll
    for (int i=0;i<4;i++)
      #pragma unroll
      for (int j=0;j<4;j++) mac[i][j] = (f32x4){0.f,0.f,0.f,0.f};
    #pragma unroll
    for (int kk=0;kk<4;kk++){
      bf16x8 frq[4], frk[4];
      #pragma unroll
      for (int i=0;i<4;i++){
        frq[i] = *(const bf16x8*)&Qs[i*16+lr][kk*32 + lk*8];
        frk[i] = *(const bf16x8*)&Ks[i*16+lr][kk*32 + lk*8];
      }
      #pragma unroll
      for (int mi=0;mi<4;mi++)
        #pragma unroll
        for (int ni=0;ni<4;ni++)
          mac[mi][ni] = mfma16(frq[mi], frk[ni], mac[mi][ni]);
    }
    #pragma unroll
    for (int mi=0;mi<4;mi++)
      #pragma unroll
      for (int ni=0;ni<4;ni++)
        #pragma unroll
        for (int r=0;r<4;r++){
          int t = mi*16 + lk*4 + r, s = ni*16 + lr;
          float v = (s <= t) ? mac[mi][ni][r] : 0.f;
          MM[(size_t)bid*4096 + t*64 + s] = f2bf(v);
        }
  }
  __syncthreads();
  for (int t=0;t<64;t++){
    float a = (t==lane) ? 1.f : 0.f;
    for (int s=0;s<t;s++) a -= As[t][s] * Ts[s][lane];
    Ts[t][lane] = a;
  }
  {
    float bc = bs[lane];
    for (int t=0;t<64;t++)
      TB[(size_t)bid*4096 + t*64 + lane] = f2bf(Ts[t][lane] * bc);
  }
  for (int d2=0; d2<64; d2++){
    unsigned uu = *(const unsigned*)&Ks[lane][2*d2];
    KT[(size_t)bid*8192 + (size_t)(2*d2)*64 + lane]   = (ushort)(uu & 0xffffu);
    KT[(size_t)bid*8192 + (size_t)(2*d2+1)*64 + lane] = (ushort)(uu >> 16);
  }
}

template<int LRB, int GRB, int NB>
__device__ __forceinline__ void stage_swz(const ushort* __restrict__ g, ushort* l,
                                          int colOff, int w, int lane){
  for (int idx = w; idx < NB/1024; idx += 4){
    int off = idx*1024 + lane*16;
    int row = off / LRB;
    int inner = off & (LRB-1);
    int src = row*GRB + colOff + (inner ^ ((row&7)<<4));
    __builtin_amdgcn_global_load_lds(
      (const __attribute__((address_space(1))) void*)((const char*)g + src),
      (__attribute__((address_space(3))) void*)((char*)l + idx*1024), 16, 0, 0);
  }
}

__global__ __launch_bounds__(256) void k_chunkrec(const ushort* __restrict__ QH, const ushort* __restrict__ KH,
      const ushort* __restrict__ VH, const ushort* __restrict__ TB, const ushort* __restrict__ MM,
      const ushort* __restrict__ KT, ushort* __restrict__ OH){
  const int bid = blockIdx.x, bh = bid>>1, vh = bid&1;
  const int tid = threadIdx.x, lane = tid&63, w = tid>>6;
  __shared__ ushort Kc[64*128], Qc[64*128], Ktc[128*64], Tbc[64*64], Mc[64*64], Vc[64*64];
  __shared__ ushort Stl[64*128], Ztl[64*64], Utl[64*64];
  const int lr = lane&15, lk = lane>>4;
  const int tq = (w>>1)*32, jq = (w&1)*32;
  const int dq = (w>>1)*64;

  f32x4 Stf[2][4];
  #pragma unroll
  for (int a=0;a<2;a++)
    #pragma unroll
    for (int b=0;b<4;b++) Stf[a][b] = (f32x4){0.f,0.f,0.f,0.f};

  const ushort* kbase  = KH + ((size_t)bh*L_)*DK_;
  const ushort* qbase  = QH + ((size_t)bh*L_)*DK_;
  const ushort* vbase  = VH + ((size_t)bh*L_)*DK_;
  const ushort* tbase  = TB + ((size_t)bh*64)*4096;
  const ushort* mbase  = MM + ((size_t)bh*64)*4096;
  const ushort* ktbase = KT + ((size_t)bh*64)*8192;
  ushort* obase = OH + ((size_t)bh*L_)*DK_ + vh*64;

  for (int c=0; c<64; c++){
    stage_swz<256,256,16384>(kbase  + (size_t)c*8192, Kc,  0, w, lane);
    stage_swz<256,256,16384>(qbase  + (size_t)c*8192, Qc,  0, w, lane);
    stage_swz<128,128,16384>(ktbase + (size_t)c*8192, Ktc, 0, w, lane);
    stage_swz<128,128, 8192>(tbase  + (size_t)c*4096, Tbc, 0, w, lane);
    stage_swz<128,128, 8192>(mbase  + (size_t)c*4096, Mc,  0, w, lane);
    stage_swz<128,256, 8192>(vbase  + (size_t)c*8192, Vc,  vh*128, w, lane);
    #pragma unroll
    for (int mj=0;mj<2;mj++)
      #pragma unroll
      for (int nd=0;nd<4;nd++)
        #pragma unroll
        for (int r=0;r<4;r++){
          int j = jq + mj*16 + lk*4 + r;
          int d = dq + nd*16 + lr;
          Stl[j*128 + (d ^ ((j&7)<<3))] = f2bf(Stf[mj][nd][r]);
        }
    __syncthreads();

    f32x4 xac[2][2];
    #pragma unroll
    for (int i=0;i<2;i++)
      #pragma unroll
      for (int j2=0;j2<2;j2++) xac[i][j2] = (f32x4){0.f,0.f,0.f,0.f};
    #pragma unroll
    for (int kk=0;kk<4;kk++){
      int e = kk*32 + lk*8;
      bf16x8 bst[2], ak[2];
      #pragma unroll
      for (int ni=0;ni<2;ni++){ int j = jq + ni*16 + lr; bst[ni] = *(const bf16x8*)&Stl[j*128 + (e ^ ((j&7)<<3))]; }
      #pragma unroll
      for (int mi=0;mi<2;mi++){ int t = tq + mi*16 + lr; ak[mi]  = *(const bf16x8*)&Kc [t*128 + (e ^ ((t&7)<<3))]; }
      #pragma unroll
      for (int mi=0;mi<2;mi++)
        #pragma unroll
        for (int ni=0;ni<2;ni++)
          xac[mi][ni] = mfma16(ak[mi], bst[ni], xac[mi][ni]);
    }
    #pragma unroll
    for (int mi=0;mi<2;mi++)
      #pragma unroll
      for (int ni=0;ni<2;ni++)
        #pragma unroll
        for (int r=0;r<4;r++){
          int t = tq + mi*16 + lk*4 + r;
          int j = jq + ni*16 + lr;
          float v = bf2f(Vc[t*64 + (j ^ ((t&7)<<3))]);
          Ztl[j*64 + (t ^ ((j&7)<<3))] = f2bf(v - xac[mi][ni][r]);
        }
    __syncthreads();

    f32x4 uac[2][2];
    #pragma unroll
    for (int i=0;i<2;i++)
      #pragma unroll
      for (int j2=0;j2<2;j2++) uac[i][j2] = (f32x4){0.f,0.f,0.f,0.f};
    #pragma unroll
    for (int kk=0;kk<2;kk++){
      int e = kk*32 + lk*8;
      bf16x8 bz[2], at[2];
      #pragma unroll
      for (int ni=0;ni<2;ni++){ int j = jq + ni*16 + lr; bz[ni] = *(const bf16x8*)&Ztl[j*64 + (e ^ ((j&7)<<3))]; }
      #pragma unroll
      for (int mi=0;mi<2;mi++){ int t = tq + mi*16 + lr; at[mi] = *(const bf16x8*)&Tbc[t*64 + (e ^ ((t&7)<<3))]; }
      #pragma unroll
      for (int mi=0;mi<2;mi++)
        #pragma unroll
        for (int ni=0;ni<2;ni++)
          uac[mi][ni] = mfma16(at[mi], bz[ni], uac[mi][ni]);
    }
    #pragma unroll
    for (int mi=0;mi<2;mi++)
      #pragma unroll
      for (int ni=0;ni<2;ni++)
        #pragma unroll
        for (int r=0;r<4;r++){
          int t = tq + mi*16 + lk*4 + r;
          int j = jq + ni*16 + lr;
          Utl[j*64 + (t ^ ((j&7)<<3))] = f2bf(uac[mi][ni][r]);
        }
    __syncthreads();

    f32x4 oac[2][2];
    #pragma unroll
    for (int i=0;i<2;i++)
      #pragma unroll
      for (int j2=0;j2<2;j2++) oac[i][j2] = (f32x4){0.f,0.f,0.f,0.f};
    #pragma unroll
    for (int kk=0;kk<4;kk++){
      int e = kk*32 + lk*8;
      bf16x8 bst[2], aq[2];
      #pragma unroll
      for (int ni=0;ni<2;ni++){ int j = jq + ni*16 + lr; bst[ni] = *(const bf16x8*)&Stl[j*128 + (e ^ ((j&7)<<3))]; }
      #pragma unroll
      for (int mi=0;mi<2;mi++){ int t = tq + mi*16 + lr; aq[mi]  = *(const bf16x8*)&Qc [t*128 + (e ^ ((t&7)<<3))]; }
      #pragma unroll
      for (int mi=0;mi<2;mi++)
        #pragma unroll
        for (int ni=0;ni<2;ni++)
          oac[mi][ni] = mfma16(aq[mi], bst[ni], oac[mi][ni]);
    }
    #pragma unroll
    for (int kk=0;kk<2;kk++){
      int e = kk*32 + lk*8;
      bf16x8 bu[2], am[2];
      #pragma unroll
      for (int ni=0;ni<2;ni++){ int j = jq + ni*16 + lr; bu[ni] = *(const bf16x8*)&Utl[j*64 + (e ^ ((j&7)<<3))]; }
      #pragma unroll
      for (int mi=0;mi<2;mi++){ int t = tq + mi*16 + lr; am[mi] = *(const bf16x8*)&Mc [t*64 + (e ^ ((t&7)<<3))]; }
      #pragma unroll
      for (int mi=0;mi<2;mi++)
        #pragma unroll
        for (int ni=0;ni<2;ni++)
          oac[mi][ni] = mfma16(am[mi], bu[ni], oac[mi][ni]);
    }
    #pragma unroll
    for (int mi=0;mi<2;mi++)
      #pragma unroll
      for (int ni=0;ni<2;ni++)
        #pragma unroll
        for (int r=0;r<4;r++){
          int t = tq + mi*16 + lk*4 + r;
          int j = jq + ni*16 + lr;
          obase[(size_t)(c*64 + t)*DK_ + j] = f2bf(oac[mi][ni][r]);
        }

    #pragma unroll
    for (int kk=0;kk<2;kk++){
      int e = kk*32 + lk*8;
      bf16x8 au[2], bk[4];
      #pragma unroll
      for (int mj=0;mj<2;mj++){ int j = jq + mj*16 + lr; au[mj] = *(const bf16x8*)&Utl[j*64 + (e ^ ((j&7)<<3))]; }
      #pragma unroll
      for (int nd=0;nd<4;nd++){ int d = dq + nd*16 + lr; bk[nd] = *(const bf16x8*)&Ktc[d*64 + (e ^ ((d&7)<<3))]; }
      #pragma unroll
      for (int mj=0;mj<2;mj++)
        #pragma unroll
        for (int nd=0;nd<4;nd++)
          Stf[mj][nd] = mfma16(au[mj], bk[nd], Stf[mj][nd]);
    }
    __syncthreads();
  }
}

__global__ __launch_bounds__(256) void k_norm(const ushort* __restrict__ OH, const float* __restrict__ gw,
                                              ushort* __restrict__ O2){
  const int blk = blockIdx.x;
  const int b = blk >> 12, l = blk & 4095;
  const int t = threadIdx.x;
  const int h = t >> 4, d0 = (t & 15) * 8;
  const ushort* ip = OH + ((size_t)(b*H_ + h)*L_ + l)*DK_ + d0;
  ushort4 a = *(const ushort4*)ip, c = *(const ushort4*)(ip+4);
  float x[8];
  x[0]=bf2f(a.x); x[1]=bf2f(a.y); x[2]=bf2f(a.z); x[3]=bf2f(a.w);
  x[4]=bf2f(c.x); x[5]=bf2f(c.y); x[6]=bf2f(c.z); x[7]=bf2f(c.w);
  float ss = 0.f;
  #pragma unroll
  for (int j=0;j<8;j++) ss += x[j]*x[j];
  #pragma unroll
  for (int m=1;m<16;m<<=1) ss += __shfl_xor(ss, m, 64);
  float sc = rsqrtf(ss * (1.f/128.f) + 1e-5f);
  ushort* opp = O2 + (size_t)blk*D_ + h*DK_ + d0;
  ushort4 o0, o1;
  o0.x=f2bf(x[0]*sc*gw[d0+0]); o0.y=f2bf(x[1]*sc*gw[d0+1]);
  o0.z=f2bf(x[2]*sc*gw[d0+2]); o0.w=f2bf(x[3]*sc*gw[d0+3]);
  o1.x=f2bf(x[4]*sc*gw[d0+4]); o1.y=f2bf(x[5]*sc*gw[d0+5]);
  o1.z=f2bf(x[6]*sc*gw[d0+6]); o1.w=f2bf(x[7]*sc*gw[d0+7]);
  *(ushort4*)opp = o0; *(ushort4*)(opp+4) = o1;
}

extern "C" void kernel_launch(void* const* d_in, const int* in_sizes, int n_in,
                              void* d_out, int out_size, void* d_ws, size_t ws_size,
                              hipStream_t stream) {
  (void)in_sizes; (void)n_in; (void)out_size; (void)ws_size;
  const float* hidden  = (const float*)d_in[0];
  const float* w_cattn = (const float*)d_in[1];
  const float* wq_conv = (const float*)d_in[2];
  const float* wk_conv = (const float*)d_in[3];
  const float* wv_conv = (const float*)d_in[4];
  const float* w_beta  = (const float*)d_in[5];
  const float* o_nw    = (const float*)d_in[6];
  const float* w_o     = (const float*)d_in[7];
  float* out = (float*)d_out;

  char* W = (char*)d_ws;                              // total 260,046,848 B (known-good size)
  ushort* A16   = (ushort*)(W);                       // 32MB ; -> OH after gemm1
  ushort* WcatT = (ushort*)(W + 33554432u);           // 24MB [6144][2048]; dead after gemm1
  ushort* WoT   = (ushort*)(W + 33554432u);           //  8MB (alias, written after gemm1)
  float*  BETA  = (float*) (W + 41943040u);           // 512KB (alias in dead WcatT region)
  ushort* WBT   = (ushort*)(W + 42467328u);           // 64KB  (alias in dead WcatT region)
  ushort* QKV   = (ushort*)(W + 58720256u);           // 96MB; dead after convhead
  ushort* TB    = (ushort*)(W + 58720256u);           // 16MB (alias in dead QKV)
  ushort* MM    = (ushort*)(W + 75497472u);           // 16MB
  ushort* KT    = (ushort*)(W + 92274688u);           // 32MB
  ushort* O2    = (ushort*)(W + 125829120u);          // 32MB
  ushort* QH    = (ushort*)(W + 159383552u);          // 32MB
  ushort* KH    = (ushort*)(W + 192937984u);          // 32MB
  ushort* VH    = (ushort*)(W + 226492416u);          // 32MB -> end 260,046,848
  ushort* OH = A16;

  k_cast<<<4096, 256, 0, stream>>>(hidden, A16, (BL_*D_)/4);
  k_transpose_cast<<<dim3(ND3/32, D_/32), dim3(32,8), 0, stream>>>(w_cattn, WcatT, D_, ND3);
  k_gemm_bt<1><<<dim3(ND3/128, BL_/128), 256, 0, stream>>>(A16, WcatT, QKV, BL_, ND3, D_);
  // WcatT region dead from here on
  k_transpose_cast<<<dim3(D_/32, D_/32), dim3(32,8), 0, stream>>>(w_o, WoT, D_, D_);
  k_wbt<<<8, 256, 0, stream>>>(w_beta, WBT);
  k_beta2<<<512, 64, 0, stream>>>(A16, WBT, BETA);
  k_convhead<<<BL_, 256, 0, stream>>>(QKV, wq_conv, wk_conv, wv_conv, QH, KH, VH);
  k_prep<<<2048, 64, 0, stream>>>(QH, KH, BETA, TB, MM, KT);
  k_chunkrec<<<64, 256, 0, stream>>>(QH, KH, VH, TB, MM, KT, OH);
  k_norm<<<BL_, 256, 0, stream>>>(OH, o_nw, O2);
  k_gemm_bt<0><<<dim3(D_/128, BL_/128), 256, 0, stream>>>(O2, WoT, out, BL_, D_, D_);
}

// Round 6
// 821.634 us; speedup vs baseline: 7.5196x; 1.1145x over previous
//
#include <hip/hip_runtime.h>
#include <stdint.h>

#define B_   2
#define L_   4096
#define D_   2048
#define H_   16
#define DK_  128
#define ND3  6144
#define BL_  8192

typedef __bf16 bf16x8 __attribute__((ext_vector_type(8)));
typedef float  f32x4  __attribute__((ext_vector_type(4)));

__device__ __forceinline__ float bf2f(ushort u){ return __uint_as_float(((unsigned)u)<<16); }
__device__ __forceinline__ ushort f2bf(float f){
  unsigned u = __float_as_uint(f);
  unsigned r = u + 0x7FFFu + ((u>>16)&1u);
  return (ushort)(r>>16);
}
__device__ __forceinline__ f32x4 mfma16(bf16x8 a, bf16x8 b, f32x4 c){
  return __builtin_amdgcn_mfma_f32_16x16x32_bf16(a, b, c, 0, 0, 0);
}

__global__ __launch_bounds__(256) void k_cast(const float* __restrict__ x, ushort* __restrict__ y, int n4){
  int i = blockIdx.x*blockDim.x + threadIdx.x;
  int stride = gridDim.x*blockDim.x;
  for (; i < n4; i += stride){
    float4 v = ((const float4*)x)[i];
    ushort4 o; o.x=f2bf(v.x); o.y=f2bf(v.y); o.z=f2bf(v.z); o.w=f2bf(v.w);
    ((ushort4*)y)[i] = o;
  }
}

__global__ __launch_bounds__(256) void k_transpose_cast(const float* __restrict__ in, ushort* __restrict__ out,
                                                        int R, int C){
  __shared__ float tile[32][33];
  int c0 = blockIdx.x*32, r0 = blockIdx.y*32;
  int tx = threadIdx.x, ty = threadIdx.y;
  #pragma unroll
  for (int i=0;i<32;i+=8) tile[ty+i][tx] = in[(size_t)(r0+ty+i)*C + (c0+tx)];
  __syncthreads();
  #pragma unroll
  for (int i=0;i<32;i+=8) out[(size_t)(c0+ty+i)*R + (r0+tx)] = f2bf(tile[tx][ty+i]);
}

// ============ 256x256 K-sliced counted-vmcnt GEMM: C = A[M][K] * Bt[N][K]^T ============
// 8 waves (2M x 4N), BK=64 split into 2 K-slices of 32. Phase (tau,s): compute slice s of
// tile tau from buf[tau&1]; stage slice s of tile tau+1 into buf[tau&1 ^ 1].
// Per phase: 12 ds_read_b128 + 4 global_load_lds + 32 MFMA; vmcnt(4)+s_barrier per phase.
// LDS chunk layout: chunk(row,hi) = (row>>4)*64 + hi*16 + (row&15)  -> fragment reads are
// 64 lanes x consecutive 16B (conflict-free); stage pre-permutes the GLOBAL source.
template<int OUT_BF16>
__global__ __launch_bounds__(512, 1) void k_gemmks(const ushort* __restrict__ A, const ushort* __restrict__ Bt,
                                                   void* __restrict__ Cv, int M, int N, int K){
  __shared__ ushort LDSB[65536];   // 128 KB: buf(2) x slice(2) x [A 16KB | B 16KB]
  char* lds = (char*)LDSB;
  const int tid = threadIdx.x, lane = tid & 63, w = tid >> 6;
  const int wm = w >> 2, wn = w & 3;
  int nwg = gridDim.x*gridDim.y;
  int id  = blockIdx.y*gridDim.x + blockIdx.x;
  int sw  = ((nwg & 7) == 0) ? ((id & 7)*(nwg >> 3) + (id >> 3)) : id;
  const int bx = sw % gridDim.x, by = sw / gridDim.x;
  const int m0 = by*256, n0 = bx*256;
  const int NT = K >> 6;
  const size_t rowb = (size_t)K*2;

  f32x4 acc[8][4];
  #pragma unroll
  for (int i=0;i<8;i++)
    #pragma unroll
    for (int j=0;j<4;j++) acc[i][j] = (f32x4){0.f,0.f,0.f,0.f};

  // staging chunk->global mapping (thread handles chunks tid and tid+512 of each 1024-chunk panel)
  const int c0 = tid, c1 = tid + 512;
  const int r0c = ((c0>>6)<<4) + (c0&15), h0 = (c0>>4)&3;
  const int r1c = ((c1>>6)<<4) + (c1&15), h1 = (c1>>4)&3;
  const char* gA = (const char*)A  + (size_t)m0*rowb;
  const char* gB = (const char*)Bt + (size_t)n0*rowb;

  auto stage = [&](int tile, int s, int nb){
    const char* ga = gA + (size_t)tile*128 + s*64;   // col offset bytes
    const char* gb = gB + (size_t)tile*128 + s*64;
    char* la = lds + nb*65536 + s*32768;
    char* lb = la + 16384;
    __builtin_amdgcn_global_load_lds((const __attribute__((address_space(1))) void*)(ga + (size_t)r0c*rowb + h0*16),
                                     (__attribute__((address_space(3))) void*)(la + c0*16), 16, 0, 0);
    __builtin_amdgcn_global_load_lds((const __attribute__((address_space(1))) void*)(ga + (size_t)r1c*rowb + h1*16),
                                     (__attribute__((address_space(3))) void*)(la + c1*16), 16, 0, 0);
    __builtin_amdgcn_global_load_lds((const __attribute__((address_space(1))) void*)(gb + (size_t)r0c*rowb + h0*16),
                                     (__attribute__((address_space(3))) void*)(lb + c0*16), 16, 0, 0);
    __builtin_amdgcn_global_load_lds((const __attribute__((address_space(1))) void*)(gb + (size_t)r1c*rowb + h1*16),
                                     (__attribute__((address_space(3))) void*)(lb + c1*16), 16, 0, 0);
  };

  // prologue: tile0 both slices -> buf0; full drain once (cold start)
  stage(0, 0, 0); stage(0, 1, 0);
  __builtin_amdgcn_sched_barrier(0);
  asm volatile("s_waitcnt vmcnt(0)" ::: "memory");
  __builtin_amdgcn_s_barrier();
  __builtin_amdgcn_sched_barrier(0);

  for (int tau = 0; tau < NT; ++tau){
    const int cb = tau & 1, nb = cb ^ 1;
    const int st = (tau+1 < NT) ? tau+1 : NT-1;   // tail: dummy re-stage (never read)
    #pragma unroll
    for (int s = 0; s < 2; ++s){
      const char* base = lds + cb*65536 + s*32768;
      bf16x8 af[8], bfr[4];
      #pragma unroll
      for (int i=0;i<8;i++) af[i]  = *(const bf16x8*)(base + (wm*128 + i*16)*64 + lane*16);
      #pragma unroll
      for (int j=0;j<4;j++) bfr[j] = *(const bf16x8*)(base + 16384 + (wn*64 + j*16)*64 + lane*16);
      stage(st, s, nb);
      __builtin_amdgcn_s_setprio(1);
      #pragma unroll
      for (int i=0;i<8;i++)
        #pragma unroll
        for (int j=0;j<4;j++)
          acc[i][j] = mfma16(af[i], bfr[j], acc[i][j]);
      __builtin_amdgcn_s_setprio(0);
      __builtin_amdgcn_sched_barrier(0);
      asm volatile("s_waitcnt vmcnt(4)" ::: "memory");
      __builtin_amdgcn_s_barrier();
      __builtin_amdgcn_sched_barrier(0);
    }
  }

  const int rbase = m0 + wm*128 + (lane>>4)*4;
  const int cbase = n0 + wn*64 + (lane&15);
  #pragma unroll
  for (int fi=0;fi<8;fi++)
    #pragma unroll
    for (int fj=0;fj<4;fj++)
      #pragma unroll
      for (int r=0;r<4;r++){
        int row = rbase + fi*16 + r;
        int col = cbase + fj*16;
        float v = acc[fi][fj][r];
        if (OUT_BF16) ((ushort*)Cv)[(size_t)row*N + col] = f2bf(v);
        else          ((float*) Cv)[(size_t)row*N + col] = v;
      }
}

// ---------------- wbT[h][d] bf16 <- wb[d][h] f32 ----------------
__global__ __launch_bounds__(256) void k_wbt(const float* __restrict__ wb, ushort* __restrict__ wbT){
  int d = blockIdx.x*256 + threadIdx.x;
  #pragma unroll
  for (int h=0;h<16;h++) wbT[(size_t)h*2048 + d] = f2bf(wb[(size_t)d*16 + h]);
}

// ---------------- beta = sigmoid(A16 @ wbT^T) via MFMA; out [b][h][l] f32 ----------------
__global__ __launch_bounds__(64) void k_beta2(const ushort* __restrict__ A16, const ushort* __restrict__ wbT,
                                              float* __restrict__ beta){
  const int rt = blockIdx.x;
  const int lane = threadIdx.x;
  const int lr = lane & 15, lk8 = (lane>>4)*8;
  const int r0 = rt*16;
  f32x4 acc = (f32x4){0.f,0.f,0.f,0.f};
  for (int k0=0; k0<2048; k0+=32){
    bf16x8 a = *(const bf16x8*)&A16[(size_t)(r0+lr)*2048 + k0 + lk8];
    bf16x8 b = *(const bf16x8*)&wbT[(size_t)lr*2048 + k0 + lk8];
    acc = mfma16(a, b, acc);
  }
  const int h = lane & 15;
  const int rbase = r0 + (lane>>4)*4;
  #pragma unroll
  for (int r=0;r<4;r++){
    int row = rbase + r;
    int b = row >> 12, l = row & 4095;
    float sg = 1.f/(1.f + __expf(-acc[r]));
    beta[((size_t)(b*H_ + h))*L_ + l] = sg;
  }
}

__global__ __launch_bounds__(256) void k_convhead(const ushort* __restrict__ qkv,
      const float* __restrict__ wq, const float* __restrict__ wk, const float* __restrict__ wv,
      ushort* __restrict__ QH, ushort* __restrict__ KH, ushort* __restrict__ VH){
  const int blk = blockIdx.x;
  const int b = blk >> 12, l = blk & 4095;
  const int t = threadIdx.x;
  const int h = t >> 4, d0 = (t & 15) * 8;
  const int ch = h*DK_ + d0;
  const float* wcs[3] = {wq, wk, wv};
  ushort* outs[3] = {QH, KH, VH};
  #pragma unroll
  for (int part=0; part<3; part++){
    float x[4][8];
    #pragma unroll
    for (int i=0;i<4;i++){
      int lrr = l - 3 + i;
      if (lrr >= 0){
        const ushort* p = qkv + ((size_t)(b*L_ + lrr))*ND3 + part*D_ + ch;
        ushort4 a = *(const ushort4*)p, c = *(const ushort4*)(p+4);
        x[i][0]=bf2f(a.x); x[i][1]=bf2f(a.y); x[i][2]=bf2f(a.z); x[i][3]=bf2f(a.w);
        x[i][4]=bf2f(c.x); x[i][5]=bf2f(c.y); x[i][6]=bf2f(c.z); x[i][7]=bf2f(c.w);
      } else {
        #pragma unroll
        for (int j=0;j<8;j++) x[i][j] = 0.f;
      }
    }
    const float* wc = wcs[part];
    float y[8]; float ss = 0.f;
    #pragma unroll
    for (int j=0;j<8;j++){
      float4 w4 = *(const float4*)&wc[(ch + j)*4];
      float yy = x[0][j]*w4.x + x[1][j]*w4.y + x[2][j]*w4.z + x[3][j]*w4.w;
      yy = yy / (1.f + __expf(-yy));
      y[j] = yy; ss += yy*yy;
    }
    if (part < 2){
      #pragma unroll
      for (int m=1;m<16;m<<=1) ss += __shfl_xor(ss, m, 64);
      float sc = rsqrtf(ss + 1e-12f);
      #pragma unroll
      for (int j=0;j<8;j++) y[j] *= sc;
    }
    ushort* op = outs[part] + ((size_t)(b*H_ + h)*L_ + l)*DK_ + d0;
    ushort4 o0, o1;
    o0.x=f2bf(y[0]); o0.y=f2bf(y[1]); o0.z=f2bf(y[2]); o0.w=f2bf(y[3]);
    o1.x=f2bf(y[4]); o1.y=f2bf(y[5]); o1.z=f2bf(y[6]); o1.w=f2bf(y[7]);
    *(ushort4*)op = o0; *(ushort4*)(op+4) = o1;
  }
}

// ---------------- phase 1: per-chunk Tb, M, Kt ----------------
__global__ __launch_bounds__(64) void k_prep(const ushort* __restrict__ QH, const ushort* __restrict__ KH,
      const float* __restrict__ BETA, ushort* __restrict__ TB, ushort* __restrict__ MM,
      ushort* __restrict__ KT){
  const int bid = blockIdx.x, bh = bid>>6, c = bid&63;
  const int lane = threadIdx.x;
  __shared__ ushort Ks[64][136];
  __shared__ ushort Qs[64][136];
  __shared__ float As[64][64];
  __shared__ float Ts[64][64];
  __shared__ float bs[64];
  const ushort* kg = KH + ((size_t)bh*L_ + c*64)*DK_;
  const ushort* qg = QH + ((size_t)bh*L_ + c*64)*DK_;
  {
    const uint4* ks4 = (const uint4*)(kg + (size_t)lane*DK_);
    const uint4* qs4 = (const uint4*)(qg + (size_t)lane*DK_);
    uint4* kd = (uint4*)&Ks[lane][0];
    uint4* qd = (uint4*)&Qs[lane][0];
    #pragma unroll
    for (int i=0;i<16;i++){ kd[i] = ks4[i]; qd[i] = qs4[i]; }
    bs[lane] = BETA[(size_t)bh*L_ + c*64 + lane];
  }
  __syncthreads();
  const int lr = lane&15, lk = lane>>4;
  {
    f32x4 gac[4][4];
    #pragma unroll
    for (int i=0;i<4;i++)
      #pragma unroll
      for (int j=0;j<4;j++) gac[i][j] = (f32x4){0.f,0.f,0.f,0.f};
    #pragma unroll
    for (int kk=0;kk<4;kk++){
      bf16x8 fr[4];
      #pragma unroll
      for (int i=0;i<4;i++) fr[i] = *(const bf16x8*)&Ks[i*16+lr][kk*32 + lk*8];
      #pragma unroll
      for (int mi=0;mi<4;mi++)
        #pragma unroll
        for (int ni=0;ni<4;ni++)
          gac[mi][ni] = mfma16(fr[mi], fr[ni], gac[mi][ni]);
    }
    #pragma unroll
    for (int mi=0;mi<4;mi++)
      #pragma unroll
      for (int ni=0;ni<4;ni++)
        #pragma unroll
        for (int r=0;r<4;r++){
          int t = mi*16 + lk*4 + r, s = ni*16 + lr;
          As[t][s] = (s < t) ? (bs[t] * gac[mi][ni][r]) : 0.f;
        }
  }
  {
    f32x4 mac[4][4];
    #pragma unroll
    for (int i=0;i<4;i++)
      #pragma unroll
      for (int j=0;j<4;j++) mac[i][j] = (f32x4){0.f,0.f,0.f,0.f};
    #pragma unroll
    for (int kk=0;kk<4;kk++){
      bf16x8 frq[4], frk[4];
      #pragma unroll
      for (int i=0;i<4;i++){
        frq[i] = *(const bf16x8*)&Qs[i*16+lr][kk*32 + lk*8];
        frk[i] = *(const bf16x8*)&Ks[i*16+lr][kk*32 + lk*8];
      }
      #pragma unroll
      for (int mi=0;mi<4;mi++)
        #pragma unroll
        for (int ni=0;ni<4;ni++)
          mac[mi][ni] = mfma16(frq[mi], frk[ni], mac[mi][ni]);
    }
    #pragma unroll
    for (int mi=0;mi<4;mi++)
      #pragma unroll
      for (int ni=0;ni<4;ni++)
        #pragma unroll
        for (int r=0;r<4;r++){
          int t = mi*16 + lk*4 + r, s = ni*16 + lr;
          float v = (s <= t) ? mac[mi][ni][r] : 0.f;
          MM[(size_t)bid*4096 + t*64 + s] = f2bf(v);
        }
  }
  __syncthreads();
  for (int t=0;t<64;t++){
    float a = (t==lane) ? 1.f : 0.f;
    for (int s=0;s<t;s++) a -= As[t][s] * Ts[s][lane];
    Ts[t][lane] = a;
  }
  {
    float bc = bs[lane];
    for (int t=0;t<64;t++)
      TB[(size_t)bid*4096 + t*64 + lane] = f2bf(Ts[t][lane] * bc);
  }
  for (int d2=0; d2<64; d2++){
    unsigned uu = *(const unsigned*)&Ks[lane][2*d2];
    KT[(size_t)bid*8192 + (size_t)(2*d2)*64 + lane]   = (ushort)(uu & 0xffffu);
    KT[(size_t)bid*8192 + (size_t)(2*d2+1)*64 + lane] = (ushort)(uu >> 16);
  }
}

template<int LRB, int GRB, int NB>
__device__ __forceinline__ void stage_swz(const ushort* __restrict__ g, ushort* l,
                                          int colOff, int w, int lane){
  for (int idx = w; idx < NB/1024; idx += 4){
    int off = idx*1024 + lane*16;
    int row = off / LRB;
    int inner = off & (LRB-1);
    int src = row*GRB + colOff + (inner ^ ((row&7)<<4));
    __builtin_amdgcn_global_load_lds(
      (const __attribute__((address_space(1))) void*)((const char*)g + src),
      (__attribute__((address_space(3))) void*)((char*)l + idx*1024), 16, 0, 0);
  }
}

__global__ __launch_bounds__(256) void k_chunkrec(const ushort* __restrict__ QH, const ushort* __restrict__ KH,
      const ushort* __restrict__ VH, const ushort* __restrict__ TB, const ushort* __restrict__ MM,
      const ushort* __restrict__ KT, ushort* __restrict__ OH){
  const int bid = blockIdx.x, bh = bid>>1, vh = bid&1;
  const int tid = threadIdx.x, lane = tid&63, w = tid>>6;
  __shared__ ushort Kc[64*128], Qc[64*128], Ktc[128*64], Tbc[64*64], Mc[64*64], Vc[64*64];
  __shared__ ushort Stl[64*128], Ztl[64*64], Utl[64*64];
  const int lr = lane&15, lk = lane>>4;
  const int tq = (w>>1)*32, jq = (w&1)*32;
  const int dq = (w>>1)*64;

  f32x4 Stf[2][4];
  #pragma unroll
  for (int a=0;a<2;a++)
    #pragma unroll
    for (int b=0;b<4;b++) Stf[a][b] = (f32x4){0.f,0.f,0.f,0.f};

  const ushort* kbase  = KH + ((size_t)bh*L_)*DK_;
  const ushort* qbase  = QH + ((size_t)bh*L_)*DK_;
  const ushort* vbase  = VH + ((size_t)bh*L_)*DK_;
  const ushort* tbase  = TB + ((size_t)bh*64)*4096;
  const ushort* mbase  = MM + ((size_t)bh*64)*4096;
  const ushort* ktbase = KT + ((size_t)bh*64)*8192;
  ushort* obase = OH + ((size_t)bh*L_)*DK_ + vh*64;

  for (int c=0; c<64; c++){
    stage_swz<256,256,16384>(kbase  + (size_t)c*8192, Kc,  0, w, lane);
    stage_swz<256,256,16384>(qbase  + (size_t)c*8192, Qc,  0, w, lane);
    stage_swz<128,128,16384>(ktbase + (size_t)c*8192, Ktc, 0, w, lane);
    stage_swz<128,128, 8192>(tbase  + (size_t)c*4096, Tbc, 0, w, lane);
    stage_swz<128,128, 8192>(mbase  + (size_t)c*4096, Mc,  0, w, lane);
    stage_swz<128,256, 8192>(vbase  + (size_t)c*8192, Vc,  vh*128, w, lane);
    #pragma unroll
    for (int mj=0;mj<2;mj++)
      #pragma unroll
      for (int nd=0;nd<4;nd++)
        #pragma unroll
        for (int r=0;r<4;r++){
          int j = jq + mj*16 + lk*4 + r;
          int d = dq + nd*16 + lr;
          Stl[j*128 + (d ^ ((j&7)<<3))] = f2bf(Stf[mj][nd][r]);
        }
    __syncthreads();

    f32x4 xac[2][2];
    #pragma unroll
    for (int i=0;i<2;i++)
      #pragma unroll
      for (int j2=0;j2<2;j2++) xac[i][j2] = (f32x4){0.f,0.f,0.f,0.f};
    #pragma unroll
    for (int kk=0;kk<4;kk++){
      int e = kk*32 + lk*8;
      bf16x8 bst[2], ak[2];
      #pragma unroll
      for (int ni=0;ni<2;ni++){ int j = jq + ni*16 + lr; bst[ni] = *(const bf16x8*)&Stl[j*128 + (e ^ ((j&7)<<3))]; }
      #pragma unroll
      for (int mi=0;mi<2;mi++){ int t = tq + mi*16 + lr; ak[mi]  = *(const bf16x8*)&Kc [t*128 + (e ^ ((t&7)<<3))]; }
      #pragma unroll
      for (int mi=0;mi<2;mi++)
        #pragma unroll
        for (int ni=0;ni<2;ni++)
          xac[mi][ni] = mfma16(ak[mi], bst[ni], xac[mi][ni]);
    }
    #pragma unroll
    for (int mi=0;mi<2;mi++)
      #pragma unroll
      for (int ni=0;ni<2;ni++)
        #pragma unroll
        for (int r=0;r<4;r++){
          int t = tq + mi*16 + lk*4 + r;
          int j = jq + ni*16 + lr;
          float v = bf2f(Vc[t*64 + (j ^ ((t&7)<<3))]);
          Ztl[j*64 + (t ^ ((j&7)<<3))] = f2bf(v - xac[mi][ni][r]);
        }
    __syncthreads();

    f32x4 uac[2][2];
    #pragma unroll
    for (int i=0;i<2;i++)
      #pragma unroll
      for (int j2=0;j2<2;j2++) uac[i][j2] = (f32x4){0.f,0.f,0.f,0.f};
    #pragma unroll
    for (int kk=0;kk<2;kk++){
      int e = kk*32 + lk*8;
      bf16x8 bz[2], at[2];
      #pragma unroll
      for (int ni=0;ni<2;ni++){ int j = jq + ni*16 + lr; bz[ni] = *(const bf16x8*)&Ztl[j*64 + (e ^ ((j&7)<<3))]; }
      #pragma unroll
      for (int mi=0;mi<2;mi++){ int t = tq + mi*16 + lr; at[mi] = *(const bf16x8*)&Tbc[t*64 + (e ^ ((t&7)<<3))]; }
      #pragma unroll
      for (int mi=0;mi<2;mi++)
        #pragma unroll
        for (int ni=0;ni<2;ni++)
          uac[mi][ni] = mfma16(at[mi], bz[ni], uac[mi][ni]);
    }
    #pragma unroll
    for (int mi=0;mi<2;mi++)
      #pragma unroll
      for (int ni=0;ni<2;ni++)
        #pragma unroll
        for (int r=0;r<4;r++){
          int t = tq + mi*16 + lk*4 + r;
          int j = jq + ni*16 + lr;
          Utl[j*64 + (t ^ ((j&7)<<3))] = f2bf(uac[mi][ni][r]);
        }
    __syncthreads();

    f32x4 oac[2][2];
    #pragma unroll
    for (int i=0;i<2;i++)
      #pragma unroll
      for (int j2=0;j2<2;j2++) oac[i][j2] = (f32x4){0.f,0.f,0.f,0.f};
    #pragma unroll
    for (int kk=0;kk<4;kk++){
      int e = kk*32 + lk*8;
      bf16x8 bst[2], aq[2];
      #pragma unroll
      for (int ni=0;ni<2;ni++){ int j = jq + ni*16 + lr; bst[ni] = *(const bf16x8*)&Stl[j*128 + (e ^ ((j&7)<<3))]; }
      #pragma unroll
      for (int mi=0;mi<2;mi++){ int t = tq + mi*16 + lr; aq[mi]  = *(const bf16x8*)&Qc [t*128 + (e ^ ((t&7)<<3))]; }
      #pragma unroll
      for (int mi=0;mi<2;mi++)
        #pragma unroll
        for (int ni=0;ni<2;ni++)
          oac[mi][ni] = mfma16(aq[mi], bst[ni], oac[mi][ni]);
    }
    #pragma unroll
    for (int kk=0;kk<2;kk++){
      int e = kk*32 + lk*8;
      bf16x8 bu[2], am[2];
      #pragma unroll
      for (int ni=0;ni<2;ni++){ int j = jq + ni*16 + lr; bu[ni] = *(const bf16x8*)&Utl[j*64 + (e ^ ((j&7)<<3))]; }
      #pragma unroll
      for (int mi=0;mi<2;mi++){ int t = tq + mi*16 + lr; am[mi] = *(const bf16x8*)&Mc [t*64 + (e ^ ((t&7)<<3))]; }
      #pragma unroll
      for (int mi=0;mi<2;mi++)
        #pragma unroll
        for (int ni=0;ni<2;ni++)
          oac[mi][ni] = mfma16(am[mi], bu[ni], oac[mi][ni]);
    }
    #pragma unroll
    for (int mi=0;mi<2;mi++)
      #pragma unroll
      for (int ni=0;ni<2;ni++)
        #pragma unroll
        for (int r=0;r<4;r++){
          int t = tq + mi*16 + lk*4 + r;
          int j = jq + ni*16 + lr;
          obase[(size_t)(c*64 + t)*DK_ + j] = f2bf(oac[mi][ni][r]);
        }

    #pragma unroll
    for (int kk=0;kk<2;kk++){
      int e = kk*32 + lk*8;
      bf16x8 au[2], bk[4];
      #pragma unroll
      for (int mj=0;mj<2;mj++){ int j = jq + mj*16 + lr; au[mj] = *(const bf16x8*)&Utl[j*64 + (e ^ ((j&7)<<3))]; }
      #pragma unroll
      for (int nd=0;nd<4;nd++){ int d = dq + nd*16 + lr; bk[nd] = *(const bf16x8*)&Ktc[d*64 + (e ^ ((d&7)<<3))]; }
      #pragma unroll
      for (int mj=0;mj<2;mj++)
        #pragma unroll
        for (int nd=0;nd<4;nd++)
          Stf[mj][nd] = mfma16(au[mj], bk[nd], Stf[mj][nd]);
    }
    __syncthreads();
  }
}

__global__ __launch_bounds__(256) void k_norm(const ushort* __restrict__ OH, const float* __restrict__ gw,
                                              ushort* __restrict__ O2){
  const int blk = blockIdx.x;
  const int b = blk >> 12, l = blk & 4095;
  const int t = threadIdx.x;
  const int h = t >> 4, d0 = (t & 15) * 8;
  const ushort* ip = OH + ((size_t)(b*H_ + h)*L_ + l)*DK_ + d0;
  ushort4 a = *(const ushort4*)ip, c = *(const ushort4*)(ip+4);
  float x[8];
  x[0]=bf2f(a.x); x[1]=bf2f(a.y); x[2]=bf2f(a.z); x[3]=bf2f(a.w);
  x[4]=bf2f(c.x); x[5]=bf2f(c.y); x[6]=bf2f(c.z); x[7]=bf2f(c.w);
  float ss = 0.f;
  #pragma unroll
  for (int j=0;j<8;j++) ss += x[j]*x[j];
  #pragma unroll
  for (int m=1;m<16;m<<=1) ss += __shfl_xor(ss, m, 64);
  float sc = rsqrtf(ss * (1.f/128.f) + 1e-5f);
  ushort* opp = O2 + (size_t)blk*D_ + h*DK_ + d0;
  ushort4 o0, o1;
  o0.x=f2bf(x[0]*sc*gw[d0+0]); o0.y=f2bf(x[1]*sc*gw[d0+1]);
  o0.z=f2bf(x[2]*sc*gw[d0+2]); o0.w=f2bf(x[3]*sc*gw[d0+3]);
  o1.x=f2bf(x[4]*sc*gw[d0+4]); o1.y=f2bf(x[5]*sc*gw[d0+5]);
  o1.z=f2bf(x[6]*sc*gw[d0+6]); o1.w=f2bf(x[7]*sc*gw[d0+7]);
  *(ushort4*)opp = o0; *(ushort4*)(opp+4) = o1;
}

extern "C" void kernel_launch(void* const* d_in, const int* in_sizes, int n_in,
                              void* d_out, int out_size, void* d_ws, size_t ws_size,
                              hipStream_t stream) {
  (void)in_sizes; (void)n_in; (void)out_size; (void)ws_size;
  const float* hidden  = (const float*)d_in[0];
  const float* w_cattn = (const float*)d_in[1];
  const float* wq_conv = (const float*)d_in[2];
  const float* wk_conv = (const float*)d_in[3];
  const float* wv_conv = (const float*)d_in[4];
  const float* w_beta  = (const float*)d_in[5];
  const float* o_nw    = (const float*)d_in[6];
  const float* w_o     = (const float*)d_in[7];
  float* out = (float*)d_out;

  char* W = (char*)d_ws;                              // total 260,046,848 B (known-good size)
  ushort* A16   = (ushort*)(W);                       // 32MB ; -> OH after gemm1
  ushort* WcatT = (ushort*)(W + 33554432u);           // 24MB [6144][2048]; dead after gemm1
  ushort* WoT   = (ushort*)(W + 33554432u);           //  8MB (alias, written after gemm1)
  float*  BETA  = (float*) (W + 41943040u);           // 512KB (alias in dead WcatT region)
  ushort* WBT   = (ushort*)(W + 42467328u);           // 64KB  (alias in dead WcatT region)
  ushort* QKV   = (ushort*)(W + 58720256u);           // 96MB; dead after convhead
  ushort* TB    = (ushort*)(W + 58720256u);           // 16MB (alias in dead QKV)
  ushort* MM    = (ushort*)(W + 75497472u);           // 16MB
  ushort* KT    = (ushort*)(W + 92274688u);           // 32MB
  ushort* O2    = (ushort*)(W + 125829120u);          // 32MB
  ushort* QH    = (ushort*)(W + 159383552u);          // 32MB
  ushort* KH    = (ushort*)(W + 192937984u);          // 32MB
  ushort* VH    = (ushort*)(W + 226492416u);          // 32MB -> end 260,046,848
  ushort* OH = A16;

  k_cast<<<4096, 256, 0, stream>>>(hidden, A16, (BL_*D_)/4);
  k_transpose_cast<<<dim3(ND3/32, D_/32), dim3(32,8), 0, stream>>>(w_cattn, WcatT, D_, ND3);
  k_gemmks<1><<<dim3(ND3/256, BL_/256), 512, 0, stream>>>(A16, WcatT, QKV, BL_, ND3, D_);
  // WcatT region dead from here on
  k_transpose_cast<<<dim3(D_/32, D_/32), dim3(32,8), 0, stream>>>(w_o, WoT, D_, D_);
  k_wbt<<<8, 256, 0, stream>>>(w_beta, WBT);
  k_beta2<<<512, 64, 0, stream>>>(A16, WBT, BETA);
  k_convhead<<<BL_, 256, 0, stream>>>(QKV, wq_conv, wk_conv, wv_conv, QH, KH, VH);
  k_prep<<<2048, 64, 0, stream>>>(QH, KH, BETA, TB, MM, KT);
  k_chunkrec<<<64, 256, 0, stream>>>(QH, KH, VH, TB, MM, KT, OH);
  k_norm<<<BL_, 256, 0, stream>>>(OH, o_nw, O2);
  k_gemmks<0><<<dim3(D_/256, BL_/256), 512, 0, stream>>>(O2, WoT, out, BL_, D_, D_);
}

// Round 7
// 757.670 us; speedup vs baseline: 8.1544x; 1.0844x over previous
//
#include <hip/hip_runtime.h>
#include <stdint.h>

#define B_   2
#define L_   4096
#define D_   2048
#define H_   16
#define DK_  128
#define ND3  6144
#define BL_  8192

typedef __bf16 bf16x8 __attribute__((ext_vector_type(8)));
typedef float  f32x4  __attribute__((ext_vector_type(4)));

__device__ __forceinline__ float bf2f(ushort u){ return __uint_as_float(((unsigned)u)<<16); }
__device__ __forceinline__ ushort f2bf(float f){
  unsigned u = __float_as_uint(f);
  unsigned r = u + 0x7FFFu + ((u>>16)&1u);
  return (ushort)(r>>16);
}
__device__ __forceinline__ f32x4 mfma16(bf16x8 a, bf16x8 b, f32x4 c){
  return __builtin_amdgcn_mfma_f32_16x16x32_bf16(a, b, c, 0, 0, 0);
}

__global__ __launch_bounds__(256) void k_cast(const float* __restrict__ x, ushort* __restrict__ y, int n4){
  int i = blockIdx.x*blockDim.x + threadIdx.x;
  int stride = gridDim.x*blockDim.x;
  for (; i < n4; i += stride){
    float4 v = ((const float4*)x)[i];
    ushort4 o; o.x=f2bf(v.x); o.y=f2bf(v.y); o.z=f2bf(v.z); o.w=f2bf(v.w);
    ((ushort4*)y)[i] = o;
  }
}

__global__ __launch_bounds__(256) void k_transpose_cast(const float* __restrict__ in, ushort* __restrict__ out,
                                                        int R, int C){
  __shared__ float tile[32][33];
  int c0 = blockIdx.x*32, r0 = blockIdx.y*32;
  int tx = threadIdx.x, ty = threadIdx.y;
  #pragma unroll
  for (int i=0;i<32;i+=8) tile[ty+i][tx] = in[(size_t)(r0+ty+i)*C + (c0+tx)];
  __syncthreads();
  #pragma unroll
  for (int i=0;i<32;i+=8) out[(size_t)(c0+ty+i)*R + (r0+tx)] = f2bf(tile[tx][ty+i]);
}

// ============ 256x256 GEMM, 4-slot ring pipeline: C = A[M][K] * Bt[N][K]^T ============
// 8 waves (2M x 4N). Phase p (= 2*tile + slice) computes K-slice of 32 from slot p&3,
// stages phase p+3's slice into slot (p+3)&3, then vmcnt(8)+s_barrier.
// At end of phase p: outstanding = stages for p+1,p+2,p+3 (12 loads); vmcnt(8) releases
// p+1's slice (issued at phase p-2 -> ~2.3-phase latency window).
template<int OUT_BF16>
__global__ __launch_bounds__(512, 1) void k_gemmks(const ushort* __restrict__ A, const ushort* __restrict__ Bt,
                                                   void* __restrict__ Cv, int M, int N, int K){
  __shared__ ushort LDSB[65536];   // 128 KB = 4 slots x (A 16KB | B 16KB)
  char* lds = (char*)LDSB;
  const int tid = threadIdx.x, lane = tid & 63, w = tid >> 6;
  const int wm = w >> 2, wn = w & 3;
  int nwg = gridDim.x*gridDim.y;
  int id  = blockIdx.y*gridDim.x + blockIdx.x;
  int sw  = ((nwg & 7) == 0) ? ((id & 7)*(nwg >> 3) + (id >> 3)) : id;
  const int bx = sw % gridDim.x, by = sw / gridDim.x;
  const int m0 = by*256, n0 = bx*256;
  const int NT = K >> 6;            // K-tiles of 64
  const int NP = NT*2;              // phases (K-slices of 32); K=2048 -> 64, %4==0
  const size_t rowb = (size_t)K*2;

  f32x4 acc[8][4];
  #pragma unroll
  for (int i=0;i<8;i++)
    #pragma unroll
    for (int j=0;j<4;j++) acc[i][j] = (f32x4){0.f,0.f,0.f,0.f};

  const int c0 = tid, c1 = tid + 512;
  const int r0c = ((c0>>6)<<4) + (c0&15), h0 = (c0>>4)&3;
  const int r1c = ((c1>>6)<<4) + (c1&15), h1 = (c1>>4)&3;
  const char* gA = (const char*)A  + (size_t)m0*rowb;
  const char* gB = (const char*)Bt + (size_t)n0*rowb;

  // stage slice (tile,s) into slot (4 x global_load_lds width-16 per thread)
  auto stage = [&](int slot, int tile, int s){
    const char* ga = gA + (size_t)tile*128 + s*64;
    const char* gb = gB + (size_t)tile*128 + s*64;
    char* la = lds + slot*32768;
    char* lb = la + 16384;
    __builtin_amdgcn_global_load_lds((const __attribute__((address_space(1))) void*)(ga + (size_t)r0c*rowb + h0*16),
                                     (__attribute__((address_space(3))) void*)(la + c0*16), 16, 0, 0);
    __builtin_amdgcn_global_load_lds((const __attribute__((address_space(1))) void*)(ga + (size_t)r1c*rowb + h1*16),
                                     (__attribute__((address_space(3))) void*)(la + c1*16), 16, 0, 0);
    __builtin_amdgcn_global_load_lds((const __attribute__((address_space(1))) void*)(gb + (size_t)r0c*rowb + h0*16),
                                     (__attribute__((address_space(3))) void*)(lb + c0*16), 16, 0, 0);
    __builtin_amdgcn_global_load_lds((const __attribute__((address_space(1))) void*)(gb + (size_t)r1c*rowb + h1*16),
                                     (__attribute__((address_space(3))) void*)(lb + c1*16), 16, 0, 0);
  };

  // prologue: stage phases 0,1,2 into slots 0,1,2; wait slot0 landed
  stage(0, 0, 0);
  stage(1, 0, 1);
  stage(2, 1, 0);
  __builtin_amdgcn_sched_barrier(0);
  asm volatile("s_waitcnt vmcnt(8)" ::: "memory");
  __builtin_amdgcn_s_barrier();
  __builtin_amdgcn_sched_barrier(0);

  for (int pb = 0; pb < NP; pb += 4){
    #pragma unroll
    for (int q = 0; q < 4; ++q){
      const int p = pb + q;                 // phase; slot = q
      const char* base = lds + q*32768;
      bf16x8 af[8], bfr[4];
      #pragma unroll
      for (int i=0;i<8;i++) af[i]  = *(const bf16x8*)(base + (wm*128 + i*16)*64 + lane*16);
      #pragma unroll
      for (int j=0;j<4;j++) bfr[j] = *(const bf16x8*)(base + 16384 + (wn*64 + j*16)*64 + lane*16);
      {
        int ps = p + 3;
        int tile = ps >> 1; if (tile >= NT) tile = NT - 1;   // tail: dummy stage, never read
        stage(ps & 3, tile, ps & 1);
      }
      __builtin_amdgcn_s_setprio(1);
      #pragma unroll
      for (int i=0;i<8;i++)
        #pragma unroll
        for (int j=0;j<4;j++)
          acc[i][j] = mfma16(af[i], bfr[j], acc[i][j]);
      __builtin_amdgcn_s_setprio(0);
      __builtin_amdgcn_sched_barrier(0);
      asm volatile("s_waitcnt vmcnt(8)" ::: "memory");
      __builtin_amdgcn_s_barrier();
      __builtin_amdgcn_sched_barrier(0);
    }
  }

  const int rbase = m0 + wm*128 + (lane>>4)*4;
  const int cbase = n0 + wn*64 + (lane&15);
  #pragma unroll
  for (int fi=0;fi<8;fi++)
    #pragma unroll
    for (int fj=0;fj<4;fj++)
      #pragma unroll
      for (int r=0;r<4;r++){
        int row = rbase + fi*16 + r;
        int col = cbase + fj*16;
        float v = acc[fi][fj][r];
        if (OUT_BF16) ((ushort*)Cv)[(size_t)row*N + col] = f2bf(v);
        else          ((float*) Cv)[(size_t)row*N + col] = v;
      }
}

// ---------------- wbT[h][d] bf16 <- wb[d][h] f32 ----------------
__global__ __launch_bounds__(256) void k_wbt(const float* __restrict__ wb, ushort* __restrict__ wbT){
  int d = blockIdx.x*256 + threadIdx.x;
  #pragma unroll
  for (int h=0;h<16;h++) wbT[(size_t)h*2048 + d] = f2bf(wb[(size_t)d*16 + h]);
}

// ---------------- beta = sigmoid(A16 @ wbT^T) via MFMA; out [b][h][l] f32 ----------------
__global__ __launch_bounds__(64) void k_beta2(const ushort* __restrict__ A16, const ushort* __restrict__ wbT,
                                              float* __restrict__ beta){
  const int rt = blockIdx.x;
  const int lane = threadIdx.x;
  const int lr = lane & 15, lk8 = (lane>>4)*8;
  const int r0 = rt*16;
  f32x4 acc0 = (f32x4){0.f,0.f,0.f,0.f};
  f32x4 acc1 = (f32x4){0.f,0.f,0.f,0.f};
  for (int k0=0; k0<2048; k0+=64){
    bf16x8 a0 = *(const bf16x8*)&A16[(size_t)(r0+lr)*2048 + k0 + lk8];
    bf16x8 b0 = *(const bf16x8*)&wbT[(size_t)lr*2048 + k0 + lk8];
    bf16x8 a1 = *(const bf16x8*)&A16[(size_t)(r0+lr)*2048 + k0 + 32 + lk8];
    bf16x8 b1 = *(const bf16x8*)&wbT[(size_t)lr*2048 + k0 + 32 + lk8];
    acc0 = mfma16(a0, b0, acc0);
    acc1 = mfma16(a1, b1, acc1);
  }
  const int h = lane & 15;
  const int rbase = r0 + (lane>>4)*4;
  #pragma unroll
  for (int r=0;r<4;r++){
    int row = rbase + r;
    int b = row >> 12, l = row & 4095;
    float sg = 1.f/(1.f + __expf(-(acc0[r] + acc1[r])));
    beta[((size_t)(b*H_ + h))*L_ + l] = sg;
  }
}

// ---------------- conv(K=4, causal)+SiLU+heads+l2norm, sliding window over L ----------------
// grid (128 segs of 32 l, 3 parts, 2 b), block 256. Thread owns 8 channels; QKV read once.
__global__ __launch_bounds__(256) void k_conv2(const ushort* __restrict__ qkv,
      const float* __restrict__ wq, const float* __restrict__ wk, const float* __restrict__ wv,
      ushort* __restrict__ QH, ushort* __restrict__ KH, ushort* __restrict__ VH){
  const int seg = blockIdx.x, part = blockIdx.y, b = blockIdx.z;
  const int t = threadIdx.x;
  const int ch = t*8;
  const int h = t >> 4, d0 = (t & 15)*8;
  const float* wc = (part==0) ? wq : (part==1) ? wk : wv;
  ushort* outs = ((part==0) ? QH : (part==1) ? KH : VH)
                 + ((size_t)(b*H_ + h)*L_)*DK_ + d0;
  const ushort* inp = qkv + ((size_t)b*L_)*ND3 + part*D_ + ch;

  float wgt[4][8];
  #pragma unroll
  for (int j=0;j<8;j++){
    float4 w4 = *(const float4*)&wc[(ch + j)*4];
    wgt[0][j]=w4.x; wgt[1][j]=w4.y; wgt[2][j]=w4.z; wgt[3][j]=w4.w;
  }

  const int l0 = seg*32;
  float x0[8], x1[8], x2[8];
  // halo rows l0-3, l0-2, l0-1 (zero if <0)
  {
    float* dsts[3] = {x0, x1, x2};
    #pragma unroll
    for (int i=0;i<3;i++){
      int l = l0 - 3 + i;
      float* d = dsts[i];
      if (l >= 0){
        const ushort* p = inp + (size_t)l*ND3;
        ushort4 a = *(const ushort4*)p, c = *(const ushort4*)(p+4);
        d[0]=bf2f(a.x); d[1]=bf2f(a.y); d[2]=bf2f(a.z); d[3]=bf2f(a.w);
        d[4]=bf2f(c.x); d[5]=bf2f(c.y); d[6]=bf2f(c.z); d[7]=bf2f(c.w);
      } else {
        #pragma unroll
        for (int j=0;j<8;j++) d[j] = 0.f;
      }
    }
  }

  for (int i=0;i<32;i++){
    const int l = l0 + i;
    float cur[8];
    {
      const ushort* p = inp + (size_t)l*ND3;
      ushort4 a = *(const ushort4*)p, c = *(const ushort4*)(p+4);
      cur[0]=bf2f(a.x); cur[1]=bf2f(a.y); cur[2]=bf2f(a.z); cur[3]=bf2f(a.w);
      cur[4]=bf2f(c.x); cur[5]=bf2f(c.y); cur[6]=bf2f(c.z); cur[7]=bf2f(c.w);
    }
    float y[8]; float ss = 0.f;
    #pragma unroll
    for (int j=0;j<8;j++){
      float yy = x0[j]*wgt[0][j] + x1[j]*wgt[1][j] + x2[j]*wgt[2][j] + cur[j]*wgt[3][j];
      yy = yy / (1.f + __expf(-yy));     // SiLU
      y[j] = yy; ss += yy*yy;
    }
    if (part < 2){
      #pragma unroll
      for (int m=1;m<16;m<<=1) ss += __shfl_xor(ss, m, 64);
      float sc = rsqrtf(ss + 1e-12f);
      #pragma unroll
      for (int j=0;j<8;j++) y[j] *= sc;
    }
    ushort4 o0, o1;
    o0.x=f2bf(y[0]); o0.y=f2bf(y[1]); o0.z=f2bf(y[2]); o0.w=f2bf(y[3]);
    o1.x=f2bf(y[4]); o1.y=f2bf(y[5]); o1.z=f2bf(y[6]); o1.w=f2bf(y[7]);
    ushort* op = outs + (size_t)l*DK_;
    *(ushort4*)op = o0; *(ushort4*)(op+4) = o1;
    #pragma unroll
    for (int j=0;j<8;j++){ x0[j]=x1[j]; x1[j]=x2[j]; x2[j]=cur[j]; }
  }
}

// ---------------- phase 1: per-chunk Tb, M, Kt ----------------
__global__ __launch_bounds__(64) void k_prep(const ushort* __restrict__ QH, const ushort* __restrict__ KH,
      const float* __restrict__ BETA, ushort* __restrict__ TB, ushort* __restrict__ MM,
      ushort* __restrict__ KT){
  const int bid = blockIdx.x, bh = bid>>6, c = bid&63;
  const int lane = threadIdx.x;
  __shared__ ushort Ks[64][136];
  __shared__ ushort Qs[64][136];
  __shared__ float As[64][64];
  __shared__ float Ts[64][64];
  __shared__ float bs[64];
  const ushort* kg = KH + ((size_t)bh*L_ + c*64)*DK_;
  const ushort* qg = QH + ((size_t)bh*L_ + c*64)*DK_;
  {
    const uint4* ks4 = (const uint4*)(kg + (size_t)lane*DK_);
    const uint4* qs4 = (const uint4*)(qg + (size_t)lane*DK_);
    uint4* kd = (uint4*)&Ks[lane][0];
    uint4* qd = (uint4*)&Qs[lane][0];
    #pragma unroll
    for (int i=0;i<16;i++){ kd[i] = ks4[i]; qd[i] = qs4[i]; }
    bs[lane] = BETA[(size_t)bh*L_ + c*64 + lane];
  }
  __syncthreads();
  const int lr = lane&15, lk = lane>>4;
  {
    f32x4 gac[4][4];
    #pragma unroll
    for (int i=0;i<4;i++)
      #pragma unroll
      for (int j=0;j<4;j++) gac[i][j] = (f32x4){0.f,0.f,0.f,0.f};
    #pragma unroll
    for (int kk=0;kk<4;kk++){
      bf16x8 fr[4];
      #pragma unroll
      for (int i=0;i<4;i++) fr[i] = *(const bf16x8*)&Ks[i*16+lr][kk*32 + lk*8];
      #pragma unroll
      for (int mi=0;mi<4;mi++)
        #pragma unroll
        for (int ni=0;ni<4;ni++)
          gac[mi][ni] = mfma16(fr[mi], fr[ni], gac[mi][ni]);
    }
    #pragma unroll
    for (int mi=0;mi<4;mi++)
      #pragma unroll
      for (int ni=0;ni<4;ni++)
        #pragma unroll
        for (int r=0;r<4;r++){
          int t = mi*16 + lk*4 + r, s = ni*16 + lr;
          As[t][s] = (s < t) ? (bs[t] * gac[mi][ni][r]) : 0.f;
        }
  }
  {
    f32x4 mac[4][4];
    #pragma unroll
    for (int i=0;i<4;i++)
      #pragma unroll
      for (int j=0;j<4;j++) mac[i][j] = (f32x4){0.f,0.f,0.f,0.f};
    #pragma unroll
    for (int kk=0;kk<4;kk++){
      bf16x8 frq[4], frk[4];
      #pragma unroll
      for (int i=0;i<4;i++){
        frq[i] = *(const bf16x8*)&Qs[i*16+lr][kk*32 + lk*8];
        frk[i] = *(const bf16x8*)&Ks[i*16+lr][kk*32 + lk*8];
      }
      #pragma unroll
      for (int mi=0;mi<4;mi++)
        #pragma unroll
        for (int ni=0;ni<4;ni++)
          mac[mi][ni] = mfma16(frq[mi], frk[ni], mac[mi][ni]);
    }
    #pragma unroll
    for (int mi=0;mi<4;mi++)
      #pragma unroll
      for (int ni=0;ni<4;ni++)
        #pragma unroll
        for (int r=0;r<4;r++){
          int t = mi*16 + lk*4 + r, s = ni*16 + lr;
          float v = (s <= t) ? mac[mi][ni][r] : 0.f;
          MM[(size_t)bid*4096 + t*64 + s] = f2bf(v);
        }
  }
  __syncthreads();
  for (int t=0;t<64;t++){
    float a = (t==lane) ? 1.f : 0.f;
    for (int s=0;s<t;s++) a -= As[t][s] * Ts[s][lane];
    Ts[t][lane] = a;
  }
  {
    float bc = bs[lane];
    for (int t=0;t<64;t++)
      TB[(size_t)bid*4096 + t*64 + lane] = f2bf(Ts[t][lane] * bc);
  }
  for (int d2=0; d2<64; d2++){
    unsigned uu = *(const unsigned*)&Ks[lane][2*d2];
    KT[(size_t)bid*8192 + (size_t)(2*d2)*64 + lane]   = (ushort)(uu & 0xffffu);
    KT[(size_t)bid*8192 + (size_t)(2*d2+1)*64 + lane] = (ushort)(uu >> 16);
  }
}

template<int LRB, int GRB, int NB>
__device__ __forceinline__ void stage_swz(const ushort* __restrict__ g, ushort* l,
                                          int colOff, int w, int lane){
  for (int idx = w; idx < NB/1024; idx += 4){
    int off = idx*1024 + lane*16;
    int row = off / LRB;
    int inner = off & (LRB-1);
    int src = row*GRB + colOff + (inner ^ ((row&7)<<4));
    __builtin_amdgcn_global_load_lds(
      (const __attribute__((address_space(1))) void*)((const char*)g + src),
      (__attribute__((address_space(3))) void*)((char*)l + idx*1024), 16, 0, 0);
  }
}

__global__ __launch_bounds__(256) void k_chunkrec(const ushort* __restrict__ QH, const ushort* __restrict__ KH,
      const ushort* __restrict__ VH, const ushort* __restrict__ TB, const ushort* __restrict__ MM,
      const ushort* __restrict__ KT, ushort* __restrict__ OH){
  const int bid = blockIdx.x, bh = bid>>1, vh = bid&1;
  const int tid = threadIdx.x, lane = tid&63, w = tid>>6;
  __shared__ ushort Kc[64*128], Qc[64*128], Ktc[128*64], Tbc[64*64], Mc[64*64], Vc[64*64];
  __shared__ ushort Stl[64*128], Ztl[64*64], Utl[64*64];
  const int lr = lane&15, lk = lane>>4;
  const int tq = (w>>1)*32, jq = (w&1)*32;
  const int dq = (w>>1)*64;

  f32x4 Stf[2][4];
  #pragma unroll
  for (int a=0;a<2;a++)
    #pragma unroll
    for (int b=0;b<4;b++) Stf[a][b] = (f32x4){0.f,0.f,0.f,0.f};

  const ushort* kbase  = KH + ((size_t)bh*L_)*DK_;
  const ushort* qbase  = QH + ((size_t)bh*L_)*DK_;
  const ushort* vbase  = VH + ((size_t)bh*L_)*DK_;
  const ushort* tbase  = TB + ((size_t)bh*64)*4096;
  const ushort* mbase  = MM + ((size_t)bh*64)*4096;
  const ushort* ktbase = KT + ((size_t)bh*64)*8192;
  ushort* obase = OH + ((size_t)bh*L_)*DK_ + vh*64;

  for (int c=0; c<64; c++){
    stage_swz<256,256,16384>(kbase  + (size_t)c*8192, Kc,  0, w, lane);
    stage_swz<256,256,16384>(qbase  + (size_t)c*8192, Qc,  0, w, lane);
    stage_swz<128,128,16384>(ktbase + (size_t)c*8192, Ktc, 0, w, lane);
    stage_swz<128,128, 8192>(tbase  + (size_t)c*4096, Tbc, 0, w, lane);
    stage_swz<128,128, 8192>(mbase  + (size_t)c*4096, Mc,  0, w, lane);
    stage_swz<128,256, 8192>(vbase  + (size_t)c*8192, Vc,  vh*128, w, lane);
    #pragma unroll
    for (int mj=0;mj<2;mj++)
      #pragma unroll
      for (int nd=0;nd<4;nd++)
        #pragma unroll
        for (int r=0;r<4;r++){
          int j = jq + mj*16 + lk*4 + r;
          int d = dq + nd*16 + lr;
          Stl[j*128 + (d ^ ((j&7)<<3))] = f2bf(Stf[mj][nd][r]);
        }
    __syncthreads();

    f32x4 xac[2][2];
    #pragma unroll
    for (int i=0;i<2;i++)
      #pragma unroll
      for (int j2=0;j2<2;j2++) xac[i][j2] = (f32x4){0.f,0.f,0.f,0.f};
    #pragma unroll
    for (int kk=0;kk<4;kk++){
      int e = kk*32 + lk*8;
      bf16x8 bst[2], ak[2];
      #pragma unroll
      for (int ni=0;ni<2;ni++){ int j = jq + ni*16 + lr; bst[ni] = *(const bf16x8*)&Stl[j*128 + (e ^ ((j&7)<<3))]; }
      #pragma unroll
      for (int mi=0;mi<2;mi++){ int t = tq + mi*16 + lr; ak[mi]  = *(const bf16x8*)&Kc [t*128 + (e ^ ((t&7)<<3))]; }
      #pragma unroll
      for (int mi=0;mi<2;mi++)
        #pragma unroll
        for (int ni=0;ni<2;ni++)
          xac[mi][ni] = mfma16(ak[mi], bst[ni], xac[mi][ni]);
    }
    #pragma unroll
    for (int mi=0;mi<2;mi++)
      #pragma unroll
      for (int ni=0;ni<2;ni++)
        #pragma unroll
        for (int r=0;r<4;r++){
          int t = tq + mi*16 + lk*4 + r;
          int j = jq + ni*16 + lr;
          float v = bf2f(Vc[t*64 + (j ^ ((t&7)<<3))]);
          Ztl[j*64 + (t ^ ((j&7)<<3))] = f2bf(v - xac[mi][ni][r]);
        }
    __syncthreads();

    f32x4 uac[2][2];
    #pragma unroll
    for (int i=0;i<2;i++)
      #pragma unroll
      for (int j2=0;j2<2;j2++) uac[i][j2] = (f32x4){0.f,0.f,0.f,0.f};
    #pragma unroll
    for (int kk=0;kk<2;kk++){
      int e = kk*32 + lk*8;
      bf16x8 bz[2], at[2];
      #pragma unroll
      for (int ni=0;ni<2;ni++){ int j = jq + ni*16 + lr; bz[ni] = *(const bf16x8*)&Ztl[j*64 + (e ^ ((j&7)<<3))]; }
      #pragma unroll
      for (int mi=0;mi<2;mi++){ int t = tq + mi*16 + lr; at[mi] = *(const bf16x8*)&Tbc[t*64 + (e ^ ((t&7)<<3))]; }
      #pragma unroll
      for (int mi=0;mi<2;mi++)
        #pragma unroll
        for (int ni=0;ni<2;ni++)
          uac[mi][ni] = mfma16(at[mi], bz[ni], uac[mi][ni]);
    }
    #pragma unroll
    for (int mi=0;mi<2;mi++)
      #pragma unroll
      for (int ni=0;ni<2;ni++)
        #pragma unroll
        for (int r=0;r<4;r++){
          int t = tq + mi*16 + lk*4 + r;
          int j = jq + ni*16 + lr;
          Utl[j*64 + (t ^ ((j&7)<<3))] = f2bf(uac[mi][ni][r]);
        }
    __syncthreads();

    f32x4 oac[2][2];
    #pragma unroll
    for (int i=0;i<2;i++)
      #pragma unroll
      for (int j2=0;j2<2;j2++) oac[i][j2] = (f32x4){0.f,0.f,0.f,0.f};
    #pragma unroll
    for (int kk=0;kk<4;kk++){
      int e = kk*32 + lk*8;
      bf16x8 bst[2], aq[2];
      #pragma unroll
      for (int ni=0;ni<2;ni++){ int j = jq + ni*16 + lr; bst[ni] = *(const bf16x8*)&Stl[j*128 + (e ^ ((j&7)<<3))]; }
      #pragma unroll
      for (int mi=0;mi<2;mi++){ int t = tq + mi*16 + lr; aq[mi]  = *(const bf16x8*)&Qc [t*128 + (e ^ ((t&7)<<3))]; }
      #pragma unroll
      for (int mi=0;mi<2;mi++)
        #pragma unroll
        for (int ni=0;ni<2;ni++)
          oac[mi][ni] = mfma16(aq[mi], bst[ni], oac[mi][ni]);
    }
    #pragma unroll
    for (int kk=0;kk<2;kk++){
      int e = kk*32 + lk*8;
      bf16x8 bu[2], am[2];
      #pragma unroll
      for (int ni=0;ni<2;ni++){ int j = jq + ni*16 + lr; bu[ni] = *(const bf16x8*)&Utl[j*64 + (e ^ ((j&7)<<3))]; }
      #pragma unroll
      for (int mi=0;mi<2;mi++){ int t = tq + mi*16 + lr; am[mi] = *(const bf16x8*)&Mc [t*64 + (e ^ ((t&7)<<3))]; }
      #pragma unroll
      for (int mi=0;mi<2;mi++)
        #pragma unroll
        for (int ni=0;ni<2;ni++)
          oac[mi][ni] = mfma16(am[mi], bu[ni], oac[mi][ni]);
    }
    #pragma unroll
    for (int mi=0;mi<2;mi++)
      #pragma unroll
      for (int ni=0;ni<2;ni++)
        #pragma unroll
        for (int r=0;r<4;r++){
          int t = tq + mi*16 + lk*4 + r;
          int j = jq + ni*16 + lr;
          obase[(size_t)(c*64 + t)*DK_ + j] = f2bf(oac[mi][ni][r]);
        }

    #pragma unroll
    for (int kk=0;kk<2;kk++){
      int e = kk*32 + lk*8;
      bf16x8 au[2], bk[4];
      #pragma unroll
      for (int mj=0;mj<2;mj++){ int j = jq + mj*16 + lr; au[mj] = *(const bf16x8*)&Utl[j*64 + (e ^ ((j&7)<<3))]; }
      #pragma unroll
      for (int nd=0;nd<4;nd++){ int d = dq + nd*16 + lr; bk[nd] = *(const bf16x8*)&Ktc[d*64 + (e ^ ((d&7)<<3))]; }
      #pragma unroll
      for (int mj=0;mj<2;mj++)
        #pragma unroll
        for (int nd=0;nd<4;nd++)
          Stf[mj][nd] = mfma16(au[mj], bk[nd], Stf[mj][nd]);
    }
    __syncthreads();
  }
}

__global__ __launch_bounds__(256) void k_norm(const ushort* __restrict__ OH, const float* __restrict__ gw,
                                              ushort* __restrict__ O2){
  const int blk = blockIdx.x;
  const int b = blk >> 12, l = blk & 4095;
  const int t = threadIdx.x;
  const int h = t >> 4, d0 = (t & 15) * 8;
  const ushort* ip = OH + ((size_t)(b*H_ + h)*L_ + l)*DK_ + d0;
  ushort4 a = *(const ushort4*)ip, c = *(const ushort4*)(ip+4);
  float x[8];
  x[0]=bf2f(a.x); x[1]=bf2f(a.y); x[2]=bf2f(a.z); x[3]=bf2f(a.w);
  x[4]=bf2f(c.x); x[5]=bf2f(c.y); x[6]=bf2f(c.z); x[7]=bf2f(c.w);
  float ss = 0.f;
  #pragma unroll
  for (int j=0;j<8;j++) ss += x[j]*x[j];
  #pragma unroll
  for (int m=1;m<16;m<<=1) ss += __shfl_xor(ss, m, 64);
  float sc = rsqrtf(ss * (1.f/128.f) + 1e-5f);
  ushort* opp = O2 + (size_t)blk*D_ + h*DK_ + d0;
  ushort4 o0, o1;
  o0.x=f2bf(x[0]*sc*gw[d0+0]); o0.y=f2bf(x[1]*sc*gw[d0+1]);
  o0.z=f2bf(x[2]*sc*gw[d0+2]); o0.w=f2bf(x[3]*sc*gw[d0+3]);
  o1.x=f2bf(x[4]*sc*gw[d0+4]); o1.y=f2bf(x[5]*sc*gw[d0+5]);
  o1.z=f2bf(x[6]*sc*gw[d0+6]); o1.w=f2bf(x[7]*sc*gw[d0+7]);
  *(ushort4*)opp = o0; *(ushort4*)(opp+4) = o1;
}

extern "C" void kernel_launch(void* const* d_in, const int* in_sizes, int n_in,
                              void* d_out, int out_size, void* d_ws, size_t ws_size,
                              hipStream_t stream) {
  (void)in_sizes; (void)n_in; (void)out_size; (void)ws_size;
  const float* hidden  = (const float*)d_in[0];
  const float* w_cattn = (const float*)d_in[1];
  const float* wq_conv = (const float*)d_in[2];
  const float* wk_conv = (const float*)d_in[3];
  const float* wv_conv = (const float*)d_in[4];
  const float* w_beta  = (const float*)d_in[5];
  const float* o_nw    = (const float*)d_in[6];
  const float* w_o     = (const float*)d_in[7];
  float* out = (float*)d_out;

  char* W = (char*)d_ws;                              // total 260,046,848 B (known-good size)
  ushort* A16   = (ushort*)(W);                       // 32MB ; -> OH after gemm1
  ushort* WcatT = (ushort*)(W + 33554432u);           // 24MB [6144][2048]; dead after gemm1
  ushort* WoT   = (ushort*)(W + 33554432u);           //  8MB (alias, written after gemm1)
  float*  BETA  = (float*) (W + 41943040u);           // 512KB (alias in dead WcatT region)
  ushort* WBT   = (ushort*)(W + 42467328u);           // 64KB  (alias in dead WcatT region)
  ushort* QKV   = (ushort*)(W + 58720256u);           // 96MB; dead after conv
  ushort* TB    = (ushort*)(W + 58720256u);           // 16MB (alias in dead QKV)
  ushort* MM    = (ushort*)(W + 75497472u);           // 16MB
  ushort* KT    = (ushort*)(W + 92274688u);           // 32MB
  ushort* O2    = (ushort*)(W + 125829120u);          // 32MB
  ushort* QH    = (ushort*)(W + 159383552u);          // 32MB
  ushort* KH    = (ushort*)(W + 192937984u);          // 32MB
  ushort* VH    = (ushort*)(W + 226492416u);          // 32MB -> end 260,046,848
  ushort* OH = A16;

  k_cast<<<4096, 256, 0, stream>>>(hidden, A16, (BL_*D_)/4);
  k_transpose_cast<<<dim3(ND3/32, D_/32), dim3(32,8), 0, stream>>>(w_cattn, WcatT, D_, ND3);
  k_gemmks<1><<<dim3(ND3/256, BL_/256), 512, 0, stream>>>(A16, WcatT, QKV, BL_, ND3, D_);
  // WcatT region dead from here on
  k_transpose_cast<<<dim3(D_/32, D_/32), dim3(32,8), 0, stream>>>(w_o, WoT, D_, D_);
  k_wbt<<<8, 256, 0, stream>>>(w_beta, WBT);
  k_beta2<<<512, 64, 0, stream>>>(A16, WBT, BETA);
  k_conv2<<<dim3(128, 3, 2), 256, 0, stream>>>(QKV, wq_conv, wk_conv, wv_conv, QH, KH, VH);
  k_prep<<<2048, 64, 0, stream>>>(QH, KH, BETA, TB, MM, KT);
  k_chunkrec<<<64, 256, 0, stream>>>(QH, KH, VH, TB, MM, KT, OH);
  k_norm<<<BL_, 256, 0, stream>>>(OH, o_nw, O2);
  k_gemmks<0><<<dim3(D_/256, BL_/256), 512, 0, stream>>>(O2, WoT, out, BL_, D_, D_);
}

// Round 8
// 753.809 us; speedup vs baseline: 8.1962x; 1.0051x over previous
//
#include <hip/hip_runtime.h>
#include <stdint.h>

#define B_   2
#define L_   4096
#define D_   2048
#define H_   16
#define DK_  128
#define ND3  6144
#define BL_  8192

typedef __bf16 bf16x8 __attribute__((ext_vector_type(8)));
typedef float  f32x4  __attribute__((ext_vector_type(4)));

__device__ __forceinline__ float bf2f(ushort u){ return __uint_as_float(((unsigned)u)<<16); }
__device__ __forceinline__ ushort f2bf(float f){
  unsigned u = __float_as_uint(f);
  unsigned r = u + 0x7FFFu + ((u>>16)&1u);
  return (ushort)(r>>16);
}
__device__ __forceinline__ f32x4 mfma16(bf16x8 a, bf16x8 b, f32x4 c){
  return __builtin_amdgcn_mfma_f32_16x16x32_bf16(a, b, c, 0, 0, 0);
}

__global__ __launch_bounds__(256) void k_cast(const float* __restrict__ x, ushort* __restrict__ y, int n4){
  int i = blockIdx.x*blockDim.x + threadIdx.x;
  int stride = gridDim.x*blockDim.x;
  for (; i < n4; i += stride){
    float4 v = ((const float4*)x)[i];
    ushort4 o; o.x=f2bf(v.x); o.y=f2bf(v.y); o.z=f2bf(v.z); o.w=f2bf(v.w);
    ((ushort4*)y)[i] = o;
  }
}

__global__ __launch_bounds__(256) void k_transpose_cast(const float* __restrict__ in, ushort* __restrict__ out,
                                                        int R, int C){
  __shared__ float tile[32][33];
  int c0 = blockIdx.x*32, r0 = blockIdx.y*32;
  int tx = threadIdx.x, ty = threadIdx.y;
  #pragma unroll
  for (int i=0;i<32;i+=8) tile[ty+i][tx] = in[(size_t)(r0+ty+i)*C + (c0+tx)];
  __syncthreads();
  #pragma unroll
  for (int i=0;i<32;i+=8) out[(size_t)(c0+ty+i)*R + (r0+tx)] = f2bf(tile[tx][ty+i]);
}

// ============ 256x256 GEMM, 4-slot ring, 1 barrier/phase, counted lgkmcnt ============
// 8 waves (2M x 4N). Phase p computes K-slice of 32 from slot p&3, stages phase p+3's
// slice into slot (p+3)&3 (= slot (p-1)&3, safe: its reads ended before the barrier
// closing phase p-1). Single s_barrier per phase, vmcnt(8) (stages of p,p-1 stay in
// flight; p-2's -> slot p+1 drained). MFMA split: lgkmcnt(4) releases af0-3/bfr0-3
// for the first 16 MFMAs while af4-7 drain; lgkmcnt(0) before the last 16.
template<int OUT_BF16>
__global__ __launch_bounds__(512, 1) void k_gemmks(const ushort* __restrict__ A, const ushort* __restrict__ Bt,
                                                   void* __restrict__ Cv, int M, int N, int K){
  __shared__ ushort LDSB[65536];   // 128 KB = 4 slots x (A 16KB | B 16KB)
  char* lds = (char*)LDSB;
  const int tid = threadIdx.x, lane = tid & 63, w = tid >> 6;
  const int wm = w >> 2, wn = w & 3;
  int nwg = gridDim.x*gridDim.y;
  int id  = blockIdx.y*gridDim.x + blockIdx.x;
  int sw  = ((nwg & 7) == 0) ? ((id & 7)*(nwg >> 3) + (id >> 3)) : id;
  const int bx = sw % gridDim.x, by = sw / gridDim.x;
  const int m0 = by*256, n0 = bx*256;
  const int NT = K >> 6;            // K-tiles of 64
  const int NP = NT*2;              // K-slices of 32; K=2048 -> 64 phases, %4==0
  const size_t rowb = (size_t)K*2;

  f32x4 acc[8][4];
  #pragma unroll
  for (int i=0;i<8;i++)
    #pragma unroll
    for (int j=0;j<4;j++) acc[i][j] = (f32x4){0.f,0.f,0.f,0.f};

  const int c0 = tid, c1 = tid + 512;
  const int r0c = ((c0>>6)<<4) + (c0&15), h0 = (c0>>4)&3;
  const int r1c = ((c1>>6)<<4) + (c1&15), h1 = (c1>>4)&3;
  const char* gA = (const char*)A  + (size_t)m0*rowb;
  const char* gB = (const char*)Bt + (size_t)n0*rowb;

  auto stage = [&](int slot, int tile, int s){
    const char* ga = gA + (size_t)tile*128 + s*64;
    const char* gb = gB + (size_t)tile*128 + s*64;
    char* la = lds + slot*32768;
    char* lb = la + 16384;
    __builtin_amdgcn_global_load_lds((const __attribute__((address_space(1))) void*)(ga + (size_t)r0c*rowb + h0*16),
                                     (__attribute__((address_space(3))) void*)(la + c0*16), 16, 0, 0);
    __builtin_amdgcn_global_load_lds((const __attribute__((address_space(1))) void*)(ga + (size_t)r1c*rowb + h1*16),
                                     (__attribute__((address_space(3))) void*)(la + c1*16), 16, 0, 0);
    __builtin_amdgcn_global_load_lds((const __attribute__((address_space(1))) void*)(gb + (size_t)r0c*rowb + h0*16),
                                     (__attribute__((address_space(3))) void*)(lb + c0*16), 16, 0, 0);
    __builtin_amdgcn_global_load_lds((const __attribute__((address_space(1))) void*)(gb + (size_t)r1c*rowb + h1*16),
                                     (__attribute__((address_space(3))) void*)(lb + c1*16), 16, 0, 0);
  };

  // prologue: stage phases 0,1,2 into slots 0,1,2; wait slot0 landed (8 newest may pend)
  stage(0, 0, 0);
  stage(1, 0, 1);
  stage(2, 1, 0);
  __builtin_amdgcn_sched_barrier(0);
  asm volatile("s_waitcnt vmcnt(8)" ::: "memory");
  __builtin_amdgcn_s_barrier();
  __builtin_amdgcn_sched_barrier(0);

  for (int pb = 0; pb < NP; pb += 4){
    #pragma unroll
    for (int q = 0; q < 4; ++q){
      const int p = pb + q;                 // phase; slot = q
      const char* base = lds + q*32768;
      bf16x8 af[8], bfr[4];
      // group 1: af0-3 + bfr0-3 (8 ds_reads)
      #pragma unroll
      for (int i=0;i<4;i++) af[i]  = *(const bf16x8*)(base + (wm*128 + i*16)*64 + lane*16);
      #pragma unroll
      for (int j=0;j<4;j++) bfr[j] = *(const bf16x8*)(base + 16384 + (wn*64 + j*16)*64 + lane*16);
      __builtin_amdgcn_sched_barrier(0);
      // group 2: af4-7 (4 ds_reads)
      #pragma unroll
      for (int i=4;i<8;i++) af[i]  = *(const bf16x8*)(base + (wm*128 + i*16)*64 + lane*16);
      // stage next+3 (vmem only, doesn't affect lgkmcnt)
      {
        int ps = p + 3;
        int tile = ps >> 1; if (tile >= NT) tile = NT - 1;   // tail: dummy stage, never read
        stage(ps & 3, tile, ps & 1);
      }
      __builtin_amdgcn_sched_barrier(0);
      asm volatile("s_waitcnt lgkmcnt(4)" ::: "memory");   // af0-3, bfr0-3 landed
      __builtin_amdgcn_sched_barrier(0);
      __builtin_amdgcn_s_setprio(1);
      #pragma unroll
      for (int i=0;i<4;i++)
        #pragma unroll
        for (int j=0;j<4;j++)
          acc[i][j] = mfma16(af[i], bfr[j], acc[i][j]);
      __builtin_amdgcn_sched_barrier(0);
      asm volatile("s_waitcnt lgkmcnt(0)" ::: "memory");   // af4-7 landed
      __builtin_amdgcn_sched_barrier(0);
      #pragma unroll
      for (int i=4;i<8;i++)
        #pragma unroll
        for (int j=0;j<4;j++)
          acc[i][j] = mfma16(af[i], bfr[j], acc[i][j]);
      __builtin_amdgcn_s_setprio(0);
      __builtin_amdgcn_sched_barrier(0);
      asm volatile("s_waitcnt vmcnt(8)" ::: "memory");
      __builtin_amdgcn_s_barrier();
      __builtin_amdgcn_sched_barrier(0);
    }
  }

  const int rbase = m0 + wm*128 + (lane>>4)*4;
  const int cbase = n0 + wn*64 + (lane&15);
  #pragma unroll
  for (int fi=0;fi<8;fi++)
    #pragma unroll
    for (int fj=0;fj<4;fj++)
      #pragma unroll
      for (int r=0;r<4;r++){
        int row = rbase + fi*16 + r;
        int col = cbase + fj*16;
        float v = acc[fi][fj][r];
        if (OUT_BF16) ((ushort*)Cv)[(size_t)row*N + col] = f2bf(v);
        else          ((float*) Cv)[(size_t)row*N + col] = v;
      }
}

// ---------------- wbT[h][d] bf16 <- wb[d][h] f32 ----------------
__global__ __launch_bounds__(256) void k_wbt(const float* __restrict__ wb, ushort* __restrict__ wbT){
  int d = blockIdx.x*256 + threadIdx.x;
  #pragma unroll
  for (int h=0;h<16;h++) wbT[(size_t)h*2048 + d] = f2bf(wb[(size_t)d*16 + h]);
}

// ---------------- beta = sigmoid(A16 @ wbT^T) via MFMA; out [b][h][l] f32 ----------------
__global__ __launch_bounds__(64) void k_beta2(const ushort* __restrict__ A16, const ushort* __restrict__ wbT,
                                              float* __restrict__ beta){
  const int rt = blockIdx.x;
  const int lane = threadIdx.x;
  const int lr = lane & 15, lk8 = (lane>>4)*8;
  const int r0 = rt*16;
  f32x4 acc0 = (f32x4){0.f,0.f,0.f,0.f};
  f32x4 acc1 = (f32x4){0.f,0.f,0.f,0.f};
  for (int k0=0; k0<2048; k0+=64){
    bf16x8 a0 = *(const bf16x8*)&A16[(size_t)(r0+lr)*2048 + k0 + lk8];
    bf16x8 b0 = *(const bf16x8*)&wbT[(size_t)lr*2048 + k0 + lk8];
    bf16x8 a1 = *(const bf16x8*)&A16[(size_t)(r0+lr)*2048 + k0 + 32 + lk8];
    bf16x8 b1 = *(const bf16x8*)&wbT[(size_t)lr*2048 + k0 + 32 + lk8];
    acc0 = mfma16(a0, b0, acc0);
    acc1 = mfma16(a1, b1, acc1);
  }
  const int h = lane & 15;
  const int rbase = r0 + (lane>>4)*4;
  #pragma unroll
  for (int r=0;r<4;r++){
    int row = rbase + r;
    int b = row >> 12, l = row & 4095;
    float sg = 1.f/(1.f + __expf(-(acc0[r] + acc1[r])));
    beta[((size_t)(b*H_ + h))*L_ + l] = sg;
  }
}

// ---------------- conv(K=4, causal)+SiLU+heads+l2norm, sliding window over L ----------------
__global__ __launch_bounds__(256) void k_conv2(const ushort* __restrict__ qkv,
      const float* __restrict__ wq, const float* __restrict__ wk, const float* __restrict__ wv,
      ushort* __restrict__ QH, ushort* __restrict__ KH, ushort* __restrict__ VH){
  const int seg = blockIdx.x, part = blockIdx.y, b = blockIdx.z;
  const int t = threadIdx.x;
  const int ch = t*8;
  const int h = t >> 4, d0 = (t & 15)*8;
  const float* wc = (part==0) ? wq : (part==1) ? wk : wv;
  ushort* outs = ((part==0) ? QH : (part==1) ? KH : VH)
                 + ((size_t)(b*H_ + h)*L_)*DK_ + d0;
  const ushort* inp = qkv + ((size_t)b*L_)*ND3 + part*D_ + ch;

  float wgt[4][8];
  #pragma unroll
  for (int j=0;j<8;j++){
    float4 w4 = *(const float4*)&wc[(ch + j)*4];
    wgt[0][j]=w4.x; wgt[1][j]=w4.y; wgt[2][j]=w4.z; wgt[3][j]=w4.w;
  }

  const int l0 = seg*32;
  float x0[8], x1[8], x2[8];
  {
    float* dsts[3] = {x0, x1, x2};
    #pragma unroll
    for (int i=0;i<3;i++){
      int l = l0 - 3 + i;
      float* d = dsts[i];
      if (l >= 0){
        const ushort* p = inp + (size_t)l*ND3;
        ushort4 a = *(const ushort4*)p, c = *(const ushort4*)(p+4);
        d[0]=bf2f(a.x); d[1]=bf2f(a.y); d[2]=bf2f(a.z); d[3]=bf2f(a.w);
        d[4]=bf2f(c.x); d[5]=bf2f(c.y); d[6]=bf2f(c.z); d[7]=bf2f(c.w);
      } else {
        #pragma unroll
        for (int j=0;j<8;j++) d[j] = 0.f;
      }
    }
  }

  for (int i=0;i<32;i++){
    const int l = l0 + i;
    float cur[8];
    {
      const ushort* p = inp + (size_t)l*ND3;
      ushort4 a = *(const ushort4*)p, c = *(const ushort4*)(p+4);
      cur[0]=bf2f(a.x); cur[1]=bf2f(a.y); cur[2]=bf2f(a.z); cur[3]=bf2f(a.w);
      cur[4]=bf2f(c.x); cur[5]=bf2f(c.y); cur[6]=bf2f(c.z); cur[7]=bf2f(c.w);
    }
    float y[8]; float ss = 0.f;
    #pragma unroll
    for (int j=0;j<8;j++){
      float yy = x0[j]*wgt[0][j] + x1[j]*wgt[1][j] + x2[j]*wgt[2][j] + cur[j]*wgt[3][j];
      yy = yy / (1.f + __expf(-yy));     // SiLU
      y[j] = yy; ss += yy*yy;
    }
    if (part < 2){
      #pragma unroll
      for (int m=1;m<16;m<<=1) ss += __shfl_xor(ss, m, 64);
      float sc = rsqrtf(ss + 1e-12f);
      #pragma unroll
      for (int j=0;j<8;j++) y[j] *= sc;
    }
    ushort4 o0, o1;
    o0.x=f2bf(y[0]); o0.y=f2bf(y[1]); o0.z=f2bf(y[2]); o0.w=f2bf(y[3]);
    o1.x=f2bf(y[4]); o1.y=f2bf(y[5]); o1.z=f2bf(y[6]); o1.w=f2bf(y[7]);
    ushort* op = outs + (size_t)l*DK_;
    *(ushort4*)op = o0; *(ushort4*)(op+4) = o1;
    #pragma unroll
    for (int j=0;j<8;j++){ x0[j]=x1[j]; x1[j]=x2[j]; x2[j]=cur[j]; }
  }
}

// ---------------- phase 1: per-chunk Tb, M, Kt ----------------
__global__ __launch_bounds__(64) void k_prep(const ushort* __restrict__ QH, const ushort* __restrict__ KH,
      const float* __restrict__ BETA, ushort* __restrict__ TB, ushort* __restrict__ MM,
      ushort* __restrict__ KT){
  const int bid = blockIdx.x, bh = bid>>6, c = bid&63;
  const int lane = threadIdx.x;
  __shared__ ushort Ks[64][136];
  __shared__ ushort Qs[64][136];
  __shared__ float As[64][64];
  __shared__ float Ts[64][64];
  __shared__ float bs[64];
  const ushort* kg = KH + ((size_t)bh*L_ + c*64)*DK_;
  const ushort* qg = QH + ((size_t)bh*L_ + c*64)*DK_;
  {
    const uint4* ks4 = (const uint4*)(kg + (size_t)lane*DK_);
    const uint4* qs4 = (const uint4*)(qg + (size_t)lane*DK_);
    uint4* kd = (uint4*)&Ks[lane][0];
    uint4* qd = (uint4*)&Qs[lane][0];
    #pragma unroll
    for (int i=0;i<16;i++){ kd[i] = ks4[i]; qd[i] = qs4[i]; }
    bs[lane] = BETA[(size_t)bh*L_ + c*64 + lane];
  }
  __syncthreads();
  const int lr = lane&15, lk = lane>>4;
  {
    f32x4 gac[4][4];
    #pragma unroll
    for (int i=0;i<4;i++)
      #pragma unroll
      for (int j=0;j<4;j++) gac[i][j] = (f32x4){0.f,0.f,0.f,0.f};
    #pragma unroll
    for (int kk=0;kk<4;kk++){
      bf16x8 fr[4];
      #pragma unroll
      for (int i=0;i<4;i++) fr[i] = *(const bf16x8*)&Ks[i*16+lr][kk*32 + lk*8];
      #pragma unroll
      for (int mi=0;mi<4;mi++)
        #pragma unroll
        for (int ni=0;ni<4;ni++)
          gac[mi][ni] = mfma16(fr[mi], fr[ni], gac[mi][ni]);
    }
    #pragma unroll
    for (int mi=0;mi<4;mi++)
      #pragma unroll
      for (int ni=0;ni<4;ni++)
        #pragma unroll
        for (int r=0;r<4;r++){
          int t = mi*16 + lk*4 + r, s = ni*16 + lr;
          As[t][s] = (s < t) ? (bs[t] * gac[mi][ni][r]) : 0.f;
        }
  }
  {
    f32x4 mac[4][4];
    #pragma unroll
    for (int i=0;i<4;i++)
      #pragma unroll
      for (int j=0;j<4;j++) mac[i][j] = (f32x4){0.f,0.f,0.f,0.f};
    #pragma unroll
    for (int kk=0;kk<4;kk++){
      bf16x8 frq[4], frk[4];
      #pragma unroll
      for (int i=0;i<4;i++){
        frq[i] = *(const bf16x8*)&Qs[i*16+lr][kk*32 + lk*8];
        frk[i] = *(const bf16x8*)&Ks[i*16+lr][kk*32 + lk*8];
      }
      #pragma unroll
      for (int mi=0;mi<4;mi++)
        #pragma unroll
        for (int ni=0;ni<4;ni++)
          mac[mi][ni] = mfma16(frq[mi], frk[ni], mac[mi][ni]);
    }
    #pragma unroll
    for (int mi=0;mi<4;mi++)
      #pragma unroll
      for (int ni=0;ni<4;ni++)
        #pragma unroll
        for (int r=0;r<4;r++){
          int t = mi*16 + lk*4 + r, s = ni*16 + lr;
          float v = (s <= t) ? mac[mi][ni][r] : 0.f;
          MM[(size_t)bid*4096 + t*64 + s] = f2bf(v);
        }
  }
  __syncthreads();
  for (int t=0;t<64;t++){
    float a = (t==lane) ? 1.f : 0.f;
    for (int s=0;s<t;s++) a -= As[t][s] * Ts[s][lane];
    Ts[t][lane] = a;
  }
  {
    float bc = bs[lane];
    for (int t=0;t<64;t++)
      TB[(size_t)bid*4096 + t*64 + lane] = f2bf(Ts[t][lane] * bc);
  }
  for (int d2=0; d2<64; d2++){
    unsigned uu = *(const unsigned*)&Ks[lane][2*d2];
    KT[(size_t)bid*8192 + (size_t)(2*d2)*64 + lane]   = (ushort)(uu & 0xffffu);
    KT[(size_t)bid*8192 + (size_t)(2*d2+1)*64 + lane] = (ushort)(uu >> 16);
  }
}

template<int LRB, int GRB, int NB>
__device__ __forceinline__ void stage_swz(const ushort* __restrict__ g, ushort* l,
                                          int colOff, int w, int lane){
  for (int idx = w; idx < NB/1024; idx += 4){
    int off = idx*1024 + lane*16;
    int row = off / LRB;
    int inner = off & (LRB-1);
    int src = row*GRB + colOff + (inner ^ ((row&7)<<4));
    __builtin_amdgcn_global_load_lds(
      (const __attribute__((address_space(1))) void*)((const char*)g + src),
      (__attribute__((address_space(3))) void*)((char*)l + idx*1024), 16, 0, 0);
  }
}

__global__ __launch_bounds__(256) void k_chunkrec(const ushort* __restrict__ QH, const ushort* __restrict__ KH,
      const ushort* __restrict__ VH, const ushort* __restrict__ TB, const ushort* __restrict__ MM,
      const ushort* __restrict__ KT, ushort* __restrict__ OH){
  const int bid = blockIdx.x, bh = bid>>1, vh = bid&1;
  const int tid = threadIdx.x, lane = tid&63, w = tid>>6;
  __shared__ ushort Kc[64*128], Qc[64*128], Ktc[128*64], Tbc[64*64], Mc[64*64], Vc[64*64];
  __shared__ ushort Stl[64*128], Ztl[64*64], Utl[64*64];
  const int lr = lane&15, lk = lane>>4;
  const int tq = (w>>1)*32, jq = (w&1)*32;
  const int dq = (w>>1)*64;

  f32x4 Stf[2][4];
  #pragma unroll
  for (int a=0;a<2;a++)
    #pragma unroll
    for (int b=0;b<4;b++) Stf[a][b] = (f32x4){0.f,0.f,0.f,0.f};

  const ushort* kbase  = KH + ((size_t)bh*L_)*DK_;
  const ushort* qbase  = QH + ((size_t)bh*L_)*DK_;
  const ushort* vbase  = VH + ((size_t)bh*L_)*DK_;
  const ushort* tbase  = TB + ((size_t)bh*64)*4096;
  const ushort* mbase  = MM + ((size_t)bh*64)*4096;
  const ushort* ktbase = KT + ((size_t)bh*64)*8192;
  ushort* obase = OH + ((size_t)bh*L_)*DK_ + vh*64;

  for (int c=0; c<64; c++){
    stage_swz<256,256,16384>(kbase  + (size_t)c*8192, Kc,  0, w, lane);
    stage_swz<256,256,16384>(qbase  + (size_t)c*8192, Qc,  0, w, lane);
    stage_swz<128,128,16384>(ktbase + (size_t)c*8192, Ktc, 0, w, lane);
    stage_swz<128,128, 8192>(tbase  + (size_t)c*4096, Tbc, 0, w, lane);
    stage_swz<128,128, 8192>(mbase  + (size_t)c*4096, Mc,  0, w, lane);
    stage_swz<128,256, 8192>(vbase  + (size_t)c*8192, Vc,  vh*128, w, lane);
    #pragma unroll
    for (int mj=0;mj<2;mj++)
      #pragma unroll
      for (int nd=0;nd<4;nd++)
        #pragma unroll
        for (int r=0;r<4;r++){
          int j = jq + mj*16 + lk*4 + r;
          int d = dq + nd*16 + lr;
          Stl[j*128 + (d ^ ((j&7)<<3))] = f2bf(Stf[mj][nd][r]);
        }
    __syncthreads();

    f32x4 xac[2][2];
    #pragma unroll
    for (int i=0;i<2;i++)
      #pragma unroll
      for (int j2=0;j2<2;j2++) xac[i][j2] = (f32x4){0.f,0.f,0.f,0.f};
    #pragma unroll
    for (int kk=0;kk<4;kk++){
      int e = kk*32 + lk*8;
      bf16x8 bst[2], ak[2];
      #pragma unroll
      for (int ni=0;ni<2;ni++){ int j = jq + ni*16 + lr; bst[ni] = *(const bf16x8*)&Stl[j*128 + (e ^ ((j&7)<<3))]; }
      #pragma unroll
      for (int mi=0;mi<2;mi++){ int t = tq + mi*16 + lr; ak[mi]  = *(const bf16x8*)&Kc [t*128 + (e ^ ((t&7)<<3))]; }
      #pragma unroll
      for (int mi=0;mi<2;mi++)
        #pragma unroll
        for (int ni=0;ni<2;ni++)
          xac[mi][ni] = mfma16(ak[mi], bst[ni], xac[mi][ni]);
    }
    #pragma unroll
    for (int mi=0;mi<2;mi++)
      #pragma unroll
      for (int ni=0;ni<2;ni++)
        #pragma unroll
        for (int r=0;r<4;r++){
          int t = tq + mi*16 + lk*4 + r;
          int j = jq + ni*16 + lr;
          float v = bf2f(Vc[t*64 + (j ^ ((t&7)<<3))]);
          Ztl[j*64 + (t ^ ((j&7)<<3))] = f2bf(v - xac[mi][ni][r]);
        }
    __syncthreads();

    f32x4 uac[2][2];
    #pragma unroll
    for (int i=0;i<2;i++)
      #pragma unroll
      for (int j2=0;j2<2;j2++) uac[i][j2] = (f32x4){0.f,0.f,0.f,0.f};
    #pragma unroll
    for (int kk=0;kk<2;kk++){
      int e = kk*32 + lk*8;
      bf16x8 bz[2], at[2];
      #pragma unroll
      for (int ni=0;ni<2;ni++){ int j = jq + ni*16 + lr; bz[ni] = *(const bf16x8*)&Ztl[j*64 + (e ^ ((j&7)<<3))]; }
      #pragma unroll
      for (int mi=0;mi<2;mi++){ int t = tq + mi*16 + lr; at[mi] = *(const bf16x8*)&Tbc[t*64 + (e ^ ((t&7)<<3))]; }
      #pragma unroll
      for (int mi=0;mi<2;mi++)
        #pragma unroll
        for (int ni=0;ni<2;ni++)
          uac[mi][ni] = mfma16(at[mi], bz[ni], uac[mi][ni]);
    }
    #pragma unroll
    for (int mi=0;mi<2;mi++)
      #pragma unroll
      for (int ni=0;ni<2;ni++)
        #pragma unroll
        for (int r=0;r<4;r++){
          int t = tq + mi*16 + lk*4 + r;
          int j = jq + ni*16 + lr;
          Utl[j*64 + (t ^ ((j&7)<<3))] = f2bf(uac[mi][ni][r]);
        }
    __syncthreads();

    f32x4 oac[2][2];
    #pragma unroll
    for (int i=0;i<2;i++)
      #pragma unroll
      for (int j2=0;j2<2;j2++) oac[i][j2] = (f32x4){0.f,0.f,0.f,0.f};
    #pragma unroll
    for (int kk=0;kk<4;kk++){
      int e = kk*32 + lk*8;
      bf16x8 bst[2], aq[2];
      #pragma unroll
      for (int ni=0;ni<2;ni++){ int j = jq + ni*16 + lr; bst[ni] = *(const bf16x8*)&Stl[j*128 + (e ^ ((j&7)<<3))]; }
      #pragma unroll
      for (int mi=0;mi<2;mi++){ int t = tq + mi*16 + lr; aq[mi]  = *(const bf16x8*)&Qc [t*128 + (e ^ ((t&7)<<3))]; }
      #pragma unroll
      for (int mi=0;mi<2;mi++)
        #pragma unroll
        for (int ni=0;ni<2;ni++)
          oac[mi][ni] = mfma16(aq[mi], bst[ni], oac[mi][ni]);
    }
    #pragma unroll
    for (int kk=0;kk<2;kk++){
      int e = kk*32 + lk*8;
      bf16x8 bu[2], am[2];
      #pragma unroll
      for (int ni=0;ni<2;ni++){ int j = jq + ni*16 + lr; bu[ni] = *(const bf16x8*)&Utl[j*64 + (e ^ ((j&7)<<3))]; }
      #pragma unroll
      for (int mi=0;mi<2;mi++){ int t = tq + mi*16 + lr; am[mi] = *(const bf16x8*)&Mc [t*64 + (e ^ ((t&7)<<3))]; }
      #pragma unroll
      for (int mi=0;mi<2;mi++)
        #pragma unroll
        for (int ni=0;ni<2;ni++)
          oac[mi][ni] = mfma16(am[mi], bu[ni], oac[mi][ni]);
    }
    #pragma unroll
    for (int mi=0;mi<2;mi++)
      #pragma unroll
      for (int ni=0;ni<2;ni++)
        #pragma unroll
        for (int r=0;r<4;r++){
          int t = tq + mi*16 + lk*4 + r;
          int j = jq + ni*16 + lr;
          obase[(size_t)(c*64 + t)*DK_ + j] = f2bf(oac[mi][ni][r]);
        }

    #pragma unroll
    for (int kk=0;kk<2;kk++){
      int e = kk*32 + lk*8;
      bf16x8 au[2], bk[4];
      #pragma unroll
      for (int mj=0;mj<2;mj++){ int j = jq + mj*16 + lr; au[mj] = *(const bf16x8*)&Utl[j*64 + (e ^ ((j&7)<<3))]; }
      #pragma unroll
      for (int nd=0;nd<4;nd++){ int d = dq + nd*16 + lr; bk[nd] = *(const bf16x8*)&Ktc[d*64 + (e ^ ((d&7)<<3))]; }
      #pragma unroll
      for (int mj=0;mj<2;mj++)
        #pragma unroll
        for (int nd=0;nd<4;nd++)
          Stf[mj][nd] = mfma16(au[mj], bk[nd], Stf[mj][nd]);
    }
    __syncthreads();
  }
}

__global__ __launch_bounds__(256) void k_norm(const ushort* __restrict__ OH, const float* __restrict__ gw,
                                              ushort* __restrict__ O2){
  const int blk = blockIdx.x;
  const int b = blk >> 12, l = blk & 4095;
  const int t = threadIdx.x;
  const int h = t >> 4, d0 = (t & 15) * 8;
  const ushort* ip = OH + ((size_t)(b*H_ + h)*L_ + l)*DK_ + d0;
  ushort4 a = *(const ushort4*)ip, c = *(const ushort4*)(ip+4);
  float x[8];
  x[0]=bf2f(a.x); x[1]=bf2f(a.y); x[2]=bf2f(a.z); x[3]=bf2f(a.w);
  x[4]=bf2f(c.x); x[5]=bf2f(c.y); x[6]=bf2f(c.z); x[7]=bf2f(c.w);
  float ss = 0.f;
  #pragma unroll
  for (int j=0;j<8;j++) ss += x[j]*x[j];
  #pragma unroll
  for (int m=1;m<16;m<<=1) ss += __shfl_xor(ss, m, 64);
  float sc = rsqrtf(ss * (1.f/128.f) + 1e-5f);
  ushort* opp = O2 + (size_t)blk*D_ + h*DK_ + d0;
  ushort4 o0, o1;
  o0.x=f2bf(x[0]*sc*gw[d0+0]); o0.y=f2bf(x[1]*sc*gw[d0+1]);
  o0.z=f2bf(x[2]*sc*gw[d0+2]); o0.w=f2bf(x[3]*sc*gw[d0+3]);
  o1.x=f2bf(x[4]*sc*gw[d0+4]); o1.y=f2bf(x[5]*sc*gw[d0+5]);
  o1.z=f2bf(x[6]*sc*gw[d0+6]); o1.w=f2bf(x[7]*sc*gw[d0+7]);
  *(ushort4*)opp = o0; *(ushort4*)(opp+4) = o1;
}

extern "C" void kernel_launch(void* const* d_in, const int* in_sizes, int n_in,
                              void* d_out, int out_size, void* d_ws, size_t ws_size,
                              hipStream_t stream) {
  (void)in_sizes; (void)n_in; (void)out_size; (void)ws_size;
  const float* hidden  = (const float*)d_in[0];
  const float* w_cattn = (const float*)d_in[1];
  const float* wq_conv = (const float*)d_in[2];
  const float* wk_conv = (const float*)d_in[3];
  const float* wv_conv = (const float*)d_in[4];
  const float* w_beta  = (const float*)d_in[5];
  const float* o_nw    = (const float*)d_in[6];
  const float* w_o     = (const float*)d_in[7];
  float* out = (float*)d_out;

  char* W = (char*)d_ws;                              // total 260,046,848 B (known-good size)
  ushort* A16   = (ushort*)(W);                       // 32MB ; -> OH after gemm1
  ushort* WcatT = (ushort*)(W + 33554432u);           // 24MB [6144][2048]; dead after gemm1
  ushort* WoT   = (ushort*)(W + 33554432u);           //  8MB (alias, written after gemm1)
  float*  BETA  = (float*) (W + 41943040u);           // 512KB (alias in dead WcatT region)
  ushort* WBT   = (ushort*)(W + 42467328u);           // 64KB  (alias in dead WcatT region)
  ushort* QKV   = (ushort*)(W + 58720256u);           // 96MB; dead after conv
  ushort* TB    = (ushort*)(W + 58720256u);           // 16MB (alias in dead QKV)
  ushort* MM    = (ushort*)(W + 75497472u);           // 16MB
  ushort* KT    = (ushort*)(W + 92274688u);           // 32MB
  ushort* O2    = (ushort*)(W + 125829120u);          // 32MB
  ushort* QH    = (ushort*)(W + 159383552u);          // 32MB
  ushort* KH    = (ushort*)(W + 192937984u);          // 32MB
  ushort* VH    = (ushort*)(W + 226492416u);          // 32MB -> end 260,046,848
  ushort* OH = A16;

  k_cast<<<4096, 256, 0, stream>>>(hidden, A16, (BL_*D_)/4);
  k_transpose_cast<<<dim3(ND3/32, D_/32), dim3(32,8), 0, stream>>>(w_cattn, WcatT, D_, ND3);
  k_gemmks<1><<<dim3(ND3/256, BL_/256), 512, 0, stream>>>(A16, WcatT, QKV, BL_, ND3, D_);
  // WcatT region dead from here on
  k_transpose_cast<<<dim3(D_/32, D_/32), dim3(32,8), 0, stream>>>(w_o, WoT, D_, D_);
  k_wbt<<<8, 256, 0, stream>>>(w_beta, WBT);
  k_beta2<<<512, 64, 0, stream>>>(A16, WBT, BETA);
  k_conv2<<<dim3(128, 3, 2), 256, 0, stream>>>(QKV, wq_conv, wk_conv, wv_conv, QH, KH, VH);
  k_prep<<<2048, 64, 0, stream>>>(QH, KH, BETA, TB, MM, KT);
  k_chunkrec<<<64, 256, 0, stream>>>(QH, KH, VH, TB, MM, KT, OH);
  k_norm<<<BL_, 256, 0, stream>>>(OH, o_nw, O2);
  k_gemmks<0><<<dim3(D_/256, BL_/256), 512, 0, stream>>>(O2, WoT, out, BL_, D_, D_);
}

// Round 9
// 710.278 us; speedup vs baseline: 8.6985x; 1.0613x over previous
//
#include <hip/hip_runtime.h>
#include <stdint.h>

#define B_   2
#define L_   4096
#define D_   2048
#define H_   16
#define DK_  128
#define ND3  6144
#define BL_  8192

typedef __bf16 bf16x8 __attribute__((ext_vector_type(8)));
typedef float  f32x4  __attribute__((ext_vector_type(4)));

__device__ __forceinline__ float bf2f(ushort u){ return __uint_as_float(((unsigned)u)<<16); }
__device__ __forceinline__ ushort f2bf(float f){
  unsigned u = __float_as_uint(f);
  unsigned r = u + 0x7FFFu + ((u>>16)&1u);
  return (ushort)(r>>16);
}
__device__ __forceinline__ f32x4 mfma16(bf16x8 a, bf16x8 b, f32x4 c){
  return __builtin_amdgcn_mfma_f32_16x16x32_bf16(a, b, c, 0, 0, 0);
}

#define BAR_LGKM() do{ __builtin_amdgcn_sched_barrier(0); \
  asm volatile("s_waitcnt lgkmcnt(0)" ::: "memory"); \
  __builtin_amdgcn_s_barrier(); \
  __builtin_amdgcn_sched_barrier(0);}while(0)
#define BAR_VMALL() do{ __builtin_amdgcn_sched_barrier(0); \
  asm volatile("s_waitcnt vmcnt(0) lgkmcnt(0)" ::: "memory"); \
  __builtin_amdgcn_s_barrier(); \
  __builtin_amdgcn_sched_barrier(0);}while(0)

__global__ __launch_bounds__(256) void k_cast(const float* __restrict__ x, ushort* __restrict__ y, int n4){
  int i = blockIdx.x*blockDim.x + threadIdx.x;
  int stride = gridDim.x*blockDim.x;
  for (; i < n4; i += stride){
    float4 v = ((const float4*)x)[i];
    ushort4 o; o.x=f2bf(v.x); o.y=f2bf(v.y); o.z=f2bf(v.z); o.w=f2bf(v.w);
    ((ushort4*)y)[i] = o;
  }
}

__global__ __launch_bounds__(256) void k_transpose_cast(const float* __restrict__ in, ushort* __restrict__ out,
                                                        int R, int C){
  __shared__ float tile[32][33];
  int c0 = blockIdx.x*32, r0 = blockIdx.y*32;
  int tx = threadIdx.x, ty = threadIdx.y;
  #pragma unroll
  for (int i=0;i<32;i+=8) tile[ty+i][tx] = in[(size_t)(r0+ty+i)*C + (c0+tx)];
  __syncthreads();
  #pragma unroll
  for (int i=0;i<32;i+=8) out[(size_t)(c0+ty+i)*R + (r0+tx)] = f2bf(tile[tx][ty+i]);
}

// ============ 256x256 GEMM, 4-slot ring, 1 barrier/phase, counted lgkmcnt ============
template<int OUT_BF16>
__global__ __launch_bounds__(512, 1) void k_gemmks(const ushort* __restrict__ A, const ushort* __restrict__ Bt,
                                                   void* __restrict__ Cv, int M, int N, int K){
  __shared__ ushort LDSB[65536];   // 128 KB = 4 slots x (A 16KB | B 16KB)
  char* lds = (char*)LDSB;
  const int tid = threadIdx.x, lane = tid & 63, w = tid >> 6;
  const int wm = w >> 2, wn = w & 3;
  int nwg = gridDim.x*gridDim.y;
  int id  = blockIdx.y*gridDim.x + blockIdx.x;
  int sw  = ((nwg & 7) == 0) ? ((id & 7)*(nwg >> 3) + (id >> 3)) : id;
  const int bx = sw % gridDim.x, by = sw / gridDim.x;
  const int m0 = by*256, n0 = bx*256;
  const int NT = K >> 6;
  const int NP = NT*2;
  const size_t rowb = (size_t)K*2;

  f32x4 acc[8][4];
  #pragma unroll
  for (int i=0;i<8;i++)
    #pragma unroll
    for (int j=0;j<4;j++) acc[i][j] = (f32x4){0.f,0.f,0.f,0.f};

  const int c0 = tid, c1 = tid + 512;
  const int r0c = ((c0>>6)<<4) + (c0&15), h0 = (c0>>4)&3;
  const int r1c = ((c1>>6)<<4) + (c1&15), h1 = (c1>>4)&3;
  const char* gA = (const char*)A  + (size_t)m0*rowb;
  const char* gB = (const char*)Bt + (size_t)n0*rowb;

  auto stage = [&](int slot, int tile, int s){
    const char* ga = gA + (size_t)tile*128 + s*64;
    const char* gb = gB + (size_t)tile*128 + s*64;
    char* la = lds + slot*32768;
    char* lb = la + 16384;
    __builtin_amdgcn_global_load_lds((const __attribute__((address_space(1))) void*)(ga + (size_t)r0c*rowb + h0*16),
                                     (__attribute__((address_space(3))) void*)(la + c0*16), 16, 0, 0);
    __builtin_amdgcn_global_load_lds((const __attribute__((address_space(1))) void*)(ga + (size_t)r1c*rowb + h1*16),
                                     (__attribute__((address_space(3))) void*)(la + c1*16), 16, 0, 0);
    __builtin_amdgcn_global_load_lds((const __attribute__((address_space(1))) void*)(gb + (size_t)r0c*rowb + h0*16),
                                     (__attribute__((address_space(3))) void*)(lb + c0*16), 16, 0, 0);
    __builtin_amdgcn_global_load_lds((const __attribute__((address_space(1))) void*)(gb + (size_t)r1c*rowb + h1*16),
                                     (__attribute__((address_space(3))) void*)(lb + c1*16), 16, 0, 0);
  };

  stage(0, 0, 0);
  stage(1, 0, 1);
  stage(2, 1, 0);
  __builtin_amdgcn_sched_barrier(0);
  asm volatile("s_waitcnt vmcnt(8)" ::: "memory");
  __builtin_amdgcn_s_barrier();
  __builtin_amdgcn_sched_barrier(0);

  for (int pb = 0; pb < NP; pb += 4){
    #pragma unroll
    for (int q = 0; q < 4; ++q){
      const int p = pb + q;
      const char* base = lds + q*32768;
      bf16x8 af[8], bfr[4];
      #pragma unroll
      for (int i=0;i<4;i++) af[i]  = *(const bf16x8*)(base + (wm*128 + i*16)*64 + lane*16);
      #pragma unroll
      for (int j=0;j<4;j++) bfr[j] = *(const bf16x8*)(base + 16384 + (wn*64 + j*16)*64 + lane*16);
      __builtin_amdgcn_sched_barrier(0);
      #pragma unroll
      for (int i=4;i<8;i++) af[i]  = *(const bf16x8*)(base + (wm*128 + i*16)*64 + lane*16);
      {
        int ps = p + 3;
        int tile = ps >> 1; if (tile >= NT) tile = NT - 1;
        stage(ps & 3, tile, ps & 1);
      }
      __builtin_amdgcn_sched_barrier(0);
      asm volatile("s_waitcnt lgkmcnt(4)" ::: "memory");
      __builtin_amdgcn_sched_barrier(0);
      __builtin_amdgcn_s_setprio(1);
      #pragma unroll
      for (int i=0;i<4;i++)
        #pragma unroll
        for (int j=0;j<4;j++)
          acc[i][j] = mfma16(af[i], bfr[j], acc[i][j]);
      __builtin_amdgcn_sched_barrier(0);
      asm volatile("s_waitcnt lgkmcnt(0)" ::: "memory");
      __builtin_amdgcn_sched_barrier(0);
      #pragma unroll
      for (int i=4;i<8;i++)
        #pragma unroll
        for (int j=0;j<4;j++)
          acc[i][j] = mfma16(af[i], bfr[j], acc[i][j]);
      __builtin_amdgcn_s_setprio(0);
      __builtin_amdgcn_sched_barrier(0);
      asm volatile("s_waitcnt vmcnt(8)" ::: "memory");
      __builtin_amdgcn_s_barrier();
      __builtin_amdgcn_sched_barrier(0);
    }
  }

  const int rbase = m0 + wm*128 + (lane>>4)*4;
  const int cbase = n0 + wn*64 + (lane&15);
  #pragma unroll
  for (int fi=0;fi<8;fi++)
    #pragma unroll
    for (int fj=0;fj<4;fj++)
      #pragma unroll
      for (int r=0;r<4;r++){
        int row = rbase + fi*16 + r;
        int col = cbase + fj*16;
        float v = acc[fi][fj][r];
        if (OUT_BF16) ((ushort*)Cv)[(size_t)row*N + col] = f2bf(v);
        else          ((float*) Cv)[(size_t)row*N + col] = v;
      }
}

// ---------------- wbT[h][d] bf16 <- wb[d][h] f32 ----------------
__global__ __launch_bounds__(256) void k_wbt(const float* __restrict__ wb, ushort* __restrict__ wbT){
  int d = blockIdx.x*256 + threadIdx.x;
  #pragma unroll
  for (int h=0;h<16;h++) wbT[(size_t)h*2048 + d] = f2bf(wb[(size_t)d*16 + h]);
}

// ---------------- beta = sigmoid(A16 @ wbT^T) via MFMA; out [b][h][l] f32 ----------------
__global__ __launch_bounds__(64) void k_beta2(const ushort* __restrict__ A16, const ushort* __restrict__ wbT,
                                              float* __restrict__ beta){
  const int rt = blockIdx.x;
  const int lane = threadIdx.x;
  const int lr = lane & 15, lk8 = (lane>>4)*8;
  const int r0 = rt*16;
  f32x4 acc0 = (f32x4){0.f,0.f,0.f,0.f};
  f32x4 acc1 = (f32x4){0.f,0.f,0.f,0.f};
  for (int k0=0; k0<2048; k0+=64){
    bf16x8 a0 = *(const bf16x8*)&A16[(size_t)(r0+lr)*2048 + k0 + lk8];
    bf16x8 b0 = *(const bf16x8*)&wbT[(size_t)lr*2048 + k0 + lk8];
    bf16x8 a1 = *(const bf16x8*)&A16[(size_t)(r0+lr)*2048 + k0 + 32 + lk8];
    bf16x8 b1 = *(const bf16x8*)&wbT[(size_t)lr*2048 + k0 + 32 + lk8];
    acc0 = mfma16(a0, b0, acc0);
    acc1 = mfma16(a1, b1, acc1);
  }
  const int h = lane & 15;
  const int rbase = r0 + (lane>>4)*4;
  #pragma unroll
  for (int r=0;r<4;r++){
    int row = rbase + r;
    int b = row >> 12, l = row & 4095;
    float sg = 1.f/(1.f + __expf(-(acc0[r] + acc1[r])));
    beta[((size_t)(b*H_ + h))*L_ + l] = sg;
  }
}

// ---------------- conv(K=4, causal)+SiLU+heads+l2norm, sliding window ----------------
__global__ __launch_bounds__(256) void k_conv2(const ushort* __restrict__ qkv,
      const float* __restrict__ wq, const float* __restrict__ wk, const float* __restrict__ wv,
      ushort* __restrict__ QH, ushort* __restrict__ KH, ushort* __restrict__ VH){
  const int seg = blockIdx.x, part = blockIdx.y, b = blockIdx.z;
  const int t = threadIdx.x;
  const int ch = t*8;
  const int h = t >> 4, d0 = (t & 15)*8;
  const float* wc = (part==0) ? wq : (part==1) ? wk : wv;
  ushort* outs = ((part==0) ? QH : (part==1) ? KH : VH)
                 + ((size_t)(b*H_ + h)*L_)*DK_ + d0;
  const ushort* inp = qkv + ((size_t)b*L_)*ND3 + part*D_ + ch;

  float wgt[4][8];
  #pragma unroll
  for (int j=0;j<8;j++){
    float4 w4 = *(const float4*)&wc[(ch + j)*4];
    wgt[0][j]=w4.x; wgt[1][j]=w4.y; wgt[2][j]=w4.z; wgt[3][j]=w4.w;
  }

  const int l0 = seg*32;
  float x0[8], x1[8], x2[8];
  {
    float* dsts[3] = {x0, x1, x2};
    #pragma unroll
    for (int i=0;i<3;i++){
      int l = l0 - 3 + i;
      float* d = dsts[i];
      if (l >= 0){
        const ushort* p = inp + (size_t)l*ND3;
        ushort4 a = *(const ushort4*)p, c = *(const ushort4*)(p+4);
        d[0]=bf2f(a.x); d[1]=bf2f(a.y); d[2]=bf2f(a.z); d[3]=bf2f(a.w);
        d[4]=bf2f(c.x); d[5]=bf2f(c.y); d[6]=bf2f(c.z); d[7]=bf2f(c.w);
      } else {
        #pragma unroll
        for (int j=0;j<8;j++) d[j] = 0.f;
      }
    }
  }

  for (int i=0;i<32;i++){
    const int l = l0 + i;
    float cur[8];
    {
      const ushort* p = inp + (size_t)l*ND3;
      ushort4 a = *(const ushort4*)p, c = *(const ushort4*)(p+4);
      cur[0]=bf2f(a.x); cur[1]=bf2f(a.y); cur[2]=bf2f(a.z); cur[3]=bf2f(a.w);
      cur[4]=bf2f(c.x); cur[5]=bf2f(c.y); cur[6]=bf2f(c.z); cur[7]=bf2f(c.w);
    }
    float y[8]; float ss = 0.f;
    #pragma unroll
    for (int j=0;j<8;j++){
      float yy = x0[j]*wgt[0][j] + x1[j]*wgt[1][j] + x2[j]*wgt[2][j] + cur[j]*wgt[3][j];
      yy = yy / (1.f + __expf(-yy));
      y[j] = yy; ss += yy*yy;
    }
    if (part < 2){
      #pragma unroll
      for (int m=1;m<16;m<<=1) ss += __shfl_xor(ss, m, 64);
      float sc = rsqrtf(ss + 1e-12f);
      #pragma unroll
      for (int j=0;j<8;j++) y[j] *= sc;
    }
    ushort4 o0, o1;
    o0.x=f2bf(y[0]); o0.y=f2bf(y[1]); o0.z=f2bf(y[2]); o0.w=f2bf(y[3]);
    o1.x=f2bf(y[4]); o1.y=f2bf(y[5]); o1.z=f2bf(y[6]); o1.w=f2bf(y[7]);
    ushort* op = outs + (size_t)l*DK_;
    *(ushort4*)op = o0; *(ushort4*)(op+4) = o1;
    #pragma unroll
    for (int j=0;j<8;j++){ x0[j]=x1[j]; x1[j]=x2[j]; x2[j]=cur[j]; }
  }
}

// ---------------- phase 1: per-chunk Tb, M, Kt ----------------
__global__ __launch_bounds__(64) void k_prep(const ushort* __restrict__ QH, const ushort* __restrict__ KH,
      const float* __restrict__ BETA, ushort* __restrict__ TB, ushort* __restrict__ MM,
      ushort* __restrict__ KT){
  const int bid = blockIdx.x, bh = bid>>6, c = bid&63;
  const int lane = threadIdx.x;
  __shared__ ushort Ks[64][136];
  __shared__ ushort Qs[64][136];
  __shared__ float As[64][64];
  __shared__ float Ts[64][64];
  __shared__ float bs[64];
  const ushort* kg = KH + ((size_t)bh*L_ + c*64)*DK_;
  const ushort* qg = QH + ((size_t)bh*L_ + c*64)*DK_;
  {
    const uint4* ks4 = (const uint4*)(kg + (size_t)lane*DK_);
    const uint4* qs4 = (const uint4*)(qg + (size_t)lane*DK_);
    uint4* kd = (uint4*)&Ks[lane][0];
    uint4* qd = (uint4*)&Qs[lane][0];
    #pragma unroll
    for (int i=0;i<16;i++){ kd[i] = ks4[i]; qd[i] = qs4[i]; }
    bs[lane] = BETA[(size_t)bh*L_ + c*64 + lane];
  }
  __syncthreads();
  const int lr = lane&15, lk = lane>>4;
  {
    f32x4 gac[4][4];
    #pragma unroll
    for (int i=0;i<4;i++)
      #pragma unroll
      for (int j=0;j<4;j++) gac[i][j] = (f32x4){0.f,0.f,0.f,0.f};
    #pragma unroll
    for (int kk=0;kk<4;kk++){
      bf16x8 fr[4];
      #pragma unroll
      for (int i=0;i<4;i++) fr[i] = *(const bf16x8*)&Ks[i*16+lr][kk*32 + lk*8];
      #pragma unroll
      for (int mi=0;mi<4;mi++)
        #pragma unroll
        for (int ni=0;ni<4;ni++)
          gac[mi][ni] = mfma16(fr[mi], fr[ni], gac[mi][ni]);
    }
    #pragma unroll
    for (int mi=0;mi<4;mi++)
      #pragma unroll
      for (int ni=0;ni<4;ni++)
        #pragma unroll
        for (int r=0;r<4;r++){
          int t = mi*16 + lk*4 + r, s = ni*16 + lr;
          As[t][s] = (s < t) ? (bs[t] * gac[mi][ni][r]) : 0.f;
        }
  }
  {
    f32x4 mac[4][4];
    #pragma unroll
    for (int i=0;i<4;i++)
      #pragma unroll
      for (int j=0;j<4;j++) mac[i][j] = (f32x4){0.f,0.f,0.f,0.f};
    #pragma unroll
    for (int kk=0;kk<4;kk++){
      bf16x8 frq[4], frk[4];
      #pragma unroll
      for (int i=0;i<4;i++){
        frq[i] = *(const bf16x8*)&Qs[i*16+lr][kk*32 + lk*8];
        frk[i] = *(const bf16x8*)&Ks[i*16+lr][kk*32 + lk*8];
      }
      #pragma unroll
      for (int mi=0;mi<4;mi++)
        #pragma unroll
        for (int ni=0;ni<4;ni++)
          mac[mi][ni] = mfma16(frq[mi], frk[ni], mac[mi][ni]);
    }
    #pragma unroll
    for (int mi=0;mi<4;mi++)
      #pragma unroll
      for (int ni=0;ni<4;ni++)
        #pragma unroll
        for (int r=0;r<4;r++){
          int t = mi*16 + lk*4 + r, s = ni*16 + lr;
          float v = (s <= t) ? mac[mi][ni][r] : 0.f;
          MM[(size_t)bid*4096 + t*64 + s] = f2bf(v);
        }
  }
  __syncthreads();
  for (int t=0;t<64;t++){
    float a = (t==lane) ? 1.f : 0.f;
    for (int s=0;s<t;s++) a -= As[t][s] * Ts[s][lane];
    Ts[t][lane] = a;
  }
  {
    float bc = bs[lane];
    for (int t=0;t<64;t++)
      TB[(size_t)bid*4096 + t*64 + lane] = f2bf(Ts[t][lane] * bc);
  }
  for (int d2=0; d2<64; d2++){
    unsigned uu = *(const unsigned*)&Ks[lane][2*d2];
    KT[(size_t)bid*8192 + (size_t)(2*d2)*64 + lane]   = (ushort)(uu & 0xffffu);
    KT[(size_t)bid*8192 + (size_t)(2*d2+1)*64 + lane] = (ushort)(uu >> 16);
  }
}

template<int LRB, int GRB, int NB, int XM>
__device__ __forceinline__ void stage_swz(const ushort* __restrict__ g, ushort* l,
                                          int colOff, int w, int lane){
  for (int idx = w; idx < NB/1024; idx += 4){
    int off = idx*1024 + lane*16;
    int row = off / LRB;
    int inner = off & (LRB-1);
    int src = row*GRB + colOff + (inner ^ ((row&XM)<<4));
    __builtin_amdgcn_global_load_lds(
      (const __attribute__((address_space(1))) void*)((const char*)g + src),
      (__attribute__((address_space(3))) void*)((char*)l + idx*1024), 16, 0, 0);
  }
}

// ======= chunk recurrence v2: 128 blocks (bh x dv-quarter), dbuf panels, raw barriers =======
// LDS 152KB: 2 x 68KB panel buffers {Kc,Qc,Ktc,Tbc,Mc,Vc} + Stl(8K) + Ztl(4K) + Utl(4K).
// Per chunk: prefetch(c+1)->nbuf issued at TOP; mid-chunk barriers are lgkmcnt-only;
// single vmcnt(0) drain at end-of-chunk (prefetch has whole chunk to land).
__global__ __launch_bounds__(256) void k_chunkrec(const ushort* __restrict__ QH, const ushort* __restrict__ KH,
      const ushort* __restrict__ VH, const ushort* __restrict__ TB, const ushort* __restrict__ MM,
      const ushort* __restrict__ KT, ushort* __restrict__ OH){
  // XCD-grouped mapping: the 4 dv-quarter siblings of one bh share panels -> same XCD
  const int p = blockIdx.x;           // 0..127
  const int xg = p & 7, slot = p >> 3;
  const int bh = xg + (slot >> 2)*8;
  const int vq = slot & 3;
  const int tid = threadIdx.x, lane = tid&63, w = tid>>6;
  const int lr = lane&15, lk = lane>>4;
  const int tw = w*16;                // t-strip for X/U/O
  const int dw = w*32;                // d-quarter for S-update

  __shared__ ushort SM[77824];        // 155,648 B
  ushort* Stl = SM + 69632;           // [32][128]
  ushort* Ztl = SM + 73728;           // [32][64]
  ushort* Utl = SM + 75776;           // [32][64]

  const ushort* kbase  = KH + ((size_t)bh*L_)*DK_;
  const ushort* qbase  = QH + ((size_t)bh*L_)*DK_;
  const ushort* vbase  = VH + ((size_t)bh*L_)*DK_;
  const ushort* tbase  = TB + ((size_t)bh*64)*4096;
  const ushort* mbase  = MM + ((size_t)bh*64)*4096;
  const ushort* ktbase = KT + ((size_t)bh*64)*8192;
  ushort* obase = OH + ((size_t)bh*L_)*DK_ + vq*32;

  auto stageall = [&](ushort* buf, int c){
    stage_swz<256,256,16384,7>(kbase  + (size_t)c*8192, buf,         0,     w, lane);
    stage_swz<256,256,16384,7>(qbase  + (size_t)c*8192, buf + 8192,  0,     w, lane);
    stage_swz<128,128,16384,7>(ktbase + (size_t)c*8192, buf + 16384, 0,     w, lane);
    stage_swz<128,128, 8192,7>(tbase  + (size_t)c*4096, buf + 24576, 0,     w, lane);
    stage_swz<128,128, 8192,7>(mbase  + (size_t)c*4096, buf + 28672, 0,     w, lane);
    stage_swz< 64,256, 4096,3>(vbase  + (size_t)c*8192, buf + 32768, vq*64, w, lane);
  };

  f32x4 Stf[2][2];
  #pragma unroll
  for (int a=0;a<2;a++)
    #pragma unroll
    for (int b=0;b<2;b++) Stf[a][b] = (f32x4){0.f,0.f,0.f,0.f};

  stageall(SM, 0);
  BAR_VMALL();

  for (int c=0; c<64; ++c){
    ushort* buf  = SM + (c&1)*34816;
    ushort* nbuf = SM + ((c+1)&1)*34816;
    const ushort* Kc  = buf;
    const ushort* Qc  = buf + 8192;
    const ushort* Ktc = buf + 16384;
    const ushort* Tbc = buf + 24576;
    const ushort* Mc  = buf + 28672;
    const ushort* Vc  = buf + 32768;

    if (c+1 < 64) stageall(nbuf, c+1);   // prefetch: lands any time before end-of-chunk drain

    // St (old state) -> LDS, swizzled; wave writes its d-quarter for all 32 j-rows
    #pragma unroll
    for (int mj=0;mj<2;mj++)
      #pragma unroll
      for (int nd=0;nd<2;nd++)
        #pragma unroll
        for (int r=0;r<4;r++){
          int j = mj*16 + lk*4 + r;
          int d = dw + nd*16 + lr;
          Stl[j*128 + (d ^ ((j&7)<<3))] = f2bf(Stf[mj][nd][r]);
        }
    BAR_LGKM();                          // B1: Stl visible (panels drained last chunk)

    // X = K · St^T   [t 16][j 32]
    f32x4 xac[2];
    xac[0] = (f32x4){0.f,0.f,0.f,0.f}; xac[1] = (f32x4){0.f,0.f,0.f,0.f};
    #pragma unroll
    for (int kk=0;kk<4;kk++){
      int e = kk*32 + lk*8;
      int ta = tw + lr;
      bf16x8 ak = *(const bf16x8*)&Kc[ta*128 + (e ^ ((ta&7)<<3))];
      #pragma unroll
      for (int ni=0;ni<2;ni++){
        int j = ni*16 + lr;
        bf16x8 bst = *(const bf16x8*)&Stl[j*128 + (e ^ ((j&7)<<3))];
        xac[ni] = mfma16(ak, bst, xac[ni]);
      }
    }
    // Z = V - X  -> Ztl transposed [j][t]
    #pragma unroll
    for (int ni=0;ni<2;ni++)
      #pragma unroll
      for (int r=0;r<4;r++){
        int t = tw + lk*4 + r;
        int j = ni*16 + lr;
        float v = bf2f(Vc[t*32 + (j ^ ((t&3)<<3))]);
        Ztl[j*64 + (t ^ ((j&7)<<3))] = f2bf(v - xac[ni][r]);
      }
    BAR_LGKM();                          // B2: Ztl visible

    // U = Tb · Z   [t 16][j 32]
    f32x4 uac[2];
    uac[0] = (f32x4){0.f,0.f,0.f,0.f}; uac[1] = (f32x4){0.f,0.f,0.f,0.f};
    #pragma unroll
    for (int kk=0;kk<2;kk++){
      int e = kk*32 + lk*8;
      int ta = tw + lr;
      bf16x8 at = *(const bf16x8*)&Tbc[ta*64 + (e ^ ((ta&7)<<3))];
      #pragma unroll
      for (int ni=0;ni<2;ni++){
        int j = ni*16 + lr;
        bf16x8 bz = *(const bf16x8*)&Ztl[j*64 + (e ^ ((j&7)<<3))];
        uac[ni] = mfma16(at, bz, uac[ni]);
      }
    }
    #pragma unroll
    for (int ni=0;ni<2;ni++)
      #pragma unroll
      for (int r=0;r<4;r++){
        int t = tw + lk*4 + r;
        int j = ni*16 + lr;
        Utl[j*64 + (t ^ ((j&7)<<3))] = f2bf(uac[ni][r]);
      }
    BAR_LGKM();                          // B3: Utl visible

    // O = Q·St^T + M·U  -> global
    f32x4 oac[2];
    oac[0] = (f32x4){0.f,0.f,0.f,0.f}; oac[1] = (f32x4){0.f,0.f,0.f,0.f};
    #pragma unroll
    for (int kk=0;kk<4;kk++){
      int e = kk*32 + lk*8;
      int ta = tw + lr;
      bf16x8 aq = *(const bf16x8*)&Qc[ta*128 + (e ^ ((ta&7)<<3))];
      #pragma unroll
      for (int ni=0;ni<2;ni++){
        int j = ni*16 + lr;
        bf16x8 bst = *(const bf16x8*)&Stl[j*128 + (e ^ ((j&7)<<3))];
        oac[ni] = mfma16(aq, bst, oac[ni]);
      }
    }
    #pragma unroll
    for (int kk=0;kk<2;kk++){
      int e = kk*32 + lk*8;
      int ta = tw + lr;
      bf16x8 am = *(const bf16x8*)&Mc[ta*64 + (e ^ ((ta&7)<<3))];
      #pragma unroll
      for (int ni=0;ni<2;ni++){
        int j = ni*16 + lr;
        bf16x8 bu = *(const bf16x8*)&Utl[j*64 + (e ^ ((j&7)<<3))];
        oac[ni] = mfma16(am, bu, oac[ni]);
      }
    }
    #pragma unroll
    for (int ni=0;ni<2;ni++)
      #pragma unroll
      for (int r=0;r<4;r++){
        int t = tw + lk*4 + r;
        int j = ni*16 + lr;
        obase[(size_t)(c*64 + t)*DK_ + j] = f2bf(oac[ni][r]);
      }

    // S-update: Stf[j 32][d-quarter 32] += Ut · Kt
    #pragma unroll
    for (int kk=0;kk<2;kk++){
      int e = kk*32 + lk*8;
      bf16x8 au[2], bk[2];
      #pragma unroll
      for (int mj=0;mj<2;mj++){ int j = mj*16 + lr; au[mj] = *(const bf16x8*)&Utl[j*64 + (e ^ ((j&7)<<3))]; }
      #pragma unroll
      for (int nd=0;nd<2;nd++){ int d = dw + nd*16 + lr; bk[nd] = *(const bf16x8*)&Ktc[d*64 + (e ^ ((d&7)<<3))]; }
      #pragma unroll
      for (int mj=0;mj<2;mj++)
        #pragma unroll
        for (int nd=0;nd<2;nd++)
          Stf[mj][nd] = mfma16(au[mj], bk[nd], Stf[mj][nd]);
    }
    BAR_VMALL();                         // end-of-chunk: prefetch landed; all reads of buf done
  }
}

__global__ __launch_bounds__(256) void k_norm(const ushort* __restrict__ OH, const float* __restrict__ gw,
                                              ushort* __restrict__ O2){
  const int blk = blockIdx.x;
  const int b = blk >> 12, l = blk & 4095;
  const int t = threadIdx.x;
  const int h = t >> 4, d0 = (t & 15) * 8;
  const ushort* ip = OH + ((size_t)(b*H_ + h)*L_ + l)*DK_ + d0;
  ushort4 a = *(const ushort4*)ip, c = *(const ushort4*)(ip+4);
  float x[8];
  x[0]=bf2f(a.x); x[1]=bf2f(a.y); x[2]=bf2f(a.z); x[3]=bf2f(a.w);
  x[4]=bf2f(c.x); x[5]=bf2f(c.y); x[6]=bf2f(c.z); x[7]=bf2f(c.w);
  float ss = 0.f;
  #pragma unroll
  for (int j=0;j<8;j++) ss += x[j]*x[j];
  #pragma unroll
  for (int m=1;m<16;m<<=1) ss += __shfl_xor(ss, m, 64);
  float sc = rsqrtf(ss * (1.f/128.f) + 1e-5f);
  ushort* opp = O2 + (size_t)blk*D_ + h*DK_ + d0;
  ushort4 o0, o1;
  o0.x=f2bf(x[0]*sc*gw[d0+0]); o0.y=f2bf(x[1]*sc*gw[d0+1]);
  o0.z=f2bf(x[2]*sc*gw[d0+2]); o0.w=f2bf(x[3]*sc*gw[d0+3]);
  o1.x=f2bf(x[4]*sc*gw[d0+4]); o1.y=f2bf(x[5]*sc*gw[d0+5]);
  o1.z=f2bf(x[6]*sc*gw[d0+6]); o1.w=f2bf(x[7]*sc*gw[d0+7]);
  *(ushort4*)opp = o0; *(ushort4*)(opp+4) = o1;
}

extern "C" void kernel_launch(void* const* d_in, const int* in_sizes, int n_in,
                              void* d_out, int out_size, void* d_ws, size_t ws_size,
                              hipStream_t stream) {
  (void)in_sizes; (void)n_in; (void)out_size; (void)ws_size;
  const float* hidden  = (const float*)d_in[0];
  const float* w_cattn = (const float*)d_in[1];
  const float* wq_conv = (const float*)d_in[2];
  const float* wk_conv = (const float*)d_in[3];
  const float* wv_conv = (const float*)d_in[4];
  const float* w_beta  = (const float*)d_in[5];
  const float* o_nw    = (const float*)d_in[6];
  const float* w_o     = (const float*)d_in[7];
  float* out = (float*)d_out;

  char* W = (char*)d_ws;                              // total 260,046,848 B (known-good size)
  ushort* A16   = (ushort*)(W);                       // 32MB ; -> OH after gemm1
  ushort* WcatT = (ushort*)(W + 33554432u);           // 24MB; dead after gemm1
  ushort* WoT   = (ushort*)(W + 33554432u);           //  8MB (alias, written after gemm1)
  float*  BETA  = (float*) (W + 41943040u);           // 512KB (alias in dead WcatT region)
  ushort* WBT   = (ushort*)(W + 42467328u);           // 64KB  (alias in dead WcatT region)
  ushort* QKV   = (ushort*)(W + 58720256u);           // 96MB; dead after conv
  ushort* TB    = (ushort*)(W + 58720256u);           // 16MB (alias in dead QKV)
  ushort* MM    = (ushort*)(W + 75497472u);           // 16MB
  ushort* KT    = (ushort*)(W + 92274688u);           // 32MB
  ushort* O2    = (ushort*)(W + 125829120u);          // 32MB
  ushort* QH    = (ushort*)(W + 159383552u);          // 32MB
  ushort* KH    = (ushort*)(W + 192937984u);          // 32MB
  ushort* VH    = (ushort*)(W + 226492416u);          // 32MB -> end 260,046,848
  ushort* OH = A16;

  k_cast<<<4096, 256, 0, stream>>>(hidden, A16, (BL_*D_)/4);
  k_transpose_cast<<<dim3(ND3/32, D_/32), dim3(32,8), 0, stream>>>(w_cattn, WcatT, D_, ND3);
  k_gemmks<1><<<dim3(ND3/256, BL_/256), 512, 0, stream>>>(A16, WcatT, QKV, BL_, ND3, D_);
  // WcatT region dead from here on
  k_transpose_cast<<<dim3(D_/32, D_/32), dim3(32,8), 0, stream>>>(w_o, WoT, D_, D_);
  k_wbt<<<8, 256, 0, stream>>>(w_beta, WBT);
  k_beta2<<<512, 64, 0, stream>>>(A16, WBT, BETA);
  k_conv2<<<dim3(128, 3, 2), 256, 0, stream>>>(QKV, wq_conv, wk_conv, wv_conv, QH, KH, VH);
  k_prep<<<2048, 64, 0, stream>>>(QH, KH, BETA, TB, MM, KT);
  k_chunkrec<<<128, 256, 0, stream>>>(QH, KH, VH, TB, MM, KT, OH);
  k_norm<<<BL_, 256, 0, stream>>>(OH, o_nw, O2);
  k_gemmks<0><<<dim3(D_/256, BL_/256), 512, 0, stream>>>(O2, WoT, out, BL_, D_, D_);
}

// Round 10
// 614.347 us; speedup vs baseline: 10.0568x; 1.1562x over previous
//
#include <hip/hip_runtime.h>
#include <stdint.h>

#define B_   2
#define L_   4096
#define D_   2048
#define H_   16
#define DK_  128
#define ND3  6144
#define BL_  8192

typedef __bf16 bf16x8 __attribute__((ext_vector_type(8)));
typedef float  f32x4  __attribute__((ext_vector_type(4)));

__device__ __forceinline__ float bf2f(ushort u){ return __uint_as_float(((unsigned)u)<<16); }
__device__ __forceinline__ ushort f2bf(float f){
  unsigned u = __float_as_uint(f);
  unsigned r = u + 0x7FFFu + ((u>>16)&1u);
  return (ushort)(r>>16);
}
__device__ __forceinline__ f32x4 mfma16(bf16x8 a, bf16x8 b, f32x4 c){
  return __builtin_amdgcn_mfma_f32_16x16x32_bf16(a, b, c, 0, 0, 0);
}

#define BAR_LGKM() do{ __builtin_amdgcn_sched_barrier(0); \
  asm volatile("s_waitcnt lgkmcnt(0)" ::: "memory"); \
  __builtin_amdgcn_s_barrier(); \
  __builtin_amdgcn_sched_barrier(0);}while(0)
#define BAR_VMALL() do{ __builtin_amdgcn_sched_barrier(0); \
  asm volatile("s_waitcnt vmcnt(0) lgkmcnt(0)" ::: "memory"); \
  __builtin_amdgcn_s_barrier(); \
  __builtin_amdgcn_sched_barrier(0);}while(0)

__global__ __launch_bounds__(256) void k_cast(const float* __restrict__ x, ushort* __restrict__ y, int n4){
  int i = blockIdx.x*blockDim.x + threadIdx.x;
  int stride = gridDim.x*blockDim.x;
  for (; i < n4; i += stride){
    float4 v = ((const float4*)x)[i];
    ushort4 o; o.x=f2bf(v.x); o.y=f2bf(v.y); o.z=f2bf(v.z); o.w=f2bf(v.w);
    ((ushort4*)y)[i] = o;
  }
}

__global__ __launch_bounds__(256) void k_transpose_cast(const float* __restrict__ in, ushort* __restrict__ out,
                                                        int R, int C){
  __shared__ float tile[32][33];
  int c0 = blockIdx.x*32, r0 = blockIdx.y*32;
  int tx = threadIdx.x, ty = threadIdx.y;
  #pragma unroll
  for (int i=0;i<32;i+=8) tile[ty+i][tx] = in[(size_t)(r0+ty+i)*C + (c0+tx)];
  __syncthreads();
  #pragma unroll
  for (int i=0;i<32;i+=8) out[(size_t)(c0+ty+i)*R + (r0+tx)] = f2bf(tile[tx][ty+i]);
}

// ============ 256x256 GEMM, 4-slot ring, 1 barrier/phase, counted lgkmcnt ============
template<int OUT_BF16>
__global__ __launch_bounds__(512, 1) void k_gemmks(const ushort* __restrict__ A, const ushort* __restrict__ Bt,
                                                   void* __restrict__ Cv, int M, int N, int K){
  __shared__ ushort LDSB[65536];   // 128 KB = 4 slots x (A 16KB | B 16KB)
  char* lds = (char*)LDSB;
  const int tid = threadIdx.x, lane = tid & 63, w = tid >> 6;
  const int wm = w >> 2, wn = w & 3;
  int nwg = gridDim.x*gridDim.y;
  int id  = blockIdx.y*gridDim.x + blockIdx.x;
  int sw  = ((nwg & 7) == 0) ? ((id & 7)*(nwg >> 3) + (id >> 3)) : id;
  const int bx = sw % gridDim.x, by = sw / gridDim.x;
  const int m0 = by*256, n0 = bx*256;
  const int NT = K >> 6;
  const int NP = NT*2;
  const size_t rowb = (size_t)K*2;

  f32x4 acc[8][4];
  #pragma unroll
  for (int i=0;i<8;i++)
    #pragma unroll
    for (int j=0;j<4;j++) acc[i][j] = (f32x4){0.f,0.f,0.f,0.f};

  const int c0 = tid, c1 = tid + 512;
  const int r0c = ((c0>>6)<<4) + (c0&15), h0 = (c0>>4)&3;
  const int r1c = ((c1>>6)<<4) + (c1&15), h1 = (c1>>4)&3;
  const char* gA = (const char*)A  + (size_t)m0*rowb;
  const char* gB = (const char*)Bt + (size_t)n0*rowb;

  auto stage = [&](int slot, int tile, int s){
    const char* ga = gA + (size_t)tile*128 + s*64;
    const char* gb = gB + (size_t)tile*128 + s*64;
    char* la = lds + slot*32768;
    char* lb = la + 16384;
    __builtin_amdgcn_global_load_lds((const __attribute__((address_space(1))) void*)(ga + (size_t)r0c*rowb + h0*16),
                                     (__attribute__((address_space(3))) void*)(la + c0*16), 16, 0, 0);
    __builtin_amdgcn_global_load_lds((const __attribute__((address_space(1))) void*)(ga + (size_t)r1c*rowb + h1*16),
                                     (__attribute__((address_space(3))) void*)(la + c1*16), 16, 0, 0);
    __builtin_amdgcn_global_load_lds((const __attribute__((address_space(1))) void*)(gb + (size_t)r0c*rowb + h0*16),
                                     (__attribute__((address_space(3))) void*)(lb + c0*16), 16, 0, 0);
    __builtin_amdgcn_global_load_lds((const __attribute__((address_space(1))) void*)(gb + (size_t)r1c*rowb + h1*16),
                                     (__attribute__((address_space(3))) void*)(lb + c1*16), 16, 0, 0);
  };

  stage(0, 0, 0);
  stage(1, 0, 1);
  stage(2, 1, 0);
  __builtin_amdgcn_sched_barrier(0);
  asm volatile("s_waitcnt vmcnt(8)" ::: "memory");
  __builtin_amdgcn_s_barrier();
  __builtin_amdgcn_sched_barrier(0);

  for (int pb = 0; pb < NP; pb += 4){
    #pragma unroll
    for (int q = 0; q < 4; ++q){
      const int p = pb + q;
      const char* base = lds + q*32768;
      bf16x8 af[8], bfr[4];
      #pragma unroll
      for (int i=0;i<4;i++) af[i]  = *(const bf16x8*)(base + (wm*128 + i*16)*64 + lane*16);
      #pragma unroll
      for (int j=0;j<4;j++) bfr[j] = *(const bf16x8*)(base + 16384 + (wn*64 + j*16)*64 + lane*16);
      __builtin_amdgcn_sched_barrier(0);
      #pragma unroll
      for (int i=4;i<8;i++) af[i]  = *(const bf16x8*)(base + (wm*128 + i*16)*64 + lane*16);
      {
        int ps = p + 3;
        int tile = ps >> 1; if (tile >= NT) tile = NT - 1;
        stage(ps & 3, tile, ps & 1);
      }
      __builtin_amdgcn_sched_barrier(0);
      asm volatile("s_waitcnt lgkmcnt(4)" ::: "memory");
      __builtin_amdgcn_sched_barrier(0);
      __builtin_amdgcn_s_setprio(1);
      #pragma unroll
      for (int i=0;i<4;i++)
        #pragma unroll
        for (int j=0;j<4;j++)
          acc[i][j] = mfma16(af[i], bfr[j], acc[i][j]);
      __builtin_amdgcn_sched_barrier(0);
      asm volatile("s_waitcnt lgkmcnt(0)" ::: "memory");
      __builtin_amdgcn_sched_barrier(0);
      #pragma unroll
      for (int i=4;i<8;i++)
        #pragma unroll
        for (int j=0;j<4;j++)
          acc[i][j] = mfma16(af[i], bfr[j], acc[i][j]);
      __builtin_amdgcn_s_setprio(0);
      __builtin_amdgcn_sched_barrier(0);
      asm volatile("s_waitcnt vmcnt(8)" ::: "memory");
      __builtin_amdgcn_s_barrier();
      __builtin_amdgcn_sched_barrier(0);
    }
  }

  const int rbase = m0 + wm*128 + (lane>>4)*4;
  const int cbase = n0 + wn*64 + (lane&15);
  #pragma unroll
  for (int fi=0;fi<8;fi++)
    #pragma unroll
    for (int fj=0;fj<4;fj++)
      #pragma unroll
      for (int r=0;r<4;r++){
        int row = rbase + fi*16 + r;
        int col = cbase + fj*16;
        float v = acc[fi][fj][r];
        if (OUT_BF16) ((ushort*)Cv)[(size_t)row*N + col] = f2bf(v);
        else          ((float*) Cv)[(size_t)row*N + col] = v;
      }
}

// ---------------- wbT[h][d] bf16 <- wb[d][h] f32 ----------------
__global__ __launch_bounds__(256) void k_wbt(const float* __restrict__ wb, ushort* __restrict__ wbT){
  int d = blockIdx.x*256 + threadIdx.x;
  #pragma unroll
  for (int h=0;h<16;h++) wbT[(size_t)h*2048 + d] = f2bf(wb[(size_t)d*16 + h]);
}

// ---------------- beta = sigmoid(A16 @ wbT^T) via MFMA; out [b][h][l] f32 ----------------
__global__ __launch_bounds__(64) void k_beta2(const ushort* __restrict__ A16, const ushort* __restrict__ wbT,
                                              float* __restrict__ beta){
  const int rt = blockIdx.x;
  const int lane = threadIdx.x;
  const int lr = lane & 15, lk8 = (lane>>4)*8;
  const int r0 = rt*16;
  f32x4 acc0 = (f32x4){0.f,0.f,0.f,0.f};
  f32x4 acc1 = (f32x4){0.f,0.f,0.f,0.f};
  for (int k0=0; k0<2048; k0+=64){
    bf16x8 a0 = *(const bf16x8*)&A16[(size_t)(r0+lr)*2048 + k0 + lk8];
    bf16x8 b0 = *(const bf16x8*)&wbT[(size_t)lr*2048 + k0 + lk8];
    bf16x8 a1 = *(const bf16x8*)&A16[(size_t)(r0+lr)*2048 + k0 + 32 + lk8];
    bf16x8 b1 = *(const bf16x8*)&wbT[(size_t)lr*2048 + k0 + 32 + lk8];
    acc0 = mfma16(a0, b0, acc0);
    acc1 = mfma16(a1, b1, acc1);
  }
  const int h = lane & 15;
  const int rbase = r0 + (lane>>4)*4;
  #pragma unroll
  for (int r=0;r<4;r++){
    int row = rbase + r;
    int b = row >> 12, l = row & 4095;
    float sg = 1.f/(1.f + __expf(-(acc0[r] + acc1[r])));
    beta[((size_t)(b*H_ + h))*L_ + l] = sg;
  }
}

// ---------------- conv(K=4, causal)+SiLU+heads+l2norm, sliding window ----------------
__global__ __launch_bounds__(256) void k_conv2(const ushort* __restrict__ qkv,
      const float* __restrict__ wq, const float* __restrict__ wk, const float* __restrict__ wv,
      ushort* __restrict__ QH, ushort* __restrict__ KH, ushort* __restrict__ VH){
  const int seg = blockIdx.x, part = blockIdx.y, b = blockIdx.z;
  const int t = threadIdx.x;
  const int ch = t*8;
  const int h = t >> 4, d0 = (t & 15)*8;
  const float* wc = (part==0) ? wq : (part==1) ? wk : wv;
  ushort* outs = ((part==0) ? QH : (part==1) ? KH : VH)
                 + ((size_t)(b*H_ + h)*L_)*DK_ + d0;
  const ushort* inp = qkv + ((size_t)b*L_)*ND3 + part*D_ + ch;

  float wgt[4][8];
  #pragma unroll
  for (int j=0;j<8;j++){
    float4 w4 = *(const float4*)&wc[(ch + j)*4];
    wgt[0][j]=w4.x; wgt[1][j]=w4.y; wgt[2][j]=w4.z; wgt[3][j]=w4.w;
  }

  const int l0 = seg*32;
  float x0[8], x1[8], x2[8];
  {
    float* dsts[3] = {x0, x1, x2};
    #pragma unroll
    for (int i=0;i<3;i++){
      int l = l0 - 3 + i;
      float* d = dsts[i];
      if (l >= 0){
        const ushort* p = inp + (size_t)l*ND3;
        ushort4 a = *(const ushort4*)p, c = *(const ushort4*)(p+4);
        d[0]=bf2f(a.x); d[1]=bf2f(a.y); d[2]=bf2f(a.z); d[3]=bf2f(a.w);
        d[4]=bf2f(c.x); d[5]=bf2f(c.y); d[6]=bf2f(c.z); d[7]=bf2f(c.w);
      } else {
        #pragma unroll
        for (int j=0;j<8;j++) d[j] = 0.f;
      }
    }
  }

  for (int i=0;i<32;i++){
    const int l = l0 + i;
    float cur[8];
    {
      const ushort* p = inp + (size_t)l*ND3;
      ushort4 a = *(const ushort4*)p, c = *(const ushort4*)(p+4);
      cur[0]=bf2f(a.x); cur[1]=bf2f(a.y); cur[2]=bf2f(a.z); cur[3]=bf2f(a.w);
      cur[4]=bf2f(c.x); cur[5]=bf2f(c.y); cur[6]=bf2f(c.z); cur[7]=bf2f(c.w);
    }
    float y[8]; float ss = 0.f;
    #pragma unroll
    for (int j=0;j<8;j++){
      float yy = x0[j]*wgt[0][j] + x1[j]*wgt[1][j] + x2[j]*wgt[2][j] + cur[j]*wgt[3][j];
      yy = yy / (1.f + __expf(-yy));
      y[j] = yy; ss += yy*yy;
    }
    if (part < 2){
      #pragma unroll
      for (int m=1;m<16;m<<=1) ss += __shfl_xor(ss, m, 64);
      float sc = rsqrtf(ss + 1e-12f);
      #pragma unroll
      for (int j=0;j<8;j++) y[j] *= sc;
    }
    ushort4 o0, o1;
    o0.x=f2bf(y[0]); o0.y=f2bf(y[1]); o0.z=f2bf(y[2]); o0.w=f2bf(y[3]);
    o1.x=f2bf(y[4]); o1.y=f2bf(y[5]); o1.z=f2bf(y[6]); o1.w=f2bf(y[7]);
    ushort* op = outs + (size_t)l*DK_;
    *(ushort4*)op = o0; *(ushort4*)(op+4) = o1;
    #pragma unroll
    for (int j=0;j<8;j++){ x0[j]=x1[j]; x1[j]=x2[j]; x2[j]=cur[j]; }
  }
}

// ---------------- phase 1 v2: per-chunk Tb, M, Kt — register solve, 35KB LDS ----------------
// Solve kept in 64 VGPRs (static indices), As[t][s] broadcast via compile-time readlane.
// Qs region reused for As (M computed before As written; Ks stays live for KT).
__global__ __launch_bounds__(64) void k_prep(const ushort* __restrict__ QH, const ushort* __restrict__ KH,
      const float* __restrict__ BETA, ushort* __restrict__ TB, ushort* __restrict__ MM,
      ushort* __restrict__ KT){
  const int bid = blockIdx.x, bh = bid>>6, c = bid&63;
  const int lane = threadIdx.x;
  __shared__ ushort Ks[64][136];                 // 17,408 B
  __shared__ __align__(16) char QA[17408];       // Qs (ushort[64][136]) -> reused as As (float[64][64])
  __shared__ float bs[64];
  ushort (*Qs)[136] = (ushort (*)[136])QA;
  float  (*As)[64]  = (float  (*)[64])QA;

  const ushort* kg = KH + ((size_t)bh*L_ + c*64)*DK_;
  const ushort* qg = QH + ((size_t)bh*L_ + c*64)*DK_;
  {
    const uint4* ks4 = (const uint4*)(kg + (size_t)lane*DK_);
    const uint4* qs4 = (const uint4*)(qg + (size_t)lane*DK_);
    uint4* kd = (uint4*)&Ks[lane][0];
    uint4* qd = (uint4*)&Qs[lane][0];
    #pragma unroll
    for (int i=0;i<16;i++){ kd[i] = ks4[i]; qd[i] = qs4[i]; }
    bs[lane] = BETA[(size_t)bh*L_ + c*64 + lane];
  }
  __syncthreads();
  const int lr = lane&15, lk = lane>>4;

  // ---- G = K K^T (keep in regs) ----
  f32x4 gac[4][4];
  #pragma unroll
  for (int i=0;i<4;i++)
    #pragma unroll
    for (int j=0;j<4;j++) gac[i][j] = (f32x4){0.f,0.f,0.f,0.f};
  #pragma unroll
  for (int kk=0;kk<4;kk++){
    bf16x8 fr[4];
    #pragma unroll
    for (int i=0;i<4;i++) fr[i] = *(const bf16x8*)&Ks[i*16+lr][kk*32 + lk*8];
    #pragma unroll
    for (int mi=0;mi<4;mi++)
      #pragma unroll
      for (int ni=0;ni<4;ni++)
        gac[mi][ni] = mfma16(fr[mi], fr[ni], gac[mi][ni]);
  }
  // ---- M = tril_incl(Q K^T) -> global (uses Qs; must precede As overwrite) ----
  {
    f32x4 mac[4][4];
    #pragma unroll
    for (int i=0;i<4;i++)
      #pragma unroll
      for (int j=0;j<4;j++) mac[i][j] = (f32x4){0.f,0.f,0.f,0.f};
    #pragma unroll
    for (int kk=0;kk<4;kk++){
      bf16x8 frq[4], frk[4];
      #pragma unroll
      for (int i=0;i<4;i++){
        frq[i] = *(const bf16x8*)&Qs[i*16+lr][kk*32 + lk*8];
        frk[i] = *(const bf16x8*)&Ks[i*16+lr][kk*32 + lk*8];
      }
      #pragma unroll
      for (int mi=0;mi<4;mi++)
        #pragma unroll
        for (int ni=0;ni<4;ni++)
          mac[mi][ni] = mfma16(frq[mi], frk[ni], mac[mi][ni]);
    }
    #pragma unroll
    for (int mi=0;mi<4;mi++)
      #pragma unroll
      for (int ni=0;ni<4;ni++)
        #pragma unroll
        for (int r=0;r<4;r++){
          int t = mi*16 + lk*4 + r, s = ni*16 + lr;
          float v = (s <= t) ? mac[mi][ni][r] : 0.f;
          MM[(size_t)bid*4096 + t*64 + s] = f2bf(v);
        }
  }
  __syncthreads();   // Qs reads done -> safe to overwrite with As

  // ---- As = strict_tril(diag(beta) G) into LDS f32 (only s<t written/used) ----
  #pragma unroll
  for (int mi=0;mi<4;mi++)
    #pragma unroll
    for (int ni=0;ni<4;ni++)
      #pragma unroll
      for (int r=0;r<4;r++){
        int t = mi*16 + lk*4 + r, s = ni*16 + lr;
        As[t][s] = (s < t) ? (bs[t] * gac[mi][ni][r]) : 0.f;
      }
  __syncthreads();

  // ---- forward solve (I+A) T = I; lane owns column `lane`; T column in registers ----
  float rT[64];
  #pragma unroll
  for (int t=0;t<64;t++){
    float arow = As[t][lane];          // row t, conflict-free, read once
    float a = (t==lane) ? 1.f : 0.f;
    #pragma unroll
    for (int s=0;s<t;s++){
      float cc = __int_as_float(__builtin_amdgcn_readlane(__float_as_int(arow), s));
      a -= cc * rT[s];
    }
    rT[t] = a;
  }
  // ---- Tb = T * diag(beta) -> global bf16 ----
  {
    float bc = bs[lane];
    #pragma unroll
    for (int t=0;t<64;t++)
      TB[(size_t)bid*4096 + t*64 + lane] = f2bf(rT[t] * bc);
  }
  // ---- Kt[d][t] = K[t][d] -> global bf16 ----
  for (int d2=0; d2<64; d2++){
    unsigned uu = *(const unsigned*)&Ks[lane][2*d2];
    KT[(size_t)bid*8192 + (size_t)(2*d2)*64 + lane]   = (ushort)(uu & 0xffffu);
    KT[(size_t)bid*8192 + (size_t)(2*d2+1)*64 + lane] = (ushort)(uu >> 16);
  }
}

template<int LRB, int GRB, int NB, int XM>
__device__ __forceinline__ void stage_swz(const ushort* __restrict__ g, ushort* l,
                                          int colOff, int w, int lane){
  for (int idx = w; idx < NB/1024; idx += 4){
    int off = idx*1024 + lane*16;
    int row = off / LRB;
    int inner = off & (LRB-1);
    int src = row*GRB + colOff + (inner ^ ((row&XM)<<4));
    __builtin_amdgcn_global_load_lds(
      (const __attribute__((address_space(1))) void*)((const char*)g + src),
      (__attribute__((address_space(3))) void*)((char*)l + idx*1024), 16, 0, 0);
  }
}

// ======= chunk recurrence v2: 128 blocks (bh x dv-quarter), dbuf panels, raw barriers =======
__global__ __launch_bounds__(256) void k_chunkrec(const ushort* __restrict__ QH, const ushort* __restrict__ KH,
      const ushort* __restrict__ VH, const ushort* __restrict__ TB, const ushort* __restrict__ MM,
      const ushort* __restrict__ KT, ushort* __restrict__ OH){
  const int p = blockIdx.x;           // 0..127
  const int xg = p & 7, slot = p >> 3;
  const int bh = xg + (slot >> 2)*8;
  const int vq = slot & 3;
  const int tid = threadIdx.x, lane = tid&63, w = tid>>6;
  const int lr = lane&15, lk = lane>>4;
  const int tw = w*16;
  const int dw = w*32;

  __shared__ ushort SM[77824];        // 155,648 B
  ushort* Stl = SM + 69632;
  ushort* Ztl = SM + 73728;
  ushort* Utl = SM + 75776;

  const ushort* kbase  = KH + ((size_t)bh*L_)*DK_;
  const ushort* qbase  = QH + ((size_t)bh*L_)*DK_;
  const ushort* vbase  = VH + ((size_t)bh*L_)*DK_;
  const ushort* tbase  = TB + ((size_t)bh*64)*4096;
  const ushort* mbase  = MM + ((size_t)bh*64)*4096;
  const ushort* ktbase = KT + ((size_t)bh*64)*8192;
  ushort* obase = OH + ((size_t)bh*L_)*DK_ + vq*32;

  auto stageall = [&](ushort* buf, int c){
    stage_swz<256,256,16384,7>(kbase  + (size_t)c*8192, buf,         0,     w, lane);
    stage_swz<256,256,16384,7>(qbase  + (size_t)c*8192, buf + 8192,  0,     w, lane);
    stage_swz<128,128,16384,7>(ktbase + (size_t)c*8192, buf + 16384, 0,     w, lane);
    stage_swz<128,128, 8192,7>(tbase  + (size_t)c*4096, buf + 24576, 0,     w, lane);
    stage_swz<128,128, 8192,7>(mbase  + (size_t)c*4096, buf + 28672, 0,     w, lane);
    stage_swz< 64,256, 4096,3>(vbase  + (size_t)c*8192, buf + 32768, vq*64, w, lane);
  };

  f32x4 Stf[2][2];
  #pragma unroll
  for (int a=0;a<2;a++)
    #pragma unroll
    for (int b=0;b<2;b++) Stf[a][b] = (f32x4){0.f,0.f,0.f,0.f};

  stageall(SM, 0);
  BAR_VMALL();

  for (int c=0; c<64; ++c){
    ushort* buf  = SM + (c&1)*34816;
    ushort* nbuf = SM + ((c+1)&1)*34816;
    const ushort* Kc  = buf;
    const ushort* Qc  = buf + 8192;
    const ushort* Ktc = buf + 16384;
    const ushort* Tbc = buf + 24576;
    const ushort* Mc  = buf + 28672;
    const ushort* Vc  = buf + 32768;

    if (c+1 < 64) stageall(nbuf, c+1);

    #pragma unroll
    for (int mj=0;mj<2;mj++)
      #pragma unroll
      for (int nd=0;nd<2;nd++)
        #pragma unroll
        for (int r=0;r<4;r++){
          int j = mj*16 + lk*4 + r;
          int d = dw + nd*16 + lr;
          Stl[j*128 + (d ^ ((j&7)<<3))] = f2bf(Stf[mj][nd][r]);
        }
    BAR_LGKM();

    f32x4 xac[2];
    xac[0] = (f32x4){0.f,0.f,0.f,0.f}; xac[1] = (f32x4){0.f,0.f,0.f,0.f};
    #pragma unroll
    for (int kk=0;kk<4;kk++){
      int e = kk*32 + lk*8;
      int ta = tw + lr;
      bf16x8 ak = *(const bf16x8*)&Kc[ta*128 + (e ^ ((ta&7)<<3))];
      #pragma unroll
      for (int ni=0;ni<2;ni++){
        int j = ni*16 + lr;
        bf16x8 bst = *(const bf16x8*)&Stl[j*128 + (e ^ ((j&7)<<3))];
        xac[ni] = mfma16(ak, bst, xac[ni]);
      }
    }
    #pragma unroll
    for (int ni=0;ni<2;ni++)
      #pragma unroll
      for (int r=0;r<4;r++){
        int t = tw + lk*4 + r;
        int j = ni*16 + lr;
        float v = bf2f(Vc[t*32 + (j ^ ((t&3)<<3))]);
        Ztl[j*64 + (t ^ ((j&7)<<3))] = f2bf(v - xac[ni][r]);
      }
    BAR_LGKM();

    f32x4 uac[2];
    uac[0] = (f32x4){0.f,0.f,0.f,0.f}; uac[1] = (f32x4){0.f,0.f,0.f,0.f};
    #pragma unroll
    for (int kk=0;kk<2;kk++){
      int e = kk*32 + lk*8;
      int ta = tw + lr;
      bf16x8 at = *(const bf16x8*)&Tbc[ta*64 + (e ^ ((ta&7)<<3))];
      #pragma unroll
      for (int ni=0;ni<2;ni++){
        int j = ni*16 + lr;
        bf16x8 bz = *(const bf16x8*)&Ztl[j*64 + (e ^ ((j&7)<<3))];
        uac[ni] = mfma16(at, bz, uac[ni]);
      }
    }
    #pragma unroll
    for (int ni=0;ni<2;ni++)
      #pragma unroll
      for (int r=0;r<4;r++){
        int t = tw + lk*4 + r;
        int j = ni*16 + lr;
        Utl[j*64 + (t ^ ((j&7)<<3))] = f2bf(uac[ni][r]);
      }
    BAR_LGKM();

    f32x4 oac[2];
    oac[0] = (f32x4){0.f,0.f,0.f,0.f}; oac[1] = (f32x4){0.f,0.f,0.f,0.f};
    #pragma unroll
    for (int kk=0;kk<4;kk++){
      int e = kk*32 + lk*8;
      int ta = tw + lr;
      bf16x8 aq = *(const bf16x8*)&Qc[ta*128 + (e ^ ((ta&7)<<3))];
      #pragma unroll
      for (int ni=0;ni<2;ni++){
        int j = ni*16 + lr;
        bf16x8 bst = *(const bf16x8*)&Stl[j*128 + (e ^ ((j&7)<<3))];
        oac[ni] = mfma16(aq, bst, oac[ni]);
      }
    }
    #pragma unroll
    for (int kk=0;kk<2;kk++){
      int e = kk*32 + lk*8;
      int ta = tw + lr;
      bf16x8 am = *(const bf16x8*)&Mc[ta*64 + (e ^ ((ta&7)<<3))];
      #pragma unroll
      for (int ni=0;ni<2;ni++){
        int j = ni*16 + lr;
        bf16x8 bu = *(const bf16x8*)&Utl[j*64 + (e ^ ((j&7)<<3))];
        oac[ni] = mfma16(am, bu, oac[ni]);
      }
    }
    #pragma unroll
    for (int ni=0;ni<2;ni++)
      #pragma unroll
      for (int r=0;r<4;r++){
        int t = tw + lk*4 + r;
        int j = ni*16 + lr;
        obase[(size_t)(c*64 + t)*DK_ + j] = f2bf(oac[ni][r]);
      }

    #pragma unroll
    for (int kk=0;kk<2;kk++){
      int e = kk*32 + lk*8;
      bf16x8 au[2], bk[2];
      #pragma unroll
      for (int mj=0;mj<2;mj++){ int j = mj*16 + lr; au[mj] = *(const bf16x8*)&Utl[j*64 + (e ^ ((j&7)<<3))]; }
      #pragma unroll
      for (int nd=0;nd<2;nd++){ int d = dw + nd*16 + lr; bk[nd] = *(const bf16x8*)&Ktc[d*64 + (e ^ ((d&7)<<3))]; }
      #pragma unroll
      for (int mj=0;mj<2;mj++)
        #pragma unroll
        for (int nd=0;nd<2;nd++)
          Stf[mj][nd] = mfma16(au[mj], bk[nd], Stf[mj][nd]);
    }
    BAR_VMALL();
  }
}

__global__ __launch_bounds__(256) void k_norm(const ushort* __restrict__ OH, const float* __restrict__ gw,
                                              ushort* __restrict__ O2){
  const int blk = blockIdx.x;
  const int b = blk >> 12, l = blk & 4095;
  const int t = threadIdx.x;
  const int h = t >> 4, d0 = (t & 15) * 8;
  const ushort* ip = OH + ((size_t)(b*H_ + h)*L_ + l)*DK_ + d0;
  ushort4 a = *(const ushort4*)ip, c = *(const ushort4*)(ip+4);
  float x[8];
  x[0]=bf2f(a.x); x[1]=bf2f(a.y); x[2]=bf2f(a.z); x[3]=bf2f(a.w);
  x[4]=bf2f(c.x); x[5]=bf2f(c.y); x[6]=bf2f(c.z); x[7]=bf2f(c.w);
  float ss = 0.f;
  #pragma unroll
  for (int j=0;j<8;j++) ss += x[j]*x[j];
  #pragma unroll
  for (int m=1;m<16;m<<=1) ss += __shfl_xor(ss, m, 64);
  float sc = rsqrtf(ss * (1.f/128.f) + 1e-5f);
  ushort* opp = O2 + (size_t)blk*D_ + h*DK_ + d0;
  ushort4 o0, o1;
  o0.x=f2bf(x[0]*sc*gw[d0+0]); o0.y=f2bf(x[1]*sc*gw[d0+1]);
  o0.z=f2bf(x[2]*sc*gw[d0+2]); o0.w=f2bf(x[3]*sc*gw[d0+3]);
  o1.x=f2bf(x[4]*sc*gw[d0+4]); o1.y=f2bf(x[5]*sc*gw[d0+5]);
  o1.z=f2bf(x[6]*sc*gw[d0+6]); o1.w=f2bf(x[7]*sc*gw[d0+7]);
  *(ushort4*)opp = o0; *(ushort4*)(opp+4) = o1;
}

extern "C" void kernel_launch(void* const* d_in, const int* in_sizes, int n_in,
                              void* d_out, int out_size, void* d_ws, size_t ws_size,
                              hipStream_t stream) {
  (void)in_sizes; (void)n_in; (void)out_size; (void)ws_size;
  const float* hidden  = (const float*)d_in[0];
  const float* w_cattn = (const float*)d_in[1];
  const float* wq_conv = (const float*)d_in[2];
  const float* wk_conv = (const float*)d_in[3];
  const float* wv_conv = (const float*)d_in[4];
  const float* w_beta  = (const float*)d_in[5];
  const float* o_nw    = (const float*)d_in[6];
  const float* w_o     = (const float*)d_in[7];
  float* out = (float*)d_out;

  char* W = (char*)d_ws;                              // total 260,046,848 B (known-good size)
  ushort* A16   = (ushort*)(W);                       // 32MB ; -> OH after gemm1
  ushort* WcatT = (ushort*)(W + 33554432u);           // 24MB; dead after gemm1
  ushort* WoT   = (ushort*)(W + 33554432u);           //  8MB (alias, written after gemm1)
  float*  BETA  = (float*) (W + 41943040u);           // 512KB (alias in dead WcatT region)
  ushort* WBT   = (ushort*)(W + 42467328u);           // 64KB  (alias in dead WcatT region)
  ushort* QKV   = (ushort*)(W + 58720256u);           // 96MB; dead after conv
  ushort* TB    = (ushort*)(W + 58720256u);           // 16MB (alias in dead QKV)
  ushort* MM    = (ushort*)(W + 75497472u);           // 16MB
  ushort* KT    = (ushort*)(W + 92274688u);           // 32MB
  ushort* O2    = (ushort*)(W + 125829120u);          // 32MB
  ushort* QH    = (ushort*)(W + 159383552u);          // 32MB
  ushort* KH    = (ushort*)(W + 192937984u);          // 32MB
  ushort* VH    = (ushort*)(W + 226492416u);          // 32MB -> end 260,046,848
  ushort* OH = A16;

  k_cast<<<4096, 256, 0, stream>>>(hidden, A16, (BL_*D_)/4);
  k_transpose_cast<<<dim3(ND3/32, D_/32), dim3(32,8), 0, stream>>>(w_cattn, WcatT, D_, ND3);
  k_gemmks<1><<<dim3(ND3/256, BL_/256), 512, 0, stream>>>(A16, WcatT, QKV, BL_, ND3, D_);
  // WcatT region dead from here on
  k_transpose_cast<<<dim3(D_/32, D_/32), dim3(32,8), 0, stream>>>(w_o, WoT, D_, D_);
  k_wbt<<<8, 256, 0, stream>>>(w_beta, WBT);
  k_beta2<<<512, 64, 0, stream>>>(A16, WBT, BETA);
  k_conv2<<<dim3(128, 3, 2), 256, 0, stream>>>(QKV, wq_conv, wk_conv, wv_conv, QH, KH, VH);
  k_prep<<<2048, 64, 0, stream>>>(QH, KH, BETA, TB, MM, KT);
  k_chunkrec<<<128, 256, 0, stream>>>(QH, KH, VH, TB, MM, KT, OH);
  k_norm<<<BL_, 256, 0, stream>>>(OH, o_nw, O2);
  k_gemmks<0><<<dim3(D_/256, BL_/256), 512, 0, stream>>>(O2, WoT, out, BL_, D_, D_);
}

// Round 11
// 580.049 us; speedup vs baseline: 10.6514x; 1.0591x over previous
//
#include <hip/hip_runtime.h>
#include <stdint.h>

#define B_   2
#define L_   4096
#define D_   2048
#define H_   16
#define DK_  128
#define ND3  6144
#define BL_  8192

typedef __bf16 bf16x8 __attribute__((ext_vector_type(8)));
typedef float  f32x4  __attribute__((ext_vector_type(4)));

__device__ __forceinline__ float bf2f(ushort u){ return __uint_as_float(((unsigned)u)<<16); }
__device__ __forceinline__ ushort f2bf(float f){
  unsigned u = __float_as_uint(f);
  unsigned r = u + 0x7FFFu + ((u>>16)&1u);
  return (ushort)(r>>16);
}
__device__ __forceinline__ f32x4 mfma16(bf16x8 a, bf16x8 b, f32x4 c){
  return __builtin_amdgcn_mfma_f32_16x16x32_bf16(a, b, c, 0, 0, 0);
}

#define BAR_LGKM() do{ __builtin_amdgcn_sched_barrier(0); \
  asm volatile("s_waitcnt lgkmcnt(0)" ::: "memory"); \
  __builtin_amdgcn_s_barrier(); \
  __builtin_amdgcn_sched_barrier(0);}while(0)
#define BAR_VMALL() do{ __builtin_amdgcn_sched_barrier(0); \
  asm volatile("s_waitcnt vmcnt(0) lgkmcnt(0)" ::: "memory"); \
  __builtin_amdgcn_s_barrier(); \
  __builtin_amdgcn_sched_barrier(0);}while(0)

__global__ __launch_bounds__(256) void k_cast(const float* __restrict__ x, ushort* __restrict__ y, int n4){
  int i = blockIdx.x*blockDim.x + threadIdx.x;
  int stride = gridDim.x*blockDim.x;
  for (; i < n4; i += stride){
    float4 v = ((const float4*)x)[i];
    ushort4 o; o.x=f2bf(v.x); o.y=f2bf(v.y); o.z=f2bf(v.z); o.w=f2bf(v.w);
    ((ushort4*)y)[i] = o;
  }
}

__global__ __launch_bounds__(256) void k_transpose_cast(const float* __restrict__ in, ushort* __restrict__ out,
                                                        int R, int C){
  __shared__ float tile[32][33];
  int c0 = blockIdx.x*32, r0 = blockIdx.y*32;
  int tx = threadIdx.x, ty = threadIdx.y;
  #pragma unroll
  for (int i=0;i<32;i+=8) tile[ty+i][tx] = in[(size_t)(r0+ty+i)*C + (c0+tx)];
  __syncthreads();
  #pragma unroll
  for (int i=0;i<32;i+=8) out[(size_t)(c0+ty+i)*R + (r0+tx)] = f2bf(tile[tx][ty+i]);
}

// ============ 256x256 GEMM, 4-slot ring, 1 barrier/phase, counted lgkmcnt ============
template<int OUT_BF16>
__global__ __launch_bounds__(512, 1) void k_gemmks(const ushort* __restrict__ A, const ushort* __restrict__ Bt,
                                                   void* __restrict__ Cv, int M, int N, int K){
  __shared__ ushort LDSB[65536];   // 128 KB = 4 slots x (A 16KB | B 16KB)
  char* lds = (char*)LDSB;
  const int tid = threadIdx.x, lane = tid & 63, w = tid >> 6;
  const int wm = w >> 2, wn = w & 3;
  int nwg = gridDim.x*gridDim.y;
  int id  = blockIdx.y*gridDim.x + blockIdx.x;
  int sw  = ((nwg & 7) == 0) ? ((id & 7)*(nwg >> 3) + (id >> 3)) : id;
  const int bx = sw % gridDim.x, by = sw / gridDim.x;
  const int m0 = by*256, n0 = bx*256;
  const int NT = K >> 6;
  const int NP = NT*2;
  const size_t rowb = (size_t)K*2;

  f32x4 acc[8][4];
  #pragma unroll
  for (int i=0;i<8;i++)
    #pragma unroll
    for (int j=0;j<4;j++) acc[i][j] = (f32x4){0.f,0.f,0.f,0.f};

  const int c0 = tid, c1 = tid + 512;
  const int r0c = ((c0>>6)<<4) + (c0&15), h0 = (c0>>4)&3;
  const int r1c = ((c1>>6)<<4) + (c1&15), h1 = (c1>>4)&3;
  const char* gA = (const char*)A  + (size_t)m0*rowb;
  const char* gB = (const char*)Bt + (size_t)n0*rowb;

  auto stage = [&](int slot, int tile, int s){
    const char* ga = gA + (size_t)tile*128 + s*64;
    const char* gb = gB + (size_t)tile*128 + s*64;
    char* la = lds + slot*32768;
    char* lb = la + 16384;
    __builtin_amdgcn_global_load_lds((const __attribute__((address_space(1))) void*)(ga + (size_t)r0c*rowb + h0*16),
                                     (__attribute__((address_space(3))) void*)(la + c0*16), 16, 0, 0);
    __builtin_amdgcn_global_load_lds((const __attribute__((address_space(1))) void*)(ga + (size_t)r1c*rowb + h1*16),
                                     (__attribute__((address_space(3))) void*)(la + c1*16), 16, 0, 0);
    __builtin_amdgcn_global_load_lds((const __attribute__((address_space(1))) void*)(gb + (size_t)r0c*rowb + h0*16),
                                     (__attribute__((address_space(3))) void*)(lb + c0*16), 16, 0, 0);
    __builtin_amdgcn_global_load_lds((const __attribute__((address_space(1))) void*)(gb + (size_t)r1c*rowb + h1*16),
                                     (__attribute__((address_space(3))) void*)(lb + c1*16), 16, 0, 0);
  };

  stage(0, 0, 0);
  stage(1, 0, 1);
  stage(2, 1, 0);
  __builtin_amdgcn_sched_barrier(0);
  asm volatile("s_waitcnt vmcnt(8)" ::: "memory");
  __builtin_amdgcn_s_barrier();
  __builtin_amdgcn_sched_barrier(0);

  for (int pb = 0; pb < NP; pb += 4){
    #pragma unroll
    for (int q = 0; q < 4; ++q){
      const int p = pb + q;
      const char* base = lds + q*32768;
      bf16x8 af[8], bfr[4];
      #pragma unroll
      for (int i=0;i<4;i++) af[i]  = *(const bf16x8*)(base + (wm*128 + i*16)*64 + lane*16);
      #pragma unroll
      for (int j=0;j<4;j++) bfr[j] = *(const bf16x8*)(base + 16384 + (wn*64 + j*16)*64 + lane*16);
      __builtin_amdgcn_sched_barrier(0);
      #pragma unroll
      for (int i=4;i<8;i++) af[i]  = *(const bf16x8*)(base + (wm*128 + i*16)*64 + lane*16);
      {
        int ps = p + 3;
        int tile = ps >> 1; if (tile >= NT) tile = NT - 1;
        stage(ps & 3, tile, ps & 1);
      }
      __builtin_amdgcn_sched_barrier(0);
      asm volatile("s_waitcnt lgkmcnt(4)" ::: "memory");
      __builtin_amdgcn_sched_barrier(0);
      __builtin_amdgcn_s_setprio(1);
      #pragma unroll
      for (int i=0;i<4;i++)
        #pragma unroll
        for (int j=0;j<4;j++)
          acc[i][j] = mfma16(af[i], bfr[j], acc[i][j]);
      __builtin_amdgcn_sched_barrier(0);
      asm volatile("s_waitcnt lgkmcnt(0)" ::: "memory");
      __builtin_amdgcn_sched_barrier(0);
      #pragma unroll
      for (int i=4;i<8;i++)
        #pragma unroll
        for (int j=0;j<4;j++)
          acc[i][j] = mfma16(af[i], bfr[j], acc[i][j]);
      __builtin_amdgcn_s_setprio(0);
      __builtin_amdgcn_sched_barrier(0);
      asm volatile("s_waitcnt vmcnt(8)" ::: "memory");
      __builtin_amdgcn_s_barrier();
      __builtin_amdgcn_sched_barrier(0);
    }
  }

  const int rbase = m0 + wm*128 + (lane>>4)*4;
  const int cbase = n0 + wn*64 + (lane&15);
  #pragma unroll
  for (int fi=0;fi<8;fi++)
    #pragma unroll
    for (int fj=0;fj<4;fj++)
      #pragma unroll
      for (int r=0;r<4;r++){
        int row = rbase + fi*16 + r;
        int col = cbase + fj*16;
        float v = acc[fi][fj][r];
        if (OUT_BF16) ((ushort*)Cv)[(size_t)row*N + col] = f2bf(v);
        else          ((float*) Cv)[(size_t)row*N + col] = v;
      }
}

// ---------------- wbT[h][d] bf16 <- wb[d][h] f32 ----------------
__global__ __launch_bounds__(256) void k_wbt(const float* __restrict__ wb, ushort* __restrict__ wbT){
  int d = blockIdx.x*256 + threadIdx.x;
  #pragma unroll
  for (int h=0;h<16;h++) wbT[(size_t)h*2048 + d] = f2bf(wb[(size_t)d*16 + h]);
}

// ---------------- beta = sigmoid(A16 @ wbT^T) via MFMA; out [b][h][l] f32 ----------------
__global__ __launch_bounds__(64) void k_beta2(const ushort* __restrict__ A16, const ushort* __restrict__ wbT,
                                              float* __restrict__ beta){
  const int rt = blockIdx.x;
  const int lane = threadIdx.x;
  const int lr = lane & 15, lk8 = (lane>>4)*8;
  const int r0 = rt*16;
  f32x4 acc0 = (f32x4){0.f,0.f,0.f,0.f};
  f32x4 acc1 = (f32x4){0.f,0.f,0.f,0.f};
  for (int k0=0; k0<2048; k0+=64){
    bf16x8 a0 = *(const bf16x8*)&A16[(size_t)(r0+lr)*2048 + k0 + lk8];
    bf16x8 b0 = *(const bf16x8*)&wbT[(size_t)lr*2048 + k0 + lk8];
    bf16x8 a1 = *(const bf16x8*)&A16[(size_t)(r0+lr)*2048 + k0 + 32 + lk8];
    bf16x8 b1 = *(const bf16x8*)&wbT[(size_t)lr*2048 + k0 + 32 + lk8];
    acc0 = mfma16(a0, b0, acc0);
    acc1 = mfma16(a1, b1, acc1);
  }
  const int h = lane & 15;
  const int rbase = r0 + (lane>>4)*4;
  #pragma unroll
  for (int r=0;r<4;r++){
    int row = rbase + r;
    int b = row >> 12, l = row & 4095;
    float sg = 1.f/(1.f + __expf(-(acc0[r] + acc1[r])));
    beta[((size_t)(b*H_ + h))*L_ + l] = sg;
  }
}

// ---------------- conv(K=4, causal)+SiLU+heads+l2norm, sliding window ----------------
__global__ __launch_bounds__(256) void k_conv2(const ushort* __restrict__ qkv,
      const float* __restrict__ wq, const float* __restrict__ wk, const float* __restrict__ wv,
      ushort* __restrict__ QH, ushort* __restrict__ KH, ushort* __restrict__ VH){
  const int seg = blockIdx.x, part = blockIdx.y, b = blockIdx.z;
  const int t = threadIdx.x;
  const int ch = t*8;
  const int h = t >> 4, d0 = (t & 15)*8;
  const float* wc = (part==0) ? wq : (part==1) ? wk : wv;
  ushort* outs = ((part==0) ? QH : (part==1) ? KH : VH)
                 + ((size_t)(b*H_ + h)*L_)*DK_ + d0;
  const ushort* inp = qkv + ((size_t)b*L_)*ND3 + part*D_ + ch;

  float wgt[4][8];
  #pragma unroll
  for (int j=0;j<8;j++){
    float4 w4 = *(const float4*)&wc[(ch + j)*4];
    wgt[0][j]=w4.x; wgt[1][j]=w4.y; wgt[2][j]=w4.z; wgt[3][j]=w4.w;
  }

  const int l0 = seg*32;
  float x0[8], x1[8], x2[8];
  {
    float* dsts[3] = {x0, x1, x2};
    #pragma unroll
    for (int i=0;i<3;i++){
      int l = l0 - 3 + i;
      float* d = dsts[i];
      if (l >= 0){
        const ushort* p = inp + (size_t)l*ND3;
        ushort4 a = *(const ushort4*)p, c = *(const ushort4*)(p+4);
        d[0]=bf2f(a.x); d[1]=bf2f(a.y); d[2]=bf2f(a.z); d[3]=bf2f(a.w);
        d[4]=bf2f(c.x); d[5]=bf2f(c.y); d[6]=bf2f(c.z); d[7]=bf2f(c.w);
      } else {
        #pragma unroll
        for (int j=0;j<8;j++) d[j] = 0.f;
      }
    }
  }

  for (int i=0;i<32;i++){
    const int l = l0 + i;
    float cur[8];
    {
      const ushort* p = inp + (size_t)l*ND3;
      ushort4 a = *(const ushort4*)p, c = *(const ushort4*)(p+4);
      cur[0]=bf2f(a.x); cur[1]=bf2f(a.y); cur[2]=bf2f(a.z); cur[3]=bf2f(a.w);
      cur[4]=bf2f(c.x); cur[5]=bf2f(c.y); cur[6]=bf2f(c.z); cur[7]=bf2f(c.w);
    }
    float y[8]; float ss = 0.f;
    #pragma unroll
    for (int j=0;j<8;j++){
      float yy = x0[j]*wgt[0][j] + x1[j]*wgt[1][j] + x2[j]*wgt[2][j] + cur[j]*wgt[3][j];
      yy = yy / (1.f + __expf(-yy));
      y[j] = yy; ss += yy*yy;
    }
    if (part < 2){
      #pragma unroll
      for (int m=1;m<16;m<<=1) ss += __shfl_xor(ss, m, 64);
      float sc = rsqrtf(ss + 1e-12f);
      #pragma unroll
      for (int j=0;j<8;j++) y[j] *= sc;
    }
    ushort4 o0, o1;
    o0.x=f2bf(y[0]); o0.y=f2bf(y[1]); o0.z=f2bf(y[2]); o0.w=f2bf(y[3]);
    o1.x=f2bf(y[4]); o1.y=f2bf(y[5]); o1.z=f2bf(y[6]); o1.w=f2bf(y[7]);
    ushort* op = outs + (size_t)l*DK_;
    *(ushort4*)op = o0; *(ushort4*)(op+4) = o1;
    #pragma unroll
    for (int j=0;j<8;j++){ x0[j]=x1[j]; x1[j]=x2[j]; x2[j]=cur[j]; }
  }
}

// ---------------- phase 1 v2: per-chunk Tb, M, Kt — register solve, 35KB LDS ----------------
__global__ __launch_bounds__(64) void k_prep(const ushort* __restrict__ QH, const ushort* __restrict__ KH,
      const float* __restrict__ BETA, ushort* __restrict__ TB, ushort* __restrict__ MM,
      ushort* __restrict__ KT){
  const int bid = blockIdx.x, bh = bid>>6, c = bid&63;
  const int lane = threadIdx.x;
  __shared__ ushort Ks[64][136];
  __shared__ __align__(16) char QA[17408];
  __shared__ float bs[64];
  ushort (*Qs)[136] = (ushort (*)[136])QA;
  float  (*As)[64]  = (float  (*)[64])QA;

  const ushort* kg = KH + ((size_t)bh*L_ + c*64)*DK_;
  const ushort* qg = QH + ((size_t)bh*L_ + c*64)*DK_;
  {
    const uint4* ks4 = (const uint4*)(kg + (size_t)lane*DK_);
    const uint4* qs4 = (const uint4*)(qg + (size_t)lane*DK_);
    uint4* kd = (uint4*)&Ks[lane][0];
    uint4* qd = (uint4*)&Qs[lane][0];
    #pragma unroll
    for (int i=0;i<16;i++){ kd[i] = ks4[i]; qd[i] = qs4[i]; }
    bs[lane] = BETA[(size_t)bh*L_ + c*64 + lane];
  }
  __syncthreads();
  const int lr = lane&15, lk = lane>>4;

  f32x4 gac[4][4];
  #pragma unroll
  for (int i=0;i<4;i++)
    #pragma unroll
    for (int j=0;j<4;j++) gac[i][j] = (f32x4){0.f,0.f,0.f,0.f};
  #pragma unroll
  for (int kk=0;kk<4;kk++){
    bf16x8 fr[4];
    #pragma unroll
    for (int i=0;i<4;i++) fr[i] = *(const bf16x8*)&Ks[i*16+lr][kk*32 + lk*8];
    #pragma unroll
    for (int mi=0;mi<4;mi++)
      #pragma unroll
      for (int ni=0;ni<4;ni++)
        gac[mi][ni] = mfma16(fr[mi], fr[ni], gac[mi][ni]);
  }
  {
    f32x4 mac[4][4];
    #pragma unroll
    for (int i=0;i<4;i++)
      #pragma unroll
      for (int j=0;j<4;j++) mac[i][j] = (f32x4){0.f,0.f,0.f,0.f};
    #pragma unroll
    for (int kk=0;kk<4;kk++){
      bf16x8 frq[4], frk[4];
      #pragma unroll
      for (int i=0;i<4;i++){
        frq[i] = *(const bf16x8*)&Qs[i*16+lr][kk*32 + lk*8];
        frk[i] = *(const bf16x8*)&Ks[i*16+lr][kk*32 + lk*8];
      }
      #pragma unroll
      for (int mi=0;mi<4;mi++)
        #pragma unroll
        for (int ni=0;ni<4;ni++)
          mac[mi][ni] = mfma16(frq[mi], frk[ni], mac[mi][ni]);
    }
    #pragma unroll
    for (int mi=0;mi<4;mi++)
      #pragma unroll
      for (int ni=0;ni<4;ni++)
        #pragma unroll
        for (int r=0;r<4;r++){
          int t = mi*16 + lk*4 + r, s = ni*16 + lr;
          float v = (s <= t) ? mac[mi][ni][r] : 0.f;
          MM[(size_t)bid*4096 + t*64 + s] = f2bf(v);
        }
  }
  __syncthreads();

  #pragma unroll
  for (int mi=0;mi<4;mi++)
    #pragma unroll
    for (int ni=0;ni<4;ni++)
      #pragma unroll
      for (int r=0;r<4;r++){
        int t = mi*16 + lk*4 + r, s = ni*16 + lr;
        As[t][s] = (s < t) ? (bs[t] * gac[mi][ni][r]) : 0.f;
      }
  __syncthreads();

  float rT[64];
  #pragma unroll
  for (int t=0;t<64;t++){
    float arow = As[t][lane];
    float a = (t==lane) ? 1.f : 0.f;
    #pragma unroll
    for (int s=0;s<t;s++){
      float cc = __int_as_float(__builtin_amdgcn_readlane(__float_as_int(arow), s));
      a -= cc * rT[s];
    }
    rT[t] = a;
  }
  {
    float bc = bs[lane];
    #pragma unroll
    for (int t=0;t<64;t++)
      TB[(size_t)bid*4096 + t*64 + lane] = f2bf(rT[t] * bc);
  }
  for (int d2=0; d2<64; d2++){
    unsigned uu = *(const unsigned*)&Ks[lane][2*d2];
    KT[(size_t)bid*8192 + (size_t)(2*d2)*64 + lane]   = (ushort)(uu & 0xffffu);
    KT[(size_t)bid*8192 + (size_t)(2*d2+1)*64 + lane] = (ushort)(uu >> 16);
  }
}

template<int LRB, int GRB, int NB, int XM>
__device__ __forceinline__ void stage_swz(const ushort* __restrict__ g, ushort* l,
                                          int colOff, int w, int lane){
  for (int idx = w; idx < NB/1024; idx += 4){
    int off = idx*1024 + lane*16;
    int row = off / LRB;
    int inner = off & (LRB-1);
    int src = row*GRB + colOff + (inner ^ ((row&XM)<<4));
    __builtin_amdgcn_global_load_lds(
      (const __attribute__((address_space(1))) void*)((const char*)g + src),
      (__attribute__((address_space(3))) void*)((char*)l + idx*1024), 16, 0, 0);
  }
}

// ======= chunk recurrence v3: 256 blocks (bh x dv-eighth), dbuf panels, raw barriers =======
// LDS 140KB: 2 x 66KB panel buffers {Kc,Qc,Ktc,Tbc,Mc,Vc(16col)} + Stl(4K)+Ztl(2K)+Utl(2K).
// Full chip (256 blocks); XCD-grouped: 8 dv-siblings of one bh share panels on one XCD.
__global__ __launch_bounds__(256) void k_chunkrec(const ushort* __restrict__ QH, const ushort* __restrict__ KH,
      const ushort* __restrict__ VH, const ushort* __restrict__ TB, const ushort* __restrict__ MM,
      const ushort* __restrict__ KT, ushort* __restrict__ OH){
  const int p = blockIdx.x;           // 0..255
  const int xg = p & 7, s = p >> 3;   // XCD (round-robin dispatch), slot within XCD
  const int bh = xg + (s >> 3)*8;     // 4 bh per XCD
  const int vo = s & 7;               // dv-eighth (16 cols)
  const int tid = threadIdx.x, lane = tid&63, w = tid>>6;
  const int lr = lane&15, lk = lane>>4;
  const int tw = w*16;                // t-strip for X/U/O
  const int dw = w*32;                // d-quarter for S-update

  __shared__ ushort SM[71680];        // 143,360 B
  ushort* Stl = SM + 67584;           // [16][128] 4KB
  ushort* Ztl = SM + 69632;           // [16][64]  2KB
  ushort* Utl = SM + 70656;           // [16][64]  2KB

  const ushort* kbase  = KH + ((size_t)bh*L_)*DK_;
  const ushort* qbase  = QH + ((size_t)bh*L_)*DK_;
  const ushort* vbase  = VH + ((size_t)bh*L_)*DK_;
  const ushort* tbase  = TB + ((size_t)bh*64)*4096;
  const ushort* mbase  = MM + ((size_t)bh*64)*4096;
  const ushort* ktbase = KT + ((size_t)bh*64)*8192;
  ushort* obase = OH + ((size_t)bh*L_)*DK_ + vo*16;

  auto stageall = [&](ushort* buf, int c){
    stage_swz<256,256,16384,7>(kbase  + (size_t)c*8192, buf,         0,     w, lane);
    stage_swz<256,256,16384,7>(qbase  + (size_t)c*8192, buf + 8192,  0,     w, lane);
    stage_swz<128,128,16384,7>(ktbase + (size_t)c*8192, buf + 16384, 0,     w, lane);
    stage_swz<128,128, 8192,7>(tbase  + (size_t)c*4096, buf + 24576, 0,     w, lane);
    stage_swz<128,128, 8192,7>(mbase  + (size_t)c*4096, buf + 28672, 0,     w, lane);
    stage_swz< 32,256, 2048,0>(vbase  + (size_t)c*8192, buf + 32768, vo*32, w, lane);
  };

  f32x4 Stf[2];                       // j 16 x d-quarter 32 per wave
  Stf[0] = (f32x4){0.f,0.f,0.f,0.f};
  Stf[1] = (f32x4){0.f,0.f,0.f,0.f};

  stageall(SM, 0);
  BAR_VMALL();

  for (int c=0; c<64; ++c){
    ushort* buf  = SM + (c&1)*33792;
    ushort* nbuf = SM + ((c+1)&1)*33792;
    const ushort* Kc  = buf;
    const ushort* Qc  = buf + 8192;
    const ushort* Ktc = buf + 16384;
    const ushort* Tbc = buf + 24576;
    const ushort* Mc  = buf + 28672;
    const ushort* Vc  = buf + 32768;

    if (c+1 < 64) stageall(nbuf, c+1);

    // St (old state) -> LDS; wave writes its d-quarter for all 16 j-rows
    #pragma unroll
    for (int nd=0;nd<2;nd++)
      #pragma unroll
      for (int r=0;r<4;r++){
        int j = lk*4 + r;
        int d = dw + nd*16 + lr;
        Stl[j*128 + (d ^ ((j&7)<<3))] = f2bf(Stf[nd][r]);
      }
    BAR_LGKM();

    // X = K · St^T   [t 16][j 16]
    f32x4 xac = (f32x4){0.f,0.f,0.f,0.f};
    #pragma unroll
    for (int kk=0;kk<4;kk++){
      int e = kk*32 + lk*8;
      int ta = tw + lr;
      bf16x8 ak  = *(const bf16x8*)&Kc[ta*128 + (e ^ ((ta&7)<<3))];
      bf16x8 bst = *(const bf16x8*)&Stl[lr*128 + (e ^ ((lr&7)<<3))];
      xac = mfma16(ak, bst, xac);
    }
    // Z = V - X  -> Ztl transposed [j][t]
    #pragma unroll
    for (int r=0;r<4;r++){
      int t = tw + lk*4 + r;
      int j = lr;
      float v = bf2f(Vc[t*16 + j]);
      Ztl[j*64 + (t ^ ((j&7)<<3))] = f2bf(v - xac[r]);
    }
    BAR_LGKM();

    // U = Tb · Z   [t 16][j 16]
    f32x4 uac = (f32x4){0.f,0.f,0.f,0.f};
    #pragma unroll
    for (int kk=0;kk<2;kk++){
      int e = kk*32 + lk*8;
      int ta = tw + lr;
      bf16x8 at = *(const bf16x8*)&Tbc[ta*64 + (e ^ ((ta&7)<<3))];
      bf16x8 bz = *(const bf16x8*)&Ztl[lr*64 + (e ^ ((lr&7)<<3))];
      uac = mfma16(at, bz, uac);
    }
    #pragma unroll
    for (int r=0;r<4;r++){
      int t = tw + lk*4 + r;
      int j = lr;
      Utl[j*64 + (t ^ ((j&7)<<3))] = f2bf(uac[r]);
    }
    BAR_LGKM();

    // O = Q·St^T + M·U  -> global
    f32x4 oac = (f32x4){0.f,0.f,0.f,0.f};
    #pragma unroll
    for (int kk=0;kk<4;kk++){
      int e = kk*32 + lk*8;
      int ta = tw + lr;
      bf16x8 aq  = *(const bf16x8*)&Qc[ta*128 + (e ^ ((ta&7)<<3))];
      bf16x8 bst = *(const bf16x8*)&Stl[lr*128 + (e ^ ((lr&7)<<3))];
      oac = mfma16(aq, bst, oac);
    }
    #pragma unroll
    for (int kk=0;kk<2;kk++){
      int e = kk*32 + lk*8;
      int ta = tw + lr;
      bf16x8 am = *(const bf16x8*)&Mc[ta*64 + (e ^ ((ta&7)<<3))];
      bf16x8 bu = *(const bf16x8*)&Utl[lr*64 + (e ^ ((lr&7)<<3))];
      oac = mfma16(am, bu, oac);
    }
    #pragma unroll
    for (int r=0;r<4;r++){
      int t = tw + lk*4 + r;
      int j = lr;
      obase[(size_t)(c*64 + t)*DK_ + j] = f2bf(oac[r]);
    }

    // S-update: Stf[j 16][d-quarter 32] += Ut · Kt
    #pragma unroll
    for (int kk=0;kk<2;kk++){
      int e = kk*32 + lk*8;
      bf16x8 au = *(const bf16x8*)&Utl[lr*64 + (e ^ ((lr&7)<<3))];
      #pragma unroll
      for (int nd=0;nd<2;nd++){
        int d = dw + nd*16 + lr;
        bf16x8 bk = *(const bf16x8*)&Ktc[d*64 + (e ^ ((d&7)<<3))];
        Stf[nd] = mfma16(au, bk, Stf[nd]);
      }
    }
    BAR_VMALL();
  }
}

__global__ __launch_bounds__(256) void k_norm(const ushort* __restrict__ OH, const float* __restrict__ gw,
                                              ushort* __restrict__ O2){
  const int blk = blockIdx.x;
  const int b = blk >> 12, l = blk & 4095;
  const int t = threadIdx.x;
  const int h = t >> 4, d0 = (t & 15) * 8;
  const ushort* ip = OH + ((size_t)(b*H_ + h)*L_ + l)*DK_ + d0;
  ushort4 a = *(const ushort4*)ip, c = *(const ushort4*)(ip+4);
  float x[8];
  x[0]=bf2f(a.x); x[1]=bf2f(a.y); x[2]=bf2f(a.z); x[3]=bf2f(a.w);
  x[4]=bf2f(c.x); x[5]=bf2f(c.y); x[6]=bf2f(c.z); x[7]=bf2f(c.w);
  float ss = 0.f;
  #pragma unroll
  for (int j=0;j<8;j++) ss += x[j]*x[j];
  #pragma unroll
  for (int m=1;m<16;m<<=1) ss += __shfl_xor(ss, m, 64);
  float sc = rsqrtf(ss * (1.f/128.f) + 1e-5f);
  ushort* opp = O2 + (size_t)blk*D_ + h*DK_ + d0;
  ushort4 o0, o1;
  o0.x=f2bf(x[0]*sc*gw[d0+0]); o0.y=f2bf(x[1]*sc*gw[d0+1]);
  o0.z=f2bf(x[2]*sc*gw[d0+2]); o0.w=f2bf(x[3]*sc*gw[d0+3]);
  o1.x=f2bf(x[4]*sc*gw[d0+4]); o1.y=f2bf(x[5]*sc*gw[d0+5]);
  o1.z=f2bf(x[6]*sc*gw[d0+6]); o1.w=f2bf(x[7]*sc*gw[d0+7]);
  *(ushort4*)opp = o0; *(ushort4*)(opp+4) = o1;
}

extern "C" void kernel_launch(void* const* d_in, const int* in_sizes, int n_in,
                              void* d_out, int out_size, void* d_ws, size_t ws_size,
                              hipStream_t stream) {
  (void)in_sizes; (void)n_in; (void)out_size; (void)ws_size;
  const float* hidden  = (const float*)d_in[0];
  const float* w_cattn = (const float*)d_in[1];
  const float* wq_conv = (const float*)d_in[2];
  const float* wk_conv = (const float*)d_in[3];
  const float* wv_conv = (const float*)d_in[4];
  const float* w_beta  = (const float*)d_in[5];
  const float* o_nw    = (const float*)d_in[6];
  const float* w_o     = (const float*)d_in[7];
  float* out = (float*)d_out;

  char* W = (char*)d_ws;                              // total 260,046,848 B (known-good size)
  ushort* A16   = (ushort*)(W);                       // 32MB ; -> OH after gemm1
  ushort* WcatT = (ushort*)(W + 33554432u);           // 24MB; dead after gemm1
  ushort* WoT   = (ushort*)(W + 33554432u);           //  8MB (alias, written after gemm1)
  float*  BETA  = (float*) (W + 41943040u);           // 512KB (alias in dead WcatT region)
  ushort* WBT   = (ushort*)(W + 42467328u);           // 64KB  (alias in dead WcatT region)
  ushort* QKV   = (ushort*)(W + 58720256u);           // 96MB; dead after conv
  ushort* TB    = (ushort*)(W + 58720256u);           // 16MB (alias in dead QKV)
  ushort* MM    = (ushort*)(W + 75497472u);           // 16MB
  ushort* KT    = (ushort*)(W + 92274688u);           // 32MB
  ushort* O2    = (ushort*)(W + 125829120u);          // 32MB
  ushort* QH    = (ushort*)(W + 159383552u);          // 32MB
  ushort* KH    = (ushort*)(W + 192937984u);          // 32MB
  ushort* VH    = (ushort*)(W + 226492416u);          // 32MB -> end 260,046,848
  ushort* OH = A16;

  k_cast<<<4096, 256, 0, stream>>>(hidden, A16, (BL_*D_)/4);
  k_transpose_cast<<<dim3(ND3/32, D_/32), dim3(32,8), 0, stream>>>(w_cattn, WcatT, D_, ND3);
  k_gemmks<1><<<dim3(ND3/256, BL_/256), 512, 0, stream>>>(A16, WcatT, QKV, BL_, ND3, D_);
  // WcatT region dead from here on
  k_transpose_cast<<<dim3(D_/32, D_/32), dim3(32,8), 0, stream>>>(w_o, WoT, D_, D_);
  k_wbt<<<8, 256, 0, stream>>>(w_beta, WBT);
  k_beta2<<<512, 64, 0, stream>>>(A16, WBT, BETA);
  k_conv2<<<dim3(128, 3, 2), 256, 0, stream>>>(QKV, wq_conv, wk_conv, wv_conv, QH, KH, VH);
  k_prep<<<2048, 64, 0, stream>>>(QH, KH, BETA, TB, MM, KT);
  k_chunkrec<<<256, 256, 0, stream>>>(QH, KH, VH, TB, MM, KT, OH);
  k_norm<<<BL_, 256, 0, stream>>>(OH, o_nw, O2);
  k_gemmks<0><<<dim3(D_/256, BL_/256), 512, 0, stream>>>(O2, WoT, out, BL_, D_, D_);
}

// Round 12
// 577.744 us; speedup vs baseline: 10.6939x; 1.0040x over previous
//
#include <hip/hip_runtime.h>
#include <stdint.h>

#define B_   2
#define L_   4096
#define D_   2048
#define H_   16
#define DK_  128
#define ND3  6144
#define BL_  8192

typedef __bf16 bf16x8 __attribute__((ext_vector_type(8)));
typedef float  f32x4  __attribute__((ext_vector_type(4)));

__device__ __forceinline__ float bf2f(ushort u){ return __uint_as_float(((unsigned)u)<<16); }
__device__ __forceinline__ ushort f2bf(float f){
  unsigned u = __float_as_uint(f);
  unsigned r = u + 0x7FFFu + ((u>>16)&1u);
  return (ushort)(r>>16);
}
__device__ __forceinline__ f32x4 mfma16(bf16x8 a, bf16x8 b, f32x4 c){
  return __builtin_amdgcn_mfma_f32_16x16x32_bf16(a, b, c, 0, 0, 0);
}

#define BAR_LGKM() do{ __builtin_amdgcn_sched_barrier(0); \
  asm volatile("s_waitcnt lgkmcnt(0)" ::: "memory"); \
  __builtin_amdgcn_s_barrier(); \
  __builtin_amdgcn_sched_barrier(0);}while(0)
#define BAR_VMALL() do{ __builtin_amdgcn_sched_barrier(0); \
  asm volatile("s_waitcnt vmcnt(0) lgkmcnt(0)" ::: "memory"); \
  __builtin_amdgcn_s_barrier(); \
  __builtin_amdgcn_sched_barrier(0);}while(0)

__global__ __launch_bounds__(256) void k_cast(const float* __restrict__ x, ushort* __restrict__ y, int n4){
  int i = blockIdx.x*blockDim.x + threadIdx.x;
  int stride = gridDim.x*blockDim.x;
  for (; i < n4; i += stride){
    float4 v = ((const float4*)x)[i];
    ushort4 o; o.x=f2bf(v.x); o.y=f2bf(v.y); o.z=f2bf(v.z); o.w=f2bf(v.w);
    ((ushort4*)y)[i] = o;
  }
}

__global__ __launch_bounds__(256) void k_transpose_cast(const float* __restrict__ in, ushort* __restrict__ out,
                                                        int R, int C){
  __shared__ float tile[32][33];
  int c0 = blockIdx.x*32, r0 = blockIdx.y*32;
  int tx = threadIdx.x, ty = threadIdx.y;
  #pragma unroll
  for (int i=0;i<32;i+=8) tile[ty+i][tx] = in[(size_t)(r0+ty+i)*C + (c0+tx)];
  __syncthreads();
  #pragma unroll
  for (int i=0;i<32;i+=8) out[(size_t)(c0+ty+i)*R + (r0+tx)] = f2bf(tile[tx][ty+i]);
}

// ======== 256x256 GEMM, m201-style 4-quadrant phases, 2 dbuf, counted vmcnt ========
// 8 waves (2M x 4N); wave C = 128x64 spanning both A-halves (fi<4 -> half0 rows wm*64,
// fi>=4 -> half1) and both B-halves (fj<2 -> half0 cols wn*32, fj>=2 -> half1).
// LDS per buf: A half h @ +h*16K, B half h @ +32K+h*16K. Half = 8 bands x 2 kk x 1KB
// blocks; fragment read = 64 consecutive lanes x 16B (zero bank conflict); DMA dst =
// uniform base + lane*16. Quadrant order (0,0),(0,1),(1,1),(1,0): A0 retires @p2,
// B1 @p3. Stages: p1->A1(t+1) otherbuf, p2->B0(t+1) otherbuf, p3->A0(t+2) samebuf,
// p4->B1(t+2) samebuf + vmcnt(4). All stages target retired regions (issued after the
// retiring barrier); vmcnt(4) at p4 guarantees every half lands >=1 phase before use.
template<int OUT_BF16>
__global__ __launch_bounds__(512, 1) void k_gemm8(const ushort* __restrict__ A, const ushort* __restrict__ Bt,
                                                  void* __restrict__ Cv, int M, int N, int K){
  __shared__ ushort LDSB[65536];   // 128 KB = 2 bufs x (A 32K | B 32K)
  char* lds = (char*)LDSB;
  const int tid = threadIdx.x, lane = tid & 63, w = tid >> 6;
  const int wm = w >> 2, wn = w & 3;
  int nwg = gridDim.x*gridDim.y;
  int id  = blockIdx.y*gridDim.x + blockIdx.x;
  int sw  = ((nwg & 7) == 0) ? ((id & 7)*(nwg >> 3) + (id >> 3)) : id;
  const int bx = sw % gridDim.x, by = sw / gridDim.x;
  const int m0 = by*256, n0 = bx*256;
  const int NT = K >> 6;                 // K-tiles of 64
  const size_t rowb = (size_t)K*2;
  const char* gA = (const char*)A  + (size_t)m0*rowb;
  const char* gB = (const char*)Bt + (size_t)n0*rowb;

  f32x4 acc[8][4];
  #pragma unroll
  for (int i=0;i<8;i++)
    #pragma unroll
    for (int j=0;j<4;j++) acc[i][j] = (f32x4){0.f,0.f,0.f,0.f};

  // stage half-tile: which 0=A0 1=A1 2=B0 3=B1 of tile T into buf d2 (2 loads/thread)
  auto stage = [&](int d2, int which, int T){
    const int isB = which >> 1, h = which & 1;
    const char* g = isB ? gB : gA;
    char* halfbase = lds + d2*65536 + isB*32768 + h*16384;
    #pragma unroll
    for (int uu=0; uu<2; ++uu){
      int u = tid + uu*512;              // unit in [0,1024)
      int band = u >> 7, kk = (u >> 6) & 1, lr = u & 15, lk = (u >> 4) & 3;
      const char* src = g + (size_t)(h*128 + band*16 + lr)*rowb + (size_t)T*128 + kk*64 + lk*16;
      __builtin_amdgcn_global_load_lds(
        (const __attribute__((address_space(1))) void*)src,
        (__attribute__((address_space(3))) void*)(halfbase + u*16), 16, 0, 0);
    }
  };

  // prologue: tile0 all 4 halves -> buf0; A0,B1 of tile1 -> buf1; wait tile0 landed
  stage(0, 0, 0); stage(0, 1, 0); stage(0, 2, 0); stage(0, 3, 0);
  {
    int t1 = (1 < NT) ? 1 : 0;
    stage(1, 0, t1); stage(1, 3, t1);
  }
  __builtin_amdgcn_sched_barrier(0);
  asm volatile("s_waitcnt vmcnt(4)" ::: "memory");
  __builtin_amdgcn_s_barrier();
  __builtin_amdgcn_sched_barrier(0);

  for (int t = 0; t < NT; ++t){
    const int d = t & 1;
    const char* bufb = lds + d*65536;
    const int tn1 = (t+1 < NT) ? t+1 : NT-1;
    const int tn2 = (t+2 < NT) ? t+2 : NT-1;
    #pragma unroll
    for (int q = 0; q < 4; ++q){
      const int qm = q >> 1;
      const int qn = (q ^ (q >> 1)) & 1;   // order (0,0),(0,1),(1,1),(1,0)
      bf16x8 af[4][2], bfr[2][2];
      #pragma unroll
      for (int il=0; il<4; ++il)
        #pragma unroll
        for (int kk=0; kk<2; ++kk)
          af[il][kk] = *(const bf16x8*)(bufb + qm*16384 + ((wm*4+il)*2+kk)*1024 + lane*16);
      #pragma unroll
      for (int jl=0; jl<2; ++jl)
        #pragma unroll
        for (int kk=0; kk<2; ++kk)
          bfr[jl][kk] = *(const bf16x8*)(bufb + 32768 + qn*16384 + ((wn*2+jl)*2+kk)*1024 + lane*16);
      // stage per schedule (targets proven-retired regions)
      if      (q == 0) stage(d^1, 1, tn1);
      else if (q == 1) stage(d^1, 2, tn1);
      else if (q == 2) stage(d,   0, tn2);
      else             stage(d,   3, tn2);
      __builtin_amdgcn_sched_barrier(0);
      asm volatile("s_waitcnt lgkmcnt(8)" ::: "memory");
      __builtin_amdgcn_s_barrier();
      asm volatile("s_waitcnt lgkmcnt(0)" ::: "memory");
      __builtin_amdgcn_sched_barrier(0);
      __builtin_amdgcn_s_setprio(1);
      #pragma unroll
      for (int kk=0; kk<2; ++kk)
        #pragma unroll
        for (int il=0; il<4; ++il)
          #pragma unroll
          for (int jl=0; jl<2; ++jl)
            acc[qm*4+il][qn*2+jl] = mfma16(af[il][kk], bfr[jl][kk], acc[qm*4+il][qn*2+jl]);
      __builtin_amdgcn_s_setprio(0);
      __builtin_amdgcn_sched_barrier(0);
      if (q == 3){ asm volatile("s_waitcnt vmcnt(4)" ::: "memory"); }
      __builtin_amdgcn_s_barrier();
      __builtin_amdgcn_sched_barrier(0);
    }
  }
  // drain outstanding dummy DMA before workgroup can end
  asm volatile("s_waitcnt vmcnt(0) lgkmcnt(0)" ::: "memory");

  // epilogue: fi<4 -> half0 rows m0+wm*64+fi*16 ; fi>=4 -> half1 rows m0+128+wm*64+(fi-4)*16
  #pragma unroll
  for (int fi=0; fi<8; ++fi){
    int row0 = m0 + (fi>>2)*128 + wm*64 + (fi&3)*16 + (lane>>4)*4;
    #pragma unroll
    for (int fj=0; fj<4; ++fj){
      int col = n0 + (fj>>1)*128 + wn*32 + (fj&1)*16 + (lane&15);
      #pragma unroll
      for (int r=0; r<4; ++r){
        float v = acc[fi][fj][r];
        if (OUT_BF16) ((ushort*)Cv)[(size_t)(row0+r)*N + col] = f2bf(v);
        else          ((float*) Cv)[(size_t)(row0+r)*N + col] = v;
      }
    }
  }
}

// ---------------- wbT[h][d] bf16 <- wb[d][h] f32 ----------------
__global__ __launch_bounds__(256) void k_wbt(const float* __restrict__ wb, ushort* __restrict__ wbT){
  int d = blockIdx.x*256 + threadIdx.x;
  #pragma unroll
  for (int h=0;h<16;h++) wbT[(size_t)h*2048 + d] = f2bf(wb[(size_t)d*16 + h]);
}

// ---------------- beta = sigmoid(A16 @ wbT^T) via MFMA; out [b][h][l] f32 ----------------
__global__ __launch_bounds__(64) void k_beta2(const ushort* __restrict__ A16, const ushort* __restrict__ wbT,
                                              float* __restrict__ beta){
  const int rt = blockIdx.x;
  const int lane = threadIdx.x;
  const int lr = lane & 15, lk8 = (lane>>4)*8;
  const int r0 = rt*16;
  f32x4 acc0 = (f32x4){0.f,0.f,0.f,0.f};
  f32x4 acc1 = (f32x4){0.f,0.f,0.f,0.f};
  for (int k0=0; k0<2048; k0+=64){
    bf16x8 a0 = *(const bf16x8*)&A16[(size_t)(r0+lr)*2048 + k0 + lk8];
    bf16x8 b0 = *(const bf16x8*)&wbT[(size_t)lr*2048 + k0 + lk8];
    bf16x8 a1 = *(const bf16x8*)&A16[(size_t)(r0+lr)*2048 + k0 + 32 + lk8];
    bf16x8 b1 = *(const bf16x8*)&wbT[(size_t)lr*2048 + k0 + 32 + lk8];
    acc0 = mfma16(a0, b0, acc0);
    acc1 = mfma16(a1, b1, acc1);
  }
  const int h = lane & 15;
  const int rbase = r0 + (lane>>4)*4;
  #pragma unroll
  for (int r=0;r<4;r++){
    int row = rbase + r;
    int b = row >> 12, l = row & 4095;
    float sg = 1.f/(1.f + __expf(-(acc0[r] + acc1[r])));
    beta[((size_t)(b*H_ + h))*L_ + l] = sg;
  }
}

// ---------------- conv(K=4, causal)+SiLU+heads+l2norm, sliding window ----------------
__global__ __launch_bounds__(256) void k_conv2(const ushort* __restrict__ qkv,
      const float* __restrict__ wq, const float* __restrict__ wk, const float* __restrict__ wv,
      ushort* __restrict__ QH, ushort* __restrict__ KH, ushort* __restrict__ VH){
  const int seg = blockIdx.x, part = blockIdx.y, b = blockIdx.z;
  const int t = threadIdx.x;
  const int ch = t*8;
  const int h = t >> 4, d0 = (t & 15)*8;
  const float* wc = (part==0) ? wq : (part==1) ? wk : wv;
  ushort* outs = ((part==0) ? QH : (part==1) ? KH : VH)
                 + ((size_t)(b*H_ + h)*L_)*DK_ + d0;
  const ushort* inp = qkv + ((size_t)b*L_)*ND3 + part*D_ + ch;

  float wgt[4][8];
  #pragma unroll
  for (int j=0;j<8;j++){
    float4 w4 = *(const float4*)&wc[(ch + j)*4];
    wgt[0][j]=w4.x; wgt[1][j]=w4.y; wgt[2][j]=w4.z; wgt[3][j]=w4.w;
  }

  const int l0 = seg*32;
  float x0[8], x1[8], x2[8];
  {
    float* dsts[3] = {x0, x1, x2};
    #pragma unroll
    for (int i=0;i<3;i++){
      int l = l0 - 3 + i;
      float* d = dsts[i];
      if (l >= 0){
        const ushort* p = inp + (size_t)l*ND3;
        ushort4 a = *(const ushort4*)p, c = *(const ushort4*)(p+4);
        d[0]=bf2f(a.x); d[1]=bf2f(a.y); d[2]=bf2f(a.z); d[3]=bf2f(a.w);
        d[4]=bf2f(c.x); d[5]=bf2f(c.y); d[6]=bf2f(c.z); d[7]=bf2f(c.w);
      } else {
        #pragma unroll
        for (int j=0;j<8;j++) d[j] = 0.f;
      }
    }
  }

  for (int i=0;i<32;i++){
    const int l = l0 + i;
    float cur[8];
    {
      const ushort* p = inp + (size_t)l*ND3;
      ushort4 a = *(const ushort4*)p, c = *(const ushort4*)(p+4);
      cur[0]=bf2f(a.x); cur[1]=bf2f(a.y); cur[2]=bf2f(a.z); cur[3]=bf2f(a.w);
      cur[4]=bf2f(c.x); cur[5]=bf2f(c.y); cur[6]=bf2f(c.z); cur[7]=bf2f(c.w);
    }
    float y[8]; float ss = 0.f;
    #pragma unroll
    for (int j=0;j<8;j++){
      float yy = x0[j]*wgt[0][j] + x1[j]*wgt[1][j] + x2[j]*wgt[2][j] + cur[j]*wgt[3][j];
      yy = yy / (1.f + __expf(-yy));
      y[j] = yy; ss += yy*yy;
    }
    if (part < 2){
      #pragma unroll
      for (int m=1;m<16;m<<=1) ss += __shfl_xor(ss, m, 64);
      float sc = rsqrtf(ss + 1e-12f);
      #pragma unroll
      for (int j=0;j<8;j++) y[j] *= sc;
    }
    ushort4 o0, o1;
    o0.x=f2bf(y[0]); o0.y=f2bf(y[1]); o0.z=f2bf(y[2]); o0.w=f2bf(y[3]);
    o1.x=f2bf(y[4]); o1.y=f2bf(y[5]); o1.z=f2bf(y[6]); o1.w=f2bf(y[7]);
    ushort* op = outs + (size_t)l*DK_;
    *(ushort4*)op = o0; *(ushort4*)(op+4) = o1;
    #pragma unroll
    for (int j=0;j<8;j++){ x0[j]=x1[j]; x1[j]=x2[j]; x2[j]=cur[j]; }
  }
}

// ---------------- phase 1 v2: per-chunk Tb, M, Kt — register solve, 35KB LDS ----------------
__global__ __launch_bounds__(64) void k_prep(const ushort* __restrict__ QH, const ushort* __restrict__ KH,
      const float* __restrict__ BETA, ushort* __restrict__ TB, ushort* __restrict__ MM,
      ushort* __restrict__ KT){
  const int bid = blockIdx.x, bh = bid>>6, c = bid&63;
  const int lane = threadIdx.x;
  __shared__ ushort Ks[64][136];
  __shared__ __align__(16) char QA[17408];
  __shared__ float bs[64];
  ushort (*Qs)[136] = (ushort (*)[136])QA;
  float  (*As)[64]  = (float  (*)[64])QA;

  const ushort* kg = KH + ((size_t)bh*L_ + c*64)*DK_;
  const ushort* qg = QH + ((size_t)bh*L_ + c*64)*DK_;
  {
    const uint4* ks4 = (const uint4*)(kg + (size_t)lane*DK_);
    const uint4* qs4 = (const uint4*)(qg + (size_t)lane*DK_);
    uint4* kd = (uint4*)&Ks[lane][0];
    uint4* qd = (uint4*)&Qs[lane][0];
    #pragma unroll
    for (int i=0;i<16;i++){ kd[i] = ks4[i]; qd[i] = qs4[i]; }
    bs[lane] = BETA[(size_t)bh*L_ + c*64 + lane];
  }
  __syncthreads();
  const int lr = lane&15, lk = lane>>4;

  f32x4 gac[4][4];
  #pragma unroll
  for (int i=0;i<4;i++)
    #pragma unroll
    for (int j=0;j<4;j++) gac[i][j] = (f32x4){0.f,0.f,0.f,0.f};
  #pragma unroll
  for (int kk=0;kk<4;kk++){
    bf16x8 fr[4];
    #pragma unroll
    for (int i=0;i<4;i++) fr[i] = *(const bf16x8*)&Ks[i*16+lr][kk*32 + lk*8];
    #pragma unroll
    for (int mi=0;mi<4;mi++)
      #pragma unroll
      for (int ni=0;ni<4;ni++)
        gac[mi][ni] = mfma16(fr[mi], fr[ni], gac[mi][ni]);
  }
  {
    f32x4 mac[4][4];
    #pragma unroll
    for (int i=0;i<4;i++)
      #pragma unroll
      for (int j=0;j<4;j++) mac[i][j] = (f32x4){0.f,0.f,0.f,0.f};
    #pragma unroll
    for (int kk=0;kk<4;kk++){
      bf16x8 frq[4], frk[4];
      #pragma unroll
      for (int i=0;i<4;i++){
        frq[i] = *(const bf16x8*)&Qs[i*16+lr][kk*32 + lk*8];
        frk[i] = *(const bf16x8*)&Ks[i*16+lr][kk*32 + lk*8];
      }
      #pragma unroll
      for (int mi=0;mi<4;mi++)
        #pragma unroll
        for (int ni=0;ni<4;ni++)
          mac[mi][ni] = mfma16(frq[mi], frk[ni], mac[mi][ni]);
    }
    #pragma unroll
    for (int mi=0;mi<4;mi++)
      #pragma unroll
      for (int ni=0;ni<4;ni++)
        #pragma unroll
        for (int r=0;r<4;r++){
          int t = mi*16 + lk*4 + r, s = ni*16 + lr;
          float v = (s <= t) ? mac[mi][ni][r] : 0.f;
          MM[(size_t)bid*4096 + t*64 + s] = f2bf(v);
        }
  }
  __syncthreads();

  #pragma unroll
  for (int mi=0;mi<4;mi++)
    #pragma unroll
    for (int ni=0;ni<4;ni++)
      #pragma unroll
      for (int r=0;r<4;r++){
        int t = mi*16 + lk*4 + r, s = ni*16 + lr;
        As[t][s] = (s < t) ? (bs[t] * gac[mi][ni][r]) : 0.f;
      }
  __syncthreads();

  float rT[64];
  #pragma unroll
  for (int t=0;t<64;t++){
    float arow = As[t][lane];
    float a = (t==lane) ? 1.f : 0.f;
    #pragma unroll
    for (int s=0;s<t;s++){
      float cc = __int_as_float(__builtin_amdgcn_readlane(__float_as_int(arow), s));
      a -= cc * rT[s];
    }
    rT[t] = a;
  }
  {
    float bc = bs[lane];
    #pragma unroll
    for (int t=0;t<64;t++)
      TB[(size_t)bid*4096 + t*64 + lane] = f2bf(rT[t] * bc);
  }
  for (int d2=0; d2<64; d2++){
    unsigned uu = *(const unsigned*)&Ks[lane][2*d2];
    KT[(size_t)bid*8192 + (size_t)(2*d2)*64 + lane]   = (ushort)(uu & 0xffffu);
    KT[(size_t)bid*8192 + (size_t)(2*d2+1)*64 + lane] = (ushort)(uu >> 16);
  }
}

template<int LRB, int GRB, int NB, int XM>
__device__ __forceinline__ void stage_swz(const ushort* __restrict__ g, ushort* l,
                                          int colOff, int w, int lane){
  for (int idx = w; idx < NB/1024; idx += 4){
    int off = idx*1024 + lane*16;
    int row = off / LRB;
    int inner = off & (LRB-1);
    int src = row*GRB + colOff + (inner ^ ((row&XM)<<4));
    __builtin_amdgcn_global_load_lds(
      (const __attribute__((address_space(1))) void*)((const char*)g + src),
      (__attribute__((address_space(3))) void*)((char*)l + idx*1024), 16, 0, 0);
  }
}

// ======= chunk recurrence v3: 256 blocks (bh x dv-eighth), dbuf panels, raw barriers =======
__global__ __launch_bounds__(256) void k_chunkrec(const ushort* __restrict__ QH, const ushort* __restrict__ KH,
      const ushort* __restrict__ VH, const ushort* __restrict__ TB, const ushort* __restrict__ MM,
      const ushort* __restrict__ KT, ushort* __restrict__ OH){
  const int p = blockIdx.x;
  const int xg = p & 7, s = p >> 3;
  const int bh = xg + (s >> 3)*8;
  const int vo = s & 7;
  const int tid = threadIdx.x, lane = tid&63, w = tid>>6;
  const int lr = lane&15, lk = lane>>4;
  const int tw = w*16;
  const int dw = w*32;

  __shared__ ushort SM[71680];
  ushort* Stl = SM + 67584;
  ushort* Ztl = SM + 69632;
  ushort* Utl = SM + 70656;

  const ushort* kbase  = KH + ((size_t)bh*L_)*DK_;
  const ushort* qbase  = QH + ((size_t)bh*L_)*DK_;
  const ushort* vbase  = VH + ((size_t)bh*L_)*DK_;
  const ushort* tbase  = TB + ((size_t)bh*64)*4096;
  const ushort* mbase  = MM + ((size_t)bh*64)*4096;
  const ushort* ktbase = KT + ((size_t)bh*64)*8192;
  ushort* obase = OH + ((size_t)bh*L_)*DK_ + vo*16;

  auto stageall = [&](ushort* buf, int c){
    stage_swz<256,256,16384,7>(kbase  + (size_t)c*8192, buf,         0,     w, lane);
    stage_swz<256,256,16384,7>(qbase  + (size_t)c*8192, buf + 8192,  0,     w, lane);
    stage_swz<128,128,16384,7>(ktbase + (size_t)c*8192, buf + 16384, 0,     w, lane);
    stage_swz<128,128, 8192,7>(tbase  + (size_t)c*4096, buf + 24576, 0,     w, lane);
    stage_swz<128,128, 8192,7>(mbase  + (size_t)c*4096, buf + 28672, 0,     w, lane);
    stage_swz< 32,256, 2048,0>(vbase  + (size_t)c*8192, buf + 32768, vo*32, w, lane);
  };

  f32x4 Stf[2];
  Stf[0] = (f32x4){0.f,0.f,0.f,0.f};
  Stf[1] = (f32x4){0.f,0.f,0.f,0.f};

  stageall(SM, 0);
  BAR_VMALL();

  for (int c=0; c<64; ++c){
    ushort* buf  = SM + (c&1)*33792;
    ushort* nbuf = SM + ((c+1)&1)*33792;
    const ushort* Kc  = buf;
    const ushort* Qc  = buf + 8192;
    const ushort* Ktc = buf + 16384;
    const ushort* Tbc = buf + 24576;
    const ushort* Mc  = buf + 28672;
    const ushort* Vc  = buf + 32768;

    if (c+1 < 64) stageall(nbuf, c+1);

    #pragma unroll
    for (int nd=0;nd<2;nd++)
      #pragma unroll
      for (int r=0;r<4;r++){
        int j = lk*4 + r;
        int d = dw + nd*16 + lr;
        Stl[j*128 + (d ^ ((j&7)<<3))] = f2bf(Stf[nd][r]);
      }
    BAR_LGKM();

    f32x4 xac = (f32x4){0.f,0.f,0.f,0.f};
    #pragma unroll
    for (int kk=0;kk<4;kk++){
      int e = kk*32 + lk*8;
      int ta = tw + lr;
      bf16x8 ak  = *(const bf16x8*)&Kc[ta*128 + (e ^ ((ta&7)<<3))];
      bf16x8 bst = *(const bf16x8*)&Stl[lr*128 + (e ^ ((lr&7)<<3))];
      xac = mfma16(ak, bst, xac);
    }
    #pragma unroll
    for (int r=0;r<4;r++){
      int t = tw + lk*4 + r;
      int j = lr;
      float v = bf2f(Vc[t*16 + j]);
      Ztl[j*64 + (t ^ ((j&7)<<3))] = f2bf(v - xac[r]);
    }
    BAR_LGKM();

    f32x4 uac = (f32x4){0.f,0.f,0.f,0.f};
    #pragma unroll
    for (int kk=0;kk<2;kk++){
      int e = kk*32 + lk*8;
      int ta = tw + lr;
      bf16x8 at = *(const bf16x8*)&Tbc[ta*64 + (e ^ ((ta&7)<<3))];
      bf16x8 bz = *(const bf16x8*)&Ztl[lr*64 + (e ^ ((lr&7)<<3))];
      uac = mfma16(at, bz, uac);
    }
    #pragma unroll
    for (int r=0;r<4;r++){
      int t = tw + lk*4 + r;
      int j = lr;
      Utl[j*64 + (t ^ ((j&7)<<3))] = f2bf(uac[r]);
    }
    BAR_LGKM();

    f32x4 oac = (f32x4){0.f,0.f,0.f,0.f};
    #pragma unroll
    for (int kk=0;kk<4;kk++){
      int e = kk*32 + lk*8;
      int ta = tw + lr;
      bf16x8 aq  = *(const bf16x8*)&Qc[ta*128 + (e ^ ((ta&7)<<3))];
      bf16x8 bst = *(const bf16x8*)&Stl[lr*128 + (e ^ ((lr&7)<<3))];
      oac = mfma16(aq, bst, oac);
    }
    #pragma unroll
    for (int kk=0;kk<2;kk++){
      int e = kk*32 + lk*8;
      int ta = tw + lr;
      bf16x8 am = *(const bf16x8*)&Mc[ta*64 + (e ^ ((ta&7)<<3))];
      bf16x8 bu = *(const bf16x8*)&Utl[lr*64 + (e ^ ((lr&7)<<3))];
      oac = mfma16(am, bu, oac);
    }
    #pragma unroll
    for (int r=0;r<4;r++){
      int t = tw + lk*4 + r;
      int j = lr;
      obase[(size_t)(c*64 + t)*DK_ + j] = f2bf(oac[r]);
    }

    #pragma unroll
    for (int kk=0;kk<2;kk++){
      int e = kk*32 + lk*8;
      bf16x8 au = *(const bf16x8*)&Utl[lr*64 + (e ^ ((lr&7)<<3))];
      #pragma unroll
      for (int nd=0;nd<2;nd++){
        int d = dw + nd*16 + lr;
        bf16x8 bk = *(const bf16x8*)&Ktc[d*64 + (e ^ ((d&7)<<3))];
        Stf[nd] = mfma16(au, bk, Stf[nd]);
      }
    }
    BAR_VMALL();
  }
}

__global__ __launch_bounds__(256) void k_norm(const ushort* __restrict__ OH, const float* __restrict__ gw,
                                              ushort* __restrict__ O2){
  const int blk = blockIdx.x;
  const int b = blk >> 12, l = blk & 4095;
  const int t = threadIdx.x;
  const int h = t >> 4, d0 = (t & 15) * 8;
  const ushort* ip = OH + ((size_t)(b*H_ + h)*L_ + l)*DK_ + d0;
  ushort4 a = *(const ushort4*)ip, c = *(const ushort4*)(ip+4);
  float x[8];
  x[0]=bf2f(a.x); x[1]=bf2f(a.y); x[2]=bf2f(a.z); x[3]=bf2f(a.w);
  x[4]=bf2f(c.x); x[5]=bf2f(c.y); x[6]=bf2f(c.z); x[7]=bf2f(c.w);
  float ss = 0.f;
  #pragma unroll
  for (int j=0;j<8;j++) ss += x[j]*x[j];
  #pragma unroll
  for (int m=1;m<16;m<<=1) ss += __shfl_xor(ss, m, 64);
  float sc = rsqrtf(ss * (1.f/128.f) + 1e-5f);
  ushort* opp = O2 + (size_t)blk*D_ + h*DK_ + d0;
  ushort4 o0, o1;
  o0.x=f2bf(x[0]*sc*gw[d0+0]); o0.y=f2bf(x[1]*sc*gw[d0+1]);
  o0.z=f2bf(x[2]*sc*gw[d0+2]); o0.w=f2bf(x[3]*sc*gw[d0+3]);
  o1.x=f2bf(x[4]*sc*gw[d0+4]); o1.y=f2bf(x[5]*sc*gw[d0+5]);
  o1.z=f2bf(x[6]*sc*gw[d0+6]); o1.w=f2bf(x[7]*sc*gw[d0+7]);
  *(ushort4*)opp = o0; *(ushort4*)(opp+4) = o1;
}

extern "C" void kernel_launch(void* const* d_in, const int* in_sizes, int n_in,
                              void* d_out, int out_size, void* d_ws, size_t ws_size,
                              hipStream_t stream) {
  (void)in_sizes; (void)n_in; (void)out_size; (void)ws_size;
  const float* hidden  = (const float*)d_in[0];
  const float* w_cattn = (const float*)d_in[1];
  const float* wq_conv = (const float*)d_in[2];
  const float* wk_conv = (const float*)d_in[3];
  const float* wv_conv = (const float*)d_in[4];
  const float* w_beta  = (const float*)d_in[5];
  const float* o_nw    = (const float*)d_in[6];
  const float* w_o     = (const float*)d_in[7];
  float* out = (float*)d_out;

  char* W = (char*)d_ws;                              // total 260,046,848 B (known-good size)
  ushort* A16   = (ushort*)(W);                       // 32MB ; -> OH after gemm1
  ushort* WcatT = (ushort*)(W + 33554432u);           // 24MB; dead after gemm1
  ushort* WoT   = (ushort*)(W + 33554432u);           //  8MB (alias, written after gemm1)
  float*  BETA  = (float*) (W + 41943040u);           // 512KB (alias in dead WcatT region)
  ushort* WBT   = (ushort*)(W + 42467328u);           // 64KB  (alias in dead WcatT region)
  ushort* QKV   = (ushort*)(W + 58720256u);           // 96MB; dead after conv
  ushort* TB    = (ushort*)(W + 58720256u);           // 16MB (alias in dead QKV)
  ushort* MM    = (ushort*)(W + 75497472u);           // 16MB
  ushort* KT    = (ushort*)(W + 92274688u);           // 32MB
  ushort* O2    = (ushort*)(W + 125829120u);          // 32MB
  ushort* QH    = (ushort*)(W + 159383552u);          // 32MB
  ushort* KH    = (ushort*)(W + 192937984u);          // 32MB
  ushort* VH    = (ushort*)(W + 226492416u);          // 32MB -> end 260,046,848
  ushort* OH = A16;

  k_cast<<<4096, 256, 0, stream>>>(hidden, A16, (BL_*D_)/4);
  k_transpose_cast<<<dim3(ND3/32, D_/32), dim3(32,8), 0, stream>>>(w_cattn, WcatT, D_, ND3);
  k_gemm8<1><<<dim3(ND3/256, BL_/256), 512, 0, stream>>>(A16, WcatT, QKV, BL_, ND3, D_);
  // WcatT region dead from here on
  k_transpose_cast<<<dim3(D_/32, D_/32), dim3(32,8), 0, stream>>>(w_o, WoT, D_, D_);
  k_wbt<<<8, 256, 0, stream>>>(w_beta, WBT);
  k_beta2<<<512, 64, 0, stream>>>(A16, WBT, BETA);
  k_conv2<<<dim3(128, 3, 2), 256, 0, stream>>>(QKV, wq_conv, wk_conv, wv_conv, QH, KH, VH);
  k_prep<<<2048, 64, 0, stream>>>(QH, KH, BETA, TB, MM, KT);
  k_chunkrec<<<256, 256, 0, stream>>>(QH, KH, VH, TB, MM, KT, OH);
  k_norm<<<BL_, 256, 0, stream>>>(OH, o_nw, O2);
  k_gemm8<0><<<dim3(D_/256, BL_/256), 512, 0, stream>>>(O2, WoT, out, BL_, D_, D_);
}

// Round 13
// 574.209 us; speedup vs baseline: 10.7598x; 1.0062x over previous
//
#include <hip/hip_runtime.h>
#include <stdint.h>

#define B_   2
#define L_   4096
#define D_   2048
#define H_   16
#define DK_  128
#define ND3  6144
#define BL_  8192

typedef __bf16 bf16x8 __attribute__((ext_vector_type(8)));
typedef float  f32x4  __attribute__((ext_vector_type(4)));

__device__ __forceinline__ float bf2f(ushort u){ return __uint_as_float(((unsigned)u)<<16); }
__device__ __forceinline__ ushort f2bf(float f){
  unsigned u = __float_as_uint(f);
  unsigned r = u + 0x7FFFu + ((u>>16)&1u);
  return (ushort)(r>>16);
}
__device__ __forceinline__ f32x4 mfma16(bf16x8 a, bf16x8 b, f32x4 c){
  return __builtin_amdgcn_mfma_f32_16x16x32_bf16(a, b, c, 0, 0, 0);
}

#define BAR_LGKM() do{ __builtin_amdgcn_sched_barrier(0); \
  asm volatile("s_waitcnt lgkmcnt(0)" ::: "memory"); \
  __builtin_amdgcn_s_barrier(); \
  __builtin_amdgcn_sched_barrier(0);}while(0)
#define BAR_VMALL() do{ __builtin_amdgcn_sched_barrier(0); \
  asm volatile("s_waitcnt vmcnt(0) lgkmcnt(0)" ::: "memory"); \
  __builtin_amdgcn_s_barrier(); \
  __builtin_amdgcn_sched_barrier(0);}while(0)

__global__ __launch_bounds__(256) void k_cast(const float* __restrict__ x, ushort* __restrict__ y, int n4){
  int i = blockIdx.x*blockDim.x + threadIdx.x;
  int stride = gridDim.x*blockDim.x;
  for (; i < n4; i += stride){
    float4 v = ((const float4*)x)[i];
    ushort4 o; o.x=f2bf(v.x); o.y=f2bf(v.y); o.z=f2bf(v.z); o.w=f2bf(v.w);
    ((ushort4*)y)[i] = o;
  }
}

__global__ __launch_bounds__(256) void k_transpose_cast(const float* __restrict__ in, ushort* __restrict__ out,
                                                        int R, int C){
  __shared__ float tile[32][33];
  int c0 = blockIdx.x*32, r0 = blockIdx.y*32;
  int tx = threadIdx.x, ty = threadIdx.y;
  #pragma unroll
  for (int i=0;i<32;i+=8) tile[ty+i][tx] = in[(size_t)(r0+ty+i)*C + (c0+tx)];
  __syncthreads();
  #pragma unroll
  for (int i=0;i<32;i+=8) out[(size_t)(c0+ty+i)*R + (r0+tx)] = f2bf(tile[tx][ty+i]);
}

// ======== 256x256 GEMM, m201 4-quadrant phases + FRAGMENT REGISTER REUSE ========
// Quadrant order (0,0),(0,1),(1,1),(1,0). Per tile LDS reads: p1 A0(8)+B0(4),
// p2 B1(4) [A0 reused], p3 A1(8) [B1 reused], p4 none [A1+B0 reused] = 24 reads
// (was 48) -> halves LDS-read demand, the measured bottleneck (~85 B/cyc ceiling).
// Stage schedule & vmcnt identical to the verified round-12 kernel:
// p1->A1(t+1) otherbuf, p2->B0(t+1) otherbuf, p3->A0(t+2) samebuf, p4->B1(t+2)
// samebuf + vmcnt(4). Every stage targets a region whose last LDS read finished
// >=2 barriers earlier (A0 read p1-of-t, staged p3-of-t; B1 read p2, staged p4;
// A1/B0 of otherbuf last read in tile t-1).
template<int OUT_BF16>
__global__ __launch_bounds__(512, 1) void k_gemm8(const ushort* __restrict__ A, const ushort* __restrict__ Bt,
                                                  void* __restrict__ Cv, int M, int N, int K){
  __shared__ ushort LDSB[65536];   // 128 KB = 2 bufs x (A 32K | B 32K)
  char* lds = (char*)LDSB;
  const int tid = threadIdx.x, lane = tid & 63, w = tid >> 6;
  const int wm = w >> 2, wn = w & 3;
  int nwg = gridDim.x*gridDim.y;
  int id  = blockIdx.y*gridDim.x + blockIdx.x;
  int sw  = ((nwg & 7) == 0) ? ((id & 7)*(nwg >> 3) + (id >> 3)) : id;
  const int bx = sw % gridDim.x, by = sw / gridDim.x;
  const int m0 = by*256, n0 = bx*256;
  const int NT = K >> 6;                 // K-tiles of 64
  const size_t rowb = (size_t)K*2;
  const char* gA = (const char*)A  + (size_t)m0*rowb;
  const char* gB = (const char*)Bt + (size_t)n0*rowb;

  f32x4 acc[8][4];
  #pragma unroll
  for (int i=0;i<8;i++)
    #pragma unroll
    for (int j=0;j<4;j++) acc[i][j] = (f32x4){0.f,0.f,0.f,0.f};

  // stage half-tile: which 0=A0 1=A1 2=B0 3=B1 of tile T into buf d2 (2 loads/thread)
  auto stage = [&](int d2, int which, int T){
    const int isB = which >> 1, h = which & 1;
    const char* g = isB ? gB : gA;
    char* halfbase = lds + d2*65536 + isB*32768 + h*16384;
    #pragma unroll
    for (int uu=0; uu<2; ++uu){
      int u = tid + uu*512;              // unit in [0,1024)
      int band = u >> 7, kk = (u >> 6) & 1, lr = u & 15, lk = (u >> 4) & 3;
      const char* src = g + (size_t)(h*128 + band*16 + lr)*rowb + (size_t)T*128 + kk*64 + lk*16;
      __builtin_amdgcn_global_load_lds(
        (const __attribute__((address_space(1))) void*)src,
        (__attribute__((address_space(3))) void*)(halfbase + u*16), 16, 0, 0);
    }
  };

  // prologue: tile0 all 4 halves -> buf0; A0,B1 of tile1 -> buf1; wait tile0 landed
  stage(0, 0, 0); stage(0, 1, 0); stage(0, 2, 0); stage(0, 3, 0);
  {
    int t1 = (1 < NT) ? 1 : 0;
    stage(1, 0, t1); stage(1, 3, t1);
  }
  __builtin_amdgcn_sched_barrier(0);
  asm volatile("s_waitcnt vmcnt(4)" ::: "memory");
  __builtin_amdgcn_s_barrier();
  __builtin_amdgcn_sched_barrier(0);

  for (int t = 0; t < NT; ++t){
    const int d = t & 1;
    const char* bufb = lds + d*65536;
    const int tn1 = (t+1 < NT) ? t+1 : NT-1;
    const int tn2 = (t+2 < NT) ? t+2 : NT-1;

    bf16x8 afr[4][2];          // current A-half fragments (A0 for p1/p2, A1 for p3/p4)
    bf16x8 b0r[2][2], b1r[2][2];

    // ======== p1: quadrant (0,0) — read A0 + B0; stage A1(t+1)->otherbuf ========
    #pragma unroll
    for (int il=0; il<4; ++il)
      #pragma unroll
      for (int kk=0; kk<2; ++kk)
        afr[il][kk] = *(const bf16x8*)(bufb + ((wm*4+il)*2+kk)*1024 + lane*16);
    #pragma unroll
    for (int jl=0; jl<2; ++jl)
      #pragma unroll
      for (int kk=0; kk<2; ++kk)
        b0r[jl][kk] = *(const bf16x8*)(bufb + 32768 + ((wn*2+jl)*2+kk)*1024 + lane*16);
    stage(d^1, 1, tn1);
    __builtin_amdgcn_sched_barrier(0);
    __builtin_amdgcn_s_barrier();
    asm volatile("s_waitcnt lgkmcnt(0)" ::: "memory");
    __builtin_amdgcn_sched_barrier(0);
    __builtin_amdgcn_s_setprio(1);
    #pragma unroll
    for (int kk=0; kk<2; ++kk)
      #pragma unroll
      for (int il=0; il<4; ++il)
        #pragma unroll
        for (int jl=0; jl<2; ++jl)
          acc[il][jl] = mfma16(afr[il][kk], b0r[jl][kk], acc[il][jl]);
    __builtin_amdgcn_s_setprio(0);
    __builtin_amdgcn_sched_barrier(0);
    __builtin_amdgcn_s_barrier();
    __builtin_amdgcn_sched_barrier(0);

    // ======== p2: quadrant (0,1) — read B1 (reuse A0); stage B0(t+1)->otherbuf ========
    #pragma unroll
    for (int jl=0; jl<2; ++jl)
      #pragma unroll
      for (int kk=0; kk<2; ++kk)
        b1r[jl][kk] = *(const bf16x8*)(bufb + 32768 + 16384 + ((wn*2+jl)*2+kk)*1024 + lane*16);
    stage(d^1, 2, tn1);
    __builtin_amdgcn_sched_barrier(0);
    __builtin_amdgcn_s_barrier();
    asm volatile("s_waitcnt lgkmcnt(0)" ::: "memory");
    __builtin_amdgcn_sched_barrier(0);
    __builtin_amdgcn_s_setprio(1);
    #pragma unroll
    for (int kk=0; kk<2; ++kk)
      #pragma unroll
      for (int il=0; il<4; ++il)
        #pragma unroll
        for (int jl=0; jl<2; ++jl)
          acc[il][2+jl] = mfma16(afr[il][kk], b1r[jl][kk], acc[il][2+jl]);
    __builtin_amdgcn_s_setprio(0);
    __builtin_amdgcn_sched_barrier(0);
    __builtin_amdgcn_s_barrier();
    __builtin_amdgcn_sched_barrier(0);

    // ======== p3: quadrant (1,1) — read A1 (reuse B1); stage A0(t+2)->samebuf ========
    #pragma unroll
    for (int il=0; il<4; ++il)
      #pragma unroll
      for (int kk=0; kk<2; ++kk)
        afr[il][kk] = *(const bf16x8*)(bufb + 16384 + ((wm*4+il)*2+kk)*1024 + lane*16);
    stage(d, 0, tn2);
    __builtin_amdgcn_sched_barrier(0);
    __builtin_amdgcn_s_barrier();
    asm volatile("s_waitcnt lgkmcnt(0)" ::: "memory");
    __builtin_amdgcn_sched_barrier(0);
    __builtin_amdgcn_s_setprio(1);
    #pragma unroll
    for (int kk=0; kk<2; ++kk)
      #pragma unroll
      for (int il=0; il<4; ++il)
        #pragma unroll
        for (int jl=0; jl<2; ++jl)
          acc[4+il][2+jl] = mfma16(afr[il][kk], b1r[jl][kk], acc[4+il][2+jl]);
    __builtin_amdgcn_s_setprio(0);
    __builtin_amdgcn_sched_barrier(0);
    __builtin_amdgcn_s_barrier();
    __builtin_amdgcn_sched_barrier(0);

    // ======== p4: quadrant (1,0) — no reads (reuse A1 + B0); stage B1(t+2)->samebuf ========
    stage(d, 3, tn2);
    __builtin_amdgcn_sched_barrier(0);
    __builtin_amdgcn_s_barrier();
    __builtin_amdgcn_sched_barrier(0);
    __builtin_amdgcn_s_setprio(1);
    #pragma unroll
    for (int kk=0; kk<2; ++kk)
      #pragma unroll
      for (int il=0; il<4; ++il)
        #pragma unroll
        for (int jl=0; jl<2; ++jl)
          acc[4+il][jl] = mfma16(afr[il][kk], b0r[jl][kk], acc[4+il][jl]);
    __builtin_amdgcn_s_setprio(0);
    __builtin_amdgcn_sched_barrier(0);
    asm volatile("s_waitcnt vmcnt(4)" ::: "memory");
    __builtin_amdgcn_s_barrier();
    __builtin_amdgcn_sched_barrier(0);
  }
  // drain outstanding dummy DMA before workgroup can end
  asm volatile("s_waitcnt vmcnt(0) lgkmcnt(0)" ::: "memory");

  // epilogue: fi<4 -> half0 rows m0+wm*64+fi*16 ; fi>=4 -> half1 rows m0+128+...
  #pragma unroll
  for (int fi=0; fi<8; ++fi){
    int row0 = m0 + (fi>>2)*128 + wm*64 + (fi&3)*16 + (lane>>4)*4;
    #pragma unroll
    for (int fj=0; fj<4; ++fj){
      int col = n0 + (fj>>1)*128 + wn*32 + (fj&1)*16 + (lane&15);
      #pragma unroll
      for (int r=0; r<4; ++r){
        float v = acc[fi][fj][r];
        if (OUT_BF16) ((ushort*)Cv)[(size_t)(row0+r)*N + col] = f2bf(v);
        else          ((float*) Cv)[(size_t)(row0+r)*N + col] = v;
      }
    }
  }
}

// ---------------- wbT[h][d] bf16 <- wb[d][h] f32 ----------------
__global__ __launch_bounds__(256) void k_wbt(const float* __restrict__ wb, ushort* __restrict__ wbT){
  int d = blockIdx.x*256 + threadIdx.x;
  #pragma unroll
  for (int h=0;h<16;h++) wbT[(size_t)h*2048 + d] = f2bf(wb[(size_t)d*16 + h]);
}

// ---------------- beta = sigmoid(A16 @ wbT^T) via MFMA; out [b][h][l] f32 ----------------
__global__ __launch_bounds__(64) void k_beta2(const ushort* __restrict__ A16, const ushort* __restrict__ wbT,
                                              float* __restrict__ beta){
  const int rt = blockIdx.x;
  const int lane = threadIdx.x;
  const int lr = lane & 15, lk8 = (lane>>4)*8;
  const int r0 = rt*16;
  f32x4 acc0 = (f32x4){0.f,0.f,0.f,0.f};
  f32x4 acc1 = (f32x4){0.f,0.f,0.f,0.f};
  for (int k0=0; k0<2048; k0+=64){
    bf16x8 a0 = *(const bf16x8*)&A16[(size_t)(r0+lr)*2048 + k0 + lk8];
    bf16x8 b0 = *(const bf16x8*)&wbT[(size_t)lr*2048 + k0 + lk8];
    bf16x8 a1 = *(const bf16x8*)&A16[(size_t)(r0+lr)*2048 + k0 + 32 + lk8];
    bf16x8 b1 = *(const bf16x8*)&wbT[(size_t)lr*2048 + k0 + 32 + lk8];
    acc0 = mfma16(a0, b0, acc0);
    acc1 = mfma16(a1, b1, acc1);
  }
  const int h = lane & 15;
  const int rbase = r0 + (lane>>4)*4;
  #pragma unroll
  for (int r=0;r<4;r++){
    int row = rbase + r;
    int b = row >> 12, l = row & 4095;
    float sg = 1.f/(1.f + __expf(-(acc0[r] + acc1[r])));
    beta[((size_t)(b*H_ + h))*L_ + l] = sg;
  }
}

// ---------------- conv(K=4, causal)+SiLU+heads+l2norm, sliding window ----------------
__global__ __launch_bounds__(256) void k_conv2(const ushort* __restrict__ qkv,
      const float* __restrict__ wq, const float* __restrict__ wk, const float* __restrict__ wv,
      ushort* __restrict__ QH, ushort* __restrict__ KH, ushort* __restrict__ VH){
  const int seg = blockIdx.x, part = blockIdx.y, b = blockIdx.z;
  const int t = threadIdx.x;
  const int ch = t*8;
  const int h = t >> 4, d0 = (t & 15)*8;
  const float* wc = (part==0) ? wq : (part==1) ? wk : wv;
  ushort* outs = ((part==0) ? QH : (part==1) ? KH : VH)
                 + ((size_t)(b*H_ + h)*L_)*DK_ + d0;
  const ushort* inp = qkv + ((size_t)b*L_)*ND3 + part*D_ + ch;

  float wgt[4][8];
  #pragma unroll
  for (int j=0;j<8;j++){
    float4 w4 = *(const float4*)&wc[(ch + j)*4];
    wgt[0][j]=w4.x; wgt[1][j]=w4.y; wgt[2][j]=w4.z; wgt[3][j]=w4.w;
  }

  const int l0 = seg*32;
  float x0[8], x1[8], x2[8];
  {
    float* dsts[3] = {x0, x1, x2};
    #pragma unroll
    for (int i=0;i<3;i++){
      int l = l0 - 3 + i;
      float* d = dsts[i];
      if (l >= 0){
        const ushort* p = inp + (size_t)l*ND3;
        ushort4 a = *(const ushort4*)p, c = *(const ushort4*)(p+4);
        d[0]=bf2f(a.x); d[1]=bf2f(a.y); d[2]=bf2f(a.z); d[3]=bf2f(a.w);
        d[4]=bf2f(c.x); d[5]=bf2f(c.y); d[6]=bf2f(c.z); d[7]=bf2f(c.w);
      } else {
        #pragma unroll
        for (int j=0;j<8;j++) d[j] = 0.f;
      }
    }
  }

  for (int i=0;i<32;i++){
    const int l = l0 + i;
    float cur[8];
    {
      const ushort* p = inp + (size_t)l*ND3;
      ushort4 a = *(const ushort4*)p, c = *(const ushort4*)(p+4);
      cur[0]=bf2f(a.x); cur[1]=bf2f(a.y); cur[2]=bf2f(a.z); cur[3]=bf2f(a.w);
      cur[4]=bf2f(c.x); cur[5]=bf2f(c.y); cur[6]=bf2f(c.z); cur[7]=bf2f(c.w);
    }
    float y[8]; float ss = 0.f;
    #pragma unroll
    for (int j=0;j<8;j++){
      float yy = x0[j]*wgt[0][j] + x1[j]*wgt[1][j] + x2[j]*wgt[2][j] + cur[j]*wgt[3][j];
      yy = yy / (1.f + __expf(-yy));
      y[j] = yy; ss += yy*yy;
    }
    if (part < 2){
      #pragma unroll
      for (int m=1;m<16;m<<=1) ss += __shfl_xor(ss, m, 64);
      float sc = rsqrtf(ss + 1e-12f);
      #pragma unroll
      for (int j=0;j<8;j++) y[j] *= sc;
    }
    ushort4 o0, o1;
    o0.x=f2bf(y[0]); o0.y=f2bf(y[1]); o0.z=f2bf(y[2]); o0.w=f2bf(y[3]);
    o1.x=f2bf(y[4]); o1.y=f2bf(y[5]); o1.z=f2bf(y[6]); o1.w=f2bf(y[7]);
    ushort* op = outs + (size_t)l*DK_;
    *(ushort4*)op = o0; *(ushort4*)(op+4) = o1;
    #pragma unroll
    for (int j=0;j<8;j++){ x0[j]=x1[j]; x1[j]=x2[j]; x2[j]=cur[j]; }
  }
}

// ---------------- phase 1 v2: per-chunk Tb, M, Kt — register solve, 35KB LDS ----------------
__global__ __launch_bounds__(64) void k_prep(const ushort* __restrict__ QH, const ushort* __restrict__ KH,
      const float* __restrict__ BETA, ushort* __restrict__ TB, ushort* __restrict__ MM,
      ushort* __restrict__ KT){
  const int bid = blockIdx.x, bh = bid>>6, c = bid&63;
  const int lane = threadIdx.x;
  __shared__ ushort Ks[64][136];
  __shared__ __align__(16) char QA[17408];
  __shared__ float bs[64];
  ushort (*Qs)[136] = (ushort (*)[136])QA;
  float  (*As)[64]  = (float  (*)[64])QA;

  const ushort* kg = KH + ((size_t)bh*L_ + c*64)*DK_;
  const ushort* qg = QH + ((size_t)bh*L_ + c*64)*DK_;
  {
    const uint4* ks4 = (const uint4*)(kg + (size_t)lane*DK_);
    const uint4* qs4 = (const uint4*)(qg + (size_t)lane*DK_);
    uint4* kd = (uint4*)&Ks[lane][0];
    uint4* qd = (uint4*)&Qs[lane][0];
    #pragma unroll
    for (int i=0;i<16;i++){ kd[i] = ks4[i]; qd[i] = qs4[i]; }
    bs[lane] = BETA[(size_t)bh*L_ + c*64 + lane];
  }
  __syncthreads();
  const int lr = lane&15, lk = lane>>4;

  f32x4 gac[4][4];
  #pragma unroll
  for (int i=0;i<4;i++)
    #pragma unroll
    for (int j=0;j<4;j++) gac[i][j] = (f32x4){0.f,0.f,0.f,0.f};
  #pragma unroll
  for (int kk=0;kk<4;kk++){
    bf16x8 fr[4];
    #pragma unroll
    for (int i=0;i<4;i++) fr[i] = *(const bf16x8*)&Ks[i*16+lr][kk*32 + lk*8];
    #pragma unroll
    for (int mi=0;mi<4;mi++)
      #pragma unroll
      for (int ni=0;ni<4;ni++)
        gac[mi][ni] = mfma16(fr[mi], fr[ni], gac[mi][ni]);
  }
  {
    f32x4 mac[4][4];
    #pragma unroll
    for (int i=0;i<4;i++)
      #pragma unroll
      for (int j=0;j<4;j++) mac[i][j] = (f32x4){0.f,0.f,0.f,0.f};
    #pragma unroll
    for (int kk=0;kk<4;kk++){
      bf16x8 frq[4], frk[4];
      #pragma unroll
      for (int i=0;i<4;i++){
        frq[i] = *(const bf16x8*)&Qs[i*16+lr][kk*32 + lk*8];
        frk[i] = *(const bf16x8*)&Ks[i*16+lr][kk*32 + lk*8];
      }
      #pragma unroll
      for (int mi=0;mi<4;mi++)
        #pragma unroll
        for (int ni=0;ni<4;ni++)
          mac[mi][ni] = mfma16(frq[mi], frk[ni], mac[mi][ni]);
    }
    #pragma unroll
    for (int mi=0;mi<4;mi++)
      #pragma unroll
      for (int ni=0;ni<4;ni++)
        #pragma unroll
        for (int r=0;r<4;r++){
          int t = mi*16 + lk*4 + r, s = ni*16 + lr;
          float v = (s <= t) ? mac[mi][ni][r] : 0.f;
          MM[(size_t)bid*4096 + t*64 + s] = f2bf(v);
        }
  }
  __syncthreads();

  #pragma unroll
  for (int mi=0;mi<4;mi++)
    #pragma unroll
    for (int ni=0;ni<4;ni++)
      #pragma unroll
      for (int r=0;r<4;r++){
        int t = mi*16 + lk*4 + r, s = ni*16 + lr;
        As[t][s] = (s < t) ? (bs[t] * gac[mi][ni][r]) : 0.f;
      }
  __syncthreads();

  float rT[64];
  #pragma unroll
  for (int t=0;t<64;t++){
    float arow = As[t][lane];
    float a = (t==lane) ? 1.f : 0.f;
    #pragma unroll
    for (int s=0;s<t;s++){
      float cc = __int_as_float(__builtin_amdgcn_readlane(__float_as_int(arow), s));
      a -= cc * rT[s];
    }
    rT[t] = a;
  }
  {
    float bc = bs[lane];
    #pragma unroll
    for (int t=0;t<64;t++)
      TB[(size_t)bid*4096 + t*64 + lane] = f2bf(rT[t] * bc);
  }
  for (int d2=0; d2<64; d2++){
    unsigned uu = *(const unsigned*)&Ks[lane][2*d2];
    KT[(size_t)bid*8192 + (size_t)(2*d2)*64 + lane]   = (ushort)(uu & 0xffffu);
    KT[(size_t)bid*8192 + (size_t)(2*d2+1)*64 + lane] = (ushort)(uu >> 16);
  }
}

template<int LRB, int GRB, int NB, int XM>
__device__ __forceinline__ void stage_swz(const ushort* __restrict__ g, ushort* l,
                                          int colOff, int w, int lane){
  for (int idx = w; idx < NB/1024; idx += 4){
    int off = idx*1024 + lane*16;
    int row = off / LRB;
    int inner = off & (LRB-1);
    int src = row*GRB + colOff + (inner ^ ((row&XM)<<4));
    __builtin_amdgcn_global_load_lds(
      (const __attribute__((address_space(1))) void*)((const char*)g + src),
      (__attribute__((address_space(3))) void*)((char*)l + idx*1024), 16, 0, 0);
  }
}

// ======= chunk recurrence v3: 256 blocks (bh x dv-eighth), dbuf panels, raw barriers =======
__global__ __launch_bounds__(256) void k_chunkrec(const ushort* __restrict__ QH, const ushort* __restrict__ KH,
      const ushort* __restrict__ VH, const ushort* __restrict__ TB, const ushort* __restrict__ MM,
      const ushort* __restrict__ KT, ushort* __restrict__ OH){
  const int p = blockIdx.x;
  const int xg = p & 7, s = p >> 3;
  const int bh = xg + (s >> 3)*8;
  const int vo = s & 7;
  const int tid = threadIdx.x, lane = tid&63, w = tid>>6;
  const int lr = lane&15, lk = lane>>4;
  const int tw = w*16;
  const int dw = w*32;

  __shared__ ushort SM[71680];
  ushort* Stl = SM + 67584;
  ushort* Ztl = SM + 69632;
  ushort* Utl = SM + 70656;

  const ushort* kbase  = KH + ((size_t)bh*L_)*DK_;
  const ushort* qbase  = QH + ((size_t)bh*L_)*DK_;
  const ushort* vbase  = VH + ((size_t)bh*L_)*DK_;
  const ushort* tbase  = TB + ((size_t)bh*64)*4096;
  const ushort* mbase  = MM + ((size_t)bh*64)*4096;
  const ushort* ktbase = KT + ((size_t)bh*64)*8192;
  ushort* obase = OH + ((size_t)bh*L_)*DK_ + vo*16;

  auto stageall = [&](ushort* buf, int c){
    stage_swz<256,256,16384,7>(kbase  + (size_t)c*8192, buf,         0,     w, lane);
    stage_swz<256,256,16384,7>(qbase  + (size_t)c*8192, buf + 8192,  0,     w, lane);
    stage_swz<128,128,16384,7>(ktbase + (size_t)c*8192, buf + 16384, 0,     w, lane);
    stage_swz<128,128, 8192,7>(tbase  + (size_t)c*4096, buf + 24576, 0,     w, lane);
    stage_swz<128,128, 8192,7>(mbase  + (size_t)c*4096, buf + 28672, 0,     w, lane);
    stage_swz< 32,256, 2048,0>(vbase  + (size_t)c*8192, buf + 32768, vo*32, w, lane);
  };

  f32x4 Stf[2];
  Stf[0] = (f32x4){0.f,0.f,0.f,0.f};
  Stf[1] = (f32x4){0.f,0.f,0.f,0.f};

  stageall(SM, 0);
  BAR_VMALL();

  for (int c=0; c<64; ++c){
    ushort* buf  = SM + (c&1)*33792;
    ushort* nbuf = SM + ((c+1)&1)*33792;
    const ushort* Kc  = buf;
    const ushort* Qc  = buf + 8192;
    const ushort* Ktc = buf + 16384;
    const ushort* Tbc = buf + 24576;
    const ushort* Mc  = buf + 28672;
    const ushort* Vc  = buf + 32768;

    if (c+1 < 64) stageall(nbuf, c+1);

    #pragma unroll
    for (int nd=0;nd<2;nd++)
      #pragma unroll
      for (int r=0;r<4;r++){
        int j = lk*4 + r;
        int d = dw + nd*16 + lr;
        Stl[j*128 + (d ^ ((j&7)<<3))] = f2bf(Stf[nd][r]);
      }
    BAR_LGKM();

    f32x4 xac = (f32x4){0.f,0.f,0.f,0.f};
    #pragma unroll
    for (int kk=0;kk<4;kk++){
      int e = kk*32 + lk*8;
      int ta = tw + lr;
      bf16x8 ak  = *(const bf16x8*)&Kc[ta*128 + (e ^ ((ta&7)<<3))];
      bf16x8 bst = *(const bf16x8*)&Stl[lr*128 + (e ^ ((lr&7)<<3))];
      xac = mfma16(ak, bst, xac);
    }
    #pragma unroll
    for (int r=0;r<4;r++){
      int t = tw + lk*4 + r;
      int j = lr;
      float v = bf2f(Vc[t*16 + j]);
      Ztl[j*64 + (t ^ ((j&7)<<3))] = f2bf(v - xac[r]);
    }
    BAR_LGKM();

    f32x4 uac = (f32x4){0.f,0.f,0.f,0.f};
    #pragma unroll
    for (int kk=0;kk<2;kk++){
      int e = kk*32 + lk*8;
      int ta = tw + lr;
      bf16x8 at = *(const bf16x8*)&Tbc[ta*64 + (e ^ ((ta&7)<<3))];
      bf16x8 bz = *(const bf16x8*)&Ztl[lr*64 + (e ^ ((lr&7)<<3))];
      uac = mfma16(at, bz, uac);
    }
    #pragma unroll
    for (int r=0;r<4;r++){
      int t = tw + lk*4 + r;
      int j = lr;
      Utl[j*64 + (t ^ ((j&7)<<3))] = f2bf(uac[r]);
    }
    BAR_LGKM();

    f32x4 oac = (f32x4){0.f,0.f,0.f,0.f};
    #pragma unroll
    for (int kk=0;kk<4;kk++){
      int e = kk*32 + lk*8;
      int ta = tw + lr;
      bf16x8 aq  = *(const bf16x8*)&Qc[ta*128 + (e ^ ((ta&7)<<3))];
      bf16x8 bst = *(const bf16x8*)&Stl[lr*128 + (e ^ ((lr&7)<<3))];
      oac = mfma16(aq, bst, oac);
    }
    #pragma unroll
    for (int kk=0;kk<2;kk++){
      int e = kk*32 + lk*8;
      int ta = tw + lr;
      bf16x8 am = *(const bf16x8*)&Mc[ta*64 + (e ^ ((ta&7)<<3))];
      bf16x8 bu = *(const bf16x8*)&Utl[lr*64 + (e ^ ((lr&7)<<3))];
      oac = mfma16(am, bu, oac);
    }
    #pragma unroll
    for (int r=0;r<4;r++){
      int t = tw + lk*4 + r;
      int j = lr;
      obase[(size_t)(c*64 + t)*DK_ + j] = f2bf(oac[r]);
    }

    #pragma unroll
    for (int kk=0;kk<2;kk++){
      int e = kk*32 + lk*8;
      bf16x8 au = *(const bf16x8*)&Utl[lr*64 + (e ^ ((lr&7)<<3))];
      #pragma unroll
      for (int nd=0;nd<2;nd++){
        int d = dw + nd*16 + lr;
        bf16x8 bk = *(const bf16x8*)&Ktc[d*64 + (e ^ ((d&7)<<3))];
        Stf[nd] = mfma16(au, bk, Stf[nd]);
      }
    }
    BAR_VMALL();
  }
}

__global__ __launch_bounds__(256) void k_norm(const ushort* __restrict__ OH, const float* __restrict__ gw,
                                              ushort* __restrict__ O2){
  const int blk = blockIdx.x;
  const int b = blk >> 12, l = blk & 4095;
  const int t = threadIdx.x;
  const int h = t >> 4, d0 = (t & 15) * 8;
  const ushort* ip = OH + ((size_t)(b*H_ + h)*L_ + l)*DK_ + d0;
  ushort4 a = *(const ushort4*)ip, c = *(const ushort4*)(ip+4);
  float x[8];
  x[0]=bf2f(a.x); x[1]=bf2f(a.y); x[2]=bf2f(a.z); x[3]=bf2f(a.w);
  x[4]=bf2f(c.x); x[5]=bf2f(c.y); x[6]=bf2f(c.z); x[7]=bf2f(c.w);
  float ss = 0.f;
  #pragma unroll
  for (int j=0;j<8;j++) ss += x[j]*x[j];
  #pragma unroll
  for (int m=1;m<16;m<<=1) ss += __shfl_xor(ss, m, 64);
  float sc = rsqrtf(ss * (1.f/128.f) + 1e-5f);
  ushort* opp = O2 + (size_t)blk*D_ + h*DK_ + d0;
  ushort4 o0, o1;
  o0.x=f2bf(x[0]*sc*gw[d0+0]); o0.y=f2bf(x[1]*sc*gw[d0+1]);
  o0.z=f2bf(x[2]*sc*gw[d0+2]); o0.w=f2bf(x[3]*sc*gw[d0+3]);
  o1.x=f2bf(x[4]*sc*gw[d0+4]); o1.y=f2bf(x[5]*sc*gw[d0+5]);
  o1.z=f2bf(x[6]*sc*gw[d0+6]); o1.w=f2bf(x[7]*sc*gw[d0+7]);
  *(ushort4*)opp = o0; *(ushort4*)(opp+4) = o1;
}

extern "C" void kernel_launch(void* const* d_in, const int* in_sizes, int n_in,
                              void* d_out, int out_size, void* d_ws, size_t ws_size,
                              hipStream_t stream) {
  (void)in_sizes; (void)n_in; (void)out_size; (void)ws_size;
  const float* hidden  = (const float*)d_in[0];
  const float* w_cattn = (const float*)d_in[1];
  const float* wq_conv = (const float*)d_in[2];
  const float* wk_conv = (const float*)d_in[3];
  const float* wv_conv = (const float*)d_in[4];
  const float* w_beta  = (const float*)d_in[5];
  const float* o_nw    = (const float*)d_in[6];
  const float* w_o     = (const float*)d_in[7];
  float* out = (float*)d_out;

  char* W = (char*)d_ws;                              // total 260,046,848 B (known-good size)
  ushort* A16   = (ushort*)(W);                       // 32MB ; -> OH after gemm1
  ushort* WcatT = (ushort*)(W + 33554432u);           // 24MB; dead after gemm1
  ushort* WoT   = (ushort*)(W + 33554432u);           //  8MB (alias, written after gemm1)
  float*  BETA  = (float*) (W + 41943040u);           // 512KB (alias in dead WcatT region)
  ushort* WBT   = (ushort*)(W + 42467328u);           // 64KB  (alias in dead WcatT region)
  ushort* QKV   = (ushort*)(W + 58720256u);           // 96MB; dead after conv
  ushort* TB    = (ushort*)(W + 58720256u);           // 16MB (alias in dead QKV)
  ushort* MM    = (ushort*)(W + 75497472u);           // 16MB
  ushort* KT    = (ushort*)(W + 92274688u);           // 32MB
  ushort* O2    = (ushort*)(W + 125829120u);          // 32MB
  ushort* QH    = (ushort*)(W + 159383552u);          // 32MB
  ushort* KH    = (ushort*)(W + 192937984u);          // 32MB
  ushort* VH    = (ushort*)(W + 226492416u);          // 32MB -> end 260,046,848
  ushort* OH = A16;

  k_cast<<<4096, 256, 0, stream>>>(hidden, A16, (BL_*D_)/4);
  k_transpose_cast<<<dim3(ND3/32, D_/32), dim3(32,8), 0, stream>>>(w_cattn, WcatT, D_, ND3);
  k_gemm8<1><<<dim3(ND3/256, BL_/256), 512, 0, stream>>>(A16, WcatT, QKV, BL_, ND3, D_);
  // WcatT region dead from here on
  k_transpose_cast<<<dim3(D_/32, D_/32), dim3(32,8), 0, stream>>>(w_o, WoT, D_, D_);
  k_wbt<<<8, 256, 0, stream>>>(w_beta, WBT);
  k_beta2<<<512, 64, 0, stream>>>(A16, WBT, BETA);
  k_conv2<<<dim3(128, 3, 2), 256, 0, stream>>>(QKV, wq_conv, wk_conv, wv_conv, QH, KH, VH);
  k_prep<<<2048, 64, 0, stream>>>(QH, KH, BETA, TB, MM, KT);
  k_chunkrec<<<256, 256, 0, stream>>>(QH, KH, VH, TB, MM, KT, OH);
  k_norm<<<BL_, 256, 0, stream>>>(OH, o_nw, O2);
  k_gemm8<0><<<dim3(D_/256, BL_/256), 512, 0, stream>>>(O2, WoT, out, BL_, D_, D_);
}